// Round 1
// baseline (1171.094 us; speedup 1.0000x reference)
//
#include <hip/hip_runtime.h>
#include <math.h>

constexpr int HD = 128;   // hidden dim
constexpr int FD = 64;    // input feature dim

// ---------------- utility kernels ----------------
__global__ void zero_int_kernel(int* __restrict__ p, int n) {
  int i = blockIdx.x * blockDim.x + threadIdx.x;
  if (i < n) p[i] = 0;
}

__global__ void count_deg_kernel(const int* __restrict__ dst, int* __restrict__ deg, int e) {
  int i = blockIdx.x * blockDim.x + threadIdx.x;
  if (i < e) atomicAdd(&deg[dst[i]], 1);
}

__global__ void dinv_kernel(const int* __restrict__ deg, float* __restrict__ dinv, int n) {
  int i = blockIdx.x * blockDim.x + threadIdx.x;
  if (i < n) dinv[i] = rsqrtf((float)(deg[i] + 1));   // +1: self-loop
}

// single-block exclusive scan of deg -> offs (and a second copy into cursor)
__global__ __launch_bounds__(1024) void scan_kernel(const int* __restrict__ deg,
    int* __restrict__ offs, int* __restrict__ cursor, int n) {
  __shared__ int part[1024];
  int t = threadIdx.x;
  int chunk = (n + 1023) >> 10;
  int lo = t * chunk; if (lo > n) lo = n;
  int hi = lo + chunk; if (hi > n) hi = n;
  int s = 0;
  for (int i = lo; i < hi; ++i) s += deg[i];
  part[t] = s;
  __syncthreads();
  for (int d = 1; d < 1024; d <<= 1) {
    int v = (t >= d) ? part[t - d] : 0;
    __syncthreads();
    part[t] += v;
    __syncthreads();
  }
  int run = part[t] - s;   // exclusive prefix of this chunk
  for (int i = lo; i < hi; ++i) { offs[i] = run; cursor[i] = run; run += deg[i]; }
  if (t == 1023) offs[n] = part[1023];
}

__global__ void fill_csr_kernel(const int* __restrict__ src, const int* __restrict__ dst,
    int* __restrict__ cursor, int* __restrict__ csr_src, float* __restrict__ csr_w,
    const float* __restrict__ dinv, int e) {
  int i = blockIdx.x * blockDim.x + threadIdx.x;
  if (i >= e) return;
  int s = src[i], d = dst[i];
  int pos = atomicAdd(&cursor[d], 1);
  csr_src[pos] = s;
  csr_w[pos] = dinv[s];
}

// ---------------- f32 GEMM: C[M x 128] = A[M x K] @ W[K x 128] (+bias)(+relu) ----------------
// 128 threads, 32 rows per block. A tile staged in LDS (broadcast reads),
// W columns held in registers per k-group of 4 -> FMA-bound inner loop.
template<int K, bool BIAS, bool RELU>
__global__ __launch_bounds__(128) void gemm_aw_kernel(const float* __restrict__ A,
    const float* __restrict__ W, const float* __restrict__ bias,
    float* __restrict__ C, int M) {
  constexpr int K4 = K / 4;
  __shared__ float4 As4[32 * K4];
  const int tid = threadIdx.x;
  const int r0 = blockIdx.x * 32;
  const float4* A4 = (const float4*)A;
  #pragma unroll
  for (int i = tid; i < 32 * K4; i += 128) {
    int r = i / K4, kk = i - r * K4;
    int row = r0 + r;
    float4 v = make_float4(0.f, 0.f, 0.f, 0.f);
    if (row < M) v = A4[(size_t)row * K4 + kk];
    As4[i] = v;
  }
  __syncthreads();
  const int cg = tid & 31;          // column group: cols 4*cg .. 4*cg+3
  const int rbase = (tid >> 5) * 8; // 8 rows per thread
  float acc[8][4];
  #pragma unroll
  for (int r = 0; r < 8; ++r)
    #pragma unroll
    for (int j = 0; j < 4; ++j) acc[r][j] = 0.f;
  const float4* W4 = (const float4*)W;   // [K][32] float4 view
  for (int k0 = 0; k0 < K; k0 += 4) {
    float4 w[4];
    #pragma unroll
    for (int kk = 0; kk < 4; ++kk) w[kk] = W4[(k0 + kk) * 32 + cg];
    #pragma unroll
    for (int r = 0; r < 8; ++r) {
      float4 a = As4[(rbase + r) * K4 + (k0 >> 2)];
      const float* ap = (const float*)&a;
      #pragma unroll
      for (int kk = 0; kk < 4; ++kk) {
        acc[r][0] = fmaf(ap[kk], w[kk].x, acc[r][0]);
        acc[r][1] = fmaf(ap[kk], w[kk].y, acc[r][1]);
        acc[r][2] = fmaf(ap[kk], w[kk].z, acc[r][2]);
        acc[r][3] = fmaf(ap[kk], w[kk].w, acc[r][3]);
      }
    }
  }
  float4 bb = make_float4(0.f, 0.f, 0.f, 0.f);
  if (BIAS) bb = ((const float4*)bias)[cg];
  float4* C4 = (float4*)C;
  #pragma unroll
  for (int r = 0; r < 8; ++r) {
    int row = r0 + rbase + r;
    if (row < M) {
      float4 o;
      o.x = acc[r][0] + bb.x;
      o.y = acc[r][1] + bb.y;
      o.z = acc[r][2] + bb.z;
      o.w = acc[r][3] + bb.w;
      if (RELU) {
        o.x = fmaxf(o.x, 0.f); o.y = fmaxf(o.y, 0.f);
        o.z = fmaxf(o.z, 0.f); o.w = fmaxf(o.w, 0.f);
      }
      C4[(size_t)row * 32 + cg] = o;
    }
  }
}

// ---------------- GCN aggregation + residual update (one wave per node) ----------------
// x[i] += relu( dinv[i]*( sum_{e: dst=i} xw[src]*dinv[src] + xw[i]*dinv[i] ) + bias )
__global__ __launch_bounds__(256) void agg_update_kernel(
    const float* __restrict__ xw, float* __restrict__ x,
    const int* __restrict__ csr_src, const float* __restrict__ csr_w,
    const int* __restrict__ offs, const float* __restrict__ dinv,
    const float* __restrict__ bias, int n) {
  int node = blockIdx.x * 4 + (threadIdx.x >> 6);
  if (node >= n) return;
  int lane = threadIdx.x & 63;
  const float2* xw2 = (const float2*)xw;
  float accx = 0.f, accy = 0.f;
  int beg = offs[node], end = offs[node + 1];
  int j = beg;
  for (; j + 1 < end; j += 2) {
    int s0 = csr_src[j];     float w0 = csr_w[j];
    int s1 = csr_src[j + 1]; float w1 = csr_w[j + 1];
    float2 v0 = xw2[s0 * 64 + lane];
    float2 v1 = xw2[s1 * 64 + lane];
    accx = fmaf(v0.x, w0, accx); accy = fmaf(v0.y, w0, accy);
    accx = fmaf(v1.x, w1, accx); accy = fmaf(v1.y, w1, accy);
  }
  if (j < end) {
    int s0 = csr_src[j]; float w0 = csr_w[j];
    float2 v0 = xw2[s0 * 64 + lane];
    accx = fmaf(v0.x, w0, accx); accy = fmaf(v0.y, w0, accy);
  }
  float di = dinv[node];
  float2 vi = xw2[node * 64 + lane];
  accx = fmaf(vi.x, di, accx);
  accy = fmaf(vi.y, di, accy);
  float2 bb = ((const float2*)bias)[lane];
  float2* x2 = (float2*)x;
  float2 xv = x2[node * 64 + lane];
  float2 o;
  o.x = fmaxf(fmaf(accx, di, bb.x), 0.f) + xv.x;
  o.y = fmaxf(fmaf(accy, di, bb.y), 0.f) + xv.y;
  x2[node * 64 + lane] = o;
}

// ---------------- graph boundaries from sorted batch ----------------
__global__ void bounds_kernel(const int* __restrict__ batch, int* __restrict__ startg,
                              int n, int ng) {
  int i = blockIdx.x * blockDim.x + threadIdx.x;
  if (i > n) return;
  int bi = (i < n) ? batch[i] : ng;
  int bp = (i == 0) ? -1 : batch[i - 1];
  for (int g = bp + 1; g <= bi && g <= ng; ++g) startg[g] = i;
}

// ---------------- per-graph mean/max pooling ----------------
__global__ __launch_bounds__(128) void pool_kernel(const float* __restrict__ x,
    const int* __restrict__ startg, float* __restrict__ repr) {
  int g = blockIdx.x, c = threadIdx.x;
  int s0 = startg[g], s1 = startg[g + 1];
  float sum = 0.f, mx = -INFINITY;
  #pragma unroll 4
  for (int r = s0; r < s1; ++r) {
    float v = x[(size_t)r * HD + c];
    sum += v;
    mx = fmaxf(mx, v);
  }
  int cnt = s1 - s0;
  float denom = (float)(cnt > 0 ? cnt : 1);
  repr[g * 256 + c] = sum / denom;
  repr[g * 256 + 128 + c] = mx;
}

// ---------------- decoder + value heads (one block per graph) ----------------
__global__ __launch_bounds__(128) void heads_kernel(
    const float* __restrict__ repr,
    const float* __restrict__ dw1, const float* __restrict__ db1,
    const float* __restrict__ dw2, const float* __restrict__ db2,
    const float* __restrict__ dw3, const float* __restrict__ db3,
    const float* __restrict__ vw1, const float* __restrict__ vb1,
    const float* __restrict__ vw2, const float* __restrict__ vb2,
    float* __restrict__ out, int ng) {
  __shared__ float rep[256];
  __shared__ float h1[128];
  __shared__ float h2[64];
  __shared__ float v1[128];
  int g = blockIdx.x, t = threadIdx.x;
  rep[t] = repr[g * 256 + t];
  rep[128 + t] = repr[g * 256 + 128 + t];
  __syncthreads();
  float a = db1[t], b = vb1[t];
  for (int k = 0; k < 256; ++k) {
    float rv = rep[k];
    a = fmaf(rv, dw1[k * 128 + t], a);
    b = fmaf(rv, vw1[k * 128 + t], b);
  }
  h1[t] = fmaxf(a, 0.f);
  v1[t] = fmaxf(b, 0.f);
  __syncthreads();
  if (t < 64) {
    float c = db2[t];
    for (int k = 0; k < 128; ++k) c = fmaf(h1[k], dw2[k * 64 + t], c);
    h2[t] = fmaxf(c, 0.f);
  }
  __syncthreads();
  if (t == 0) {
    float l0 = db3[0], l2 = db3[2];
    for (int k = 0; k < 64; ++k) {
      l0 = fmaf(h2[k], dw3[k * 3 + 0], l0);
      l2 = fmaf(h2[k], dw3[k * 3 + 2], l2);
    }
    out[g] = 1.f / (1.f + expf(-l0));          // adaptation_prob
    out[ng + g] = 1.0f;                        // softmax over 1 element == 1
    out[2 * ng + g] = 1.f / (1.f + expf(-l2)); // urgency_score
    float v = vb2[0];
    for (int k = 0; k < 128; ++k) v = fmaf(v1[k], vw2[k], v);
    out[3 * ng + g] = v;                       // value_estimate
  }
}

// ---------------- launch ----------------
extern "C" void kernel_launch(void* const* d_in, const int* in_sizes, int n_in,
                              void* d_out, int out_size, void* d_ws, size_t ws_size,
                              hipStream_t stream) {
  const float* nf     = (const float*)d_in[0];
  const int*   ei     = (const int*)d_in[1];
  const int*   batch  = (const int*)d_in[2];
  const float* enc_w1 = (const float*)d_in[3];
  const float* enc_b1 = (const float*)d_in[4];
  const float* enc_w2 = (const float*)d_in[5];
  const float* enc_b2 = (const float*)d_in[6];
  const float* gcn_w  = (const float*)d_in[7];
  const float* gcn_b  = (const float*)d_in[8];
  const float* dec_w1 = (const float*)d_in[9];
  const float* dec_b1 = (const float*)d_in[10];
  const float* dec_w2 = (const float*)d_in[11];
  const float* dec_b2 = (const float*)d_in[12];
  const float* dec_w3 = (const float*)d_in[13];
  const float* dec_b3 = (const float*)d_in[14];
  const float* val_w1 = (const float*)d_in[15];
  const float* val_b1 = (const float*)d_in[16];
  const float* val_w2 = (const float*)d_in[17];
  const float* val_b2 = (const float*)d_in[18];
  float* out = (float*)d_out;

  const int n = in_sizes[0] / FD;           // 100000
  const int e = in_sizes[1] / 2;            // 1600000
  const int L = in_sizes[7] / (HD * HD);    // 3
  const int G = out_size / 4;               // 64

  // workspace carve
  char* p = (char*)d_ws;
  auto carve = [&](size_t bytes) {
    void* r = (void*)p;
    p += (bytes + 255) & ~(size_t)255;
    return r;
  };
  float* x       = (float*)carve((size_t)n * HD * 4);
  float* xw      = (float*)carve((size_t)n * HD * 4);
  float* dinv    = (float*)carve((size_t)n * 4);
  int*   deg     = (int*)carve((size_t)n * 4);
  int*   offs    = (int*)carve((size_t)(n + 1) * 4);
  int*   cursor  = (int*)carve((size_t)n * 4);
  int*   csr_src = (int*)carve((size_t)e * 4);
  float* csr_w   = (float*)carve((size_t)e * 4);
  float* repr    = (float*)carve((size_t)G * 256 * 4);
  int*   startg  = (int*)carve((size_t)(G + 1) * 4);

  const int gemm_grid = (n + 31) / 32;

  // graph structure (reused across layers)
  zero_int_kernel<<<(n + 255) / 256, 256, 0, stream>>>(deg, n);
  count_deg_kernel<<<(e + 255) / 256, 256, 0, stream>>>(ei + e, deg, e);
  dinv_kernel<<<(n + 255) / 256, 256, 0, stream>>>(deg, dinv, n);
  scan_kernel<<<1, 1024, 0, stream>>>(deg, offs, cursor, n);
  fill_csr_kernel<<<(e + 255) / 256, 256, 0, stream>>>(ei, ei + e, cursor, csr_src, csr_w, dinv, e);

  // encoder
  gemm_aw_kernel<FD, true, true><<<gemm_grid, 128, 0, stream>>>(nf, enc_w1, enc_b1, xw, n);
  gemm_aw_kernel<HD, true, false><<<gemm_grid, 128, 0, stream>>>(xw, enc_w2, enc_b2, x, n);

  // GCN layers
  for (int l = 0; l < L; ++l) {
    gemm_aw_kernel<HD, false, false><<<gemm_grid, 128, 0, stream>>>(
        x, gcn_w + (size_t)l * HD * HD, nullptr, xw, n);
    agg_update_kernel<<<(n + 3) / 4, 256, 0, stream>>>(
        xw, x, csr_src, csr_w, offs, dinv, gcn_b + (size_t)l * HD, n);
  }

  // pooling + heads
  bounds_kernel<<<(n + 1 + 255) / 256, 256, 0, stream>>>(batch, startg, n, G);
  pool_kernel<<<G, 128, 0, stream>>>(x, startg, repr);
  heads_kernel<<<G, 128, 0, stream>>>(repr,
      dec_w1, dec_b1, dec_w2, dec_b2, dec_w3, dec_b3,
      val_w1, val_b1, val_w2, val_b2, out, G);
}

// Round 2
// 956.315 us; speedup vs baseline: 1.2246x; 1.2246x over previous
//
#include <hip/hip_runtime.h>
#include <math.h>

constexpr int HD = 128;   // hidden dim
constexpr int FD = 64;    // input feature dim

// ---------------- utility kernels ----------------
__global__ void zero_int_kernel(int* __restrict__ p, int n) {
  int i = blockIdx.x * blockDim.x + threadIdx.x;
  if (i < n) p[i] = 0;
}

__global__ void count_deg_kernel(const int* __restrict__ dst, int* __restrict__ deg, int e) {
  int i = blockIdx.x * blockDim.x + threadIdx.x;
  if (i < e) atomicAdd(&deg[dst[i]], 1);
}

__global__ void dinv_kernel(const int* __restrict__ deg, float* __restrict__ dinv, int n) {
  int i = blockIdx.x * blockDim.x + threadIdx.x;
  if (i < n) dinv[i] = rsqrtf((float)(deg[i] + 1));   // +1: self-loop
}

// ---------------- hierarchical scan (3 kernels) ----------------
// 1) per-block (1024-elem chunk) reduction
__global__ __launch_bounds__(256) void deg_reduce_kernel(const int* __restrict__ deg,
    int* __restrict__ partial, int n) {
  __shared__ int sh[256];
  int b = blockIdx.x, t = threadIdx.x;
  int base = b * 1024 + t * 4;
  int s = 0;
  #pragma unroll
  for (int k = 0; k < 4; ++k) { int i = base + k; if (i < n) s += deg[i]; }
  sh[t] = s;
  __syncthreads();
  for (int d = 128; d > 0; d >>= 1) {
    if (t < d) sh[t] += sh[t + d];
    __syncthreads();
  }
  if (t == 0) partial[b] = sh[0];
}

// 2) scan the (<=128) block partials in one block
__global__ __launch_bounds__(128) void partial_scan_kernel(const int* __restrict__ partial,
    int* __restrict__ pref, int nb) {
  __shared__ int sh[128];
  int t = threadIdx.x;
  int v = (t < nb) ? partial[t] : 0;
  sh[t] = v;
  __syncthreads();
  for (int d = 1; d < 128; d <<= 1) {
    int u = (t >= d) ? sh[t - d] : 0;
    __syncthreads();
    sh[t] += u;
    __syncthreads();
  }
  if (t < nb) pref[t] = sh[t] - v;          // exclusive prefix
  if (t == 127) pref[nb] = sh[127];         // total
}

// 3) per-block exclusive scan of the chunk, offset by block prefix
__global__ __launch_bounds__(256) void offs_fill_kernel(const int* __restrict__ deg,
    const int* __restrict__ pref, int* __restrict__ offs, int* __restrict__ cursor,
    int n, int nb) {
  __shared__ int sh[256];
  int b = blockIdx.x, t = threadIdx.x;
  int base = b * 1024 + t * 4;
  int d[4]; int s = 0;
  #pragma unroll
  for (int k = 0; k < 4; ++k) {
    int i = base + k;
    d[k] = (i < n) ? deg[i] : 0;
    s += d[k];
  }
  sh[t] = s;
  __syncthreads();
  for (int dd = 1; dd < 256; dd <<= 1) {
    int u = (t >= dd) ? sh[t - dd] : 0;
    __syncthreads();
    sh[t] += u;
    __syncthreads();
  }
  int run = pref[b] + sh[t] - s;   // exclusive prefix for this thread's 4 elems
  #pragma unroll
  for (int k = 0; k < 4; ++k) {
    int i = base + k;
    if (i < n) { offs[i] = run; cursor[i] = run; }
    run += d[k];
  }
  if (b == 0 && t == 0) offs[n] = pref[nb];
}

__global__ void fill_csr_kernel(const int* __restrict__ src, const int* __restrict__ dst,
    int* __restrict__ cursor, int* __restrict__ csr_src, float* __restrict__ csr_w,
    const float* __restrict__ dinv, int e) {
  int i = blockIdx.x * blockDim.x + threadIdx.x;
  if (i >= e) return;
  int s = src[i], d = dst[i];
  int pos = atomicAdd(&cursor[d], 1);
  csr_src[pos] = s;
  csr_w[pos] = dinv[s];
}

// ---------------- f32 GEMM: C[M x 128] = A[M x K] @ W[K x 128] (+bias)(+relu) ----------------
template<int K, bool BIAS, bool RELU>
__global__ __launch_bounds__(128) void gemm_aw_kernel(const float* __restrict__ A,
    const float* __restrict__ W, const float* __restrict__ bias,
    float* __restrict__ C, int M) {
  constexpr int K4 = K / 4;
  __shared__ float4 As4[32 * K4];
  const int tid = threadIdx.x;
  const int r0 = blockIdx.x * 32;
  const float4* A4 = (const float4*)A;
  #pragma unroll
  for (int i = tid; i < 32 * K4; i += 128) {
    int r = i / K4, kk = i - r * K4;
    int row = r0 + r;
    float4 v = make_float4(0.f, 0.f, 0.f, 0.f);
    if (row < M) v = A4[(size_t)row * K4 + kk];
    As4[i] = v;
  }
  __syncthreads();
  const int cg = tid & 31;          // column group: cols 4*cg .. 4*cg+3
  const int rbase = (tid >> 5) * 8; // 8 rows per thread
  float acc[8][4];
  #pragma unroll
  for (int r = 0; r < 8; ++r)
    #pragma unroll
    for (int j = 0; j < 4; ++j) acc[r][j] = 0.f;
  const float4* W4 = (const float4*)W;   // [K][32] float4 view
  for (int k0 = 0; k0 < K; k0 += 4) {
    float4 w[4];
    #pragma unroll
    for (int kk = 0; kk < 4; ++kk) w[kk] = W4[(k0 + kk) * 32 + cg];
    #pragma unroll
    for (int r = 0; r < 8; ++r) {
      float4 a = As4[(rbase + r) * K4 + (k0 >> 2)];
      const float* ap = (const float*)&a;
      #pragma unroll
      for (int kk = 0; kk < 4; ++kk) {
        acc[r][0] = fmaf(ap[kk], w[kk].x, acc[r][0]);
        acc[r][1] = fmaf(ap[kk], w[kk].y, acc[r][1]);
        acc[r][2] = fmaf(ap[kk], w[kk].z, acc[r][2]);
        acc[r][3] = fmaf(ap[kk], w[kk].w, acc[r][3]);
      }
    }
  }
  float4 bb = make_float4(0.f, 0.f, 0.f, 0.f);
  if (BIAS) bb = ((const float4*)bias)[cg];
  float4* C4 = (float4*)C;
  #pragma unroll
  for (int r = 0; r < 8; ++r) {
    int row = r0 + rbase + r;
    if (row < M) {
      float4 o;
      o.x = acc[r][0] + bb.x;
      o.y = acc[r][1] + bb.y;
      o.z = acc[r][2] + bb.z;
      o.w = acc[r][3] + bb.w;
      if (RELU) {
        o.x = fmaxf(o.x, 0.f); o.y = fmaxf(o.y, 0.f);
        o.z = fmaxf(o.z, 0.f); o.w = fmaxf(o.w, 0.f);
      }
      C4[(size_t)row * 32 + cg] = o;
    }
  }
}

// ---------------- GCN aggregation + residual update (one wave per node) ----------------
__global__ __launch_bounds__(256) void agg_update_kernel(
    const float* __restrict__ xw, float* __restrict__ x,
    const int* __restrict__ csr_src, const float* __restrict__ csr_w,
    const int* __restrict__ offs, const float* __restrict__ dinv,
    const float* __restrict__ bias, int n) {
  int node = blockIdx.x * 4 + (threadIdx.x >> 6);
  if (node >= n) return;
  int lane = threadIdx.x & 63;
  const float2* xw2 = (const float2*)xw;
  float accx = 0.f, accy = 0.f;
  int beg = offs[node], end = offs[node + 1];
  int j = beg;
  for (; j + 1 < end; j += 2) {
    int s0 = csr_src[j];     float w0 = csr_w[j];
    int s1 = csr_src[j + 1]; float w1 = csr_w[j + 1];
    float2 v0 = xw2[s0 * 64 + lane];
    float2 v1 = xw2[s1 * 64 + lane];
    accx = fmaf(v0.x, w0, accx); accy = fmaf(v0.y, w0, accy);
    accx = fmaf(v1.x, w1, accx); accy = fmaf(v1.y, w1, accy);
  }
  if (j < end) {
    int s0 = csr_src[j]; float w0 = csr_w[j];
    float2 v0 = xw2[s0 * 64 + lane];
    accx = fmaf(v0.x, w0, accx); accy = fmaf(v0.y, w0, accy);
  }
  float di = dinv[node];
  float2 vi = xw2[node * 64 + lane];
  accx = fmaf(vi.x, di, accx);
  accy = fmaf(vi.y, di, accy);
  float2 bb = ((const float2*)bias)[lane];
  float2* x2 = (float2*)x;
  float2 xv = x2[node * 64 + lane];
  float2 o;
  o.x = fmaxf(fmaf(accx, di, bb.x), 0.f) + xv.x;
  o.y = fmaxf(fmaf(accy, di, bb.y), 0.f) + xv.y;
  x2[node * 64 + lane] = o;
}

// ---------------- graph boundaries from sorted batch ----------------
__global__ void bounds_kernel(const int* __restrict__ batch, int* __restrict__ startg,
                              int n, int ng) {
  int i = blockIdx.x * blockDim.x + threadIdx.x;
  if (i > n) return;
  int bi = (i < n) ? batch[i] : ng;
  int bp = (i == 0) ? -1 : batch[i - 1];
  for (int g = bp + 1; g <= bi && g <= ng; ++g) startg[g] = i;
}

// ---------------- per-graph mean/max pooling ----------------
__global__ __launch_bounds__(128) void pool_kernel(const float* __restrict__ x,
    const int* __restrict__ startg, float* __restrict__ repr) {
  int g = blockIdx.x, c = threadIdx.x;
  int s0 = startg[g], s1 = startg[g + 1];
  float sum = 0.f, mx = -INFINITY;
  #pragma unroll 4
  for (int r = s0; r < s1; ++r) {
    float v = x[(size_t)r * HD + c];
    sum += v;
    mx = fmaxf(mx, v);
  }
  int cnt = s1 - s0;
  float denom = (float)(cnt > 0 ? cnt : 1);
  repr[g * 256 + c] = sum / denom;
  repr[g * 256 + 128 + c] = mx;
}

// ---------------- decoder + value heads (one block per graph) ----------------
__global__ __launch_bounds__(128) void heads_kernel(
    const float* __restrict__ repr,
    const float* __restrict__ dw1, const float* __restrict__ db1,
    const float* __restrict__ dw2, const float* __restrict__ db2,
    const float* __restrict__ dw3, const float* __restrict__ db3,
    const float* __restrict__ vw1, const float* __restrict__ vb1,
    const float* __restrict__ vw2, const float* __restrict__ vb2,
    float* __restrict__ out, int ng) {
  __shared__ float rep[256];
  __shared__ float h1[128];
  __shared__ float h2[64];
  __shared__ float v1[128];
  int g = blockIdx.x, t = threadIdx.x;
  rep[t] = repr[g * 256 + t];
  rep[128 + t] = repr[g * 256 + 128 + t];
  __syncthreads();
  float a = db1[t], b = vb1[t];
  for (int k = 0; k < 256; ++k) {
    float rv = rep[k];
    a = fmaf(rv, dw1[k * 128 + t], a);
    b = fmaf(rv, vw1[k * 128 + t], b);
  }
  h1[t] = fmaxf(a, 0.f);
  v1[t] = fmaxf(b, 0.f);
  __syncthreads();
  if (t < 64) {
    float c = db2[t];
    for (int k = 0; k < 128; ++k) c = fmaf(h1[k], dw2[k * 64 + t], c);
    h2[t] = fmaxf(c, 0.f);
  }
  __syncthreads();
  if (t == 0) {
    float l0 = db3[0], l2 = db3[2];
    for (int k = 0; k < 64; ++k) {
      l0 = fmaf(h2[k], dw3[k * 3 + 0], l0);
      l2 = fmaf(h2[k], dw3[k * 3 + 2], l2);
    }
    out[g] = 1.f / (1.f + expf(-l0));          // adaptation_prob
    out[ng + g] = 1.0f;                        // softmax over 1 element == 1
    out[2 * ng + g] = 1.f / (1.f + expf(-l2)); // urgency_score
    float v = vb2[0];
    for (int k = 0; k < 128; ++k) v = fmaf(v1[k], vw2[k], v);
    out[3 * ng + g] = v;                       // value_estimate
  }
}

// ---------------- launch ----------------
extern "C" void kernel_launch(void* const* d_in, const int* in_sizes, int n_in,
                              void* d_out, int out_size, void* d_ws, size_t ws_size,
                              hipStream_t stream) {
  const float* nf     = (const float*)d_in[0];
  const int*   ei     = (const int*)d_in[1];
  const int*   batch  = (const int*)d_in[2];
  const float* enc_w1 = (const float*)d_in[3];
  const float* enc_b1 = (const float*)d_in[4];
  const float* enc_w2 = (const float*)d_in[5];
  const float* enc_b2 = (const float*)d_in[6];
  const float* gcn_w  = (const float*)d_in[7];
  const float* gcn_b  = (const float*)d_in[8];
  const float* dec_w1 = (const float*)d_in[9];
  const float* dec_b1 = (const float*)d_in[10];
  const float* dec_w2 = (const float*)d_in[11];
  const float* dec_b2 = (const float*)d_in[12];
  const float* dec_w3 = (const float*)d_in[13];
  const float* dec_b3 = (const float*)d_in[14];
  const float* val_w1 = (const float*)d_in[15];
  const float* val_b1 = (const float*)d_in[16];
  const float* val_w2 = (const float*)d_in[17];
  const float* val_b2 = (const float*)d_in[18];
  float* out = (float*)d_out;

  const int n = in_sizes[0] / FD;           // 100000
  const int e = in_sizes[1] / 2;            // 1600000
  const int L = in_sizes[7] / (HD * HD);    // 3
  const int G = out_size / 4;               // 64

  // workspace carve
  char* p = (char*)d_ws;
  auto carve = [&](size_t bytes) {
    void* r = (void*)p;
    p += (bytes + 255) & ~(size_t)255;
    return r;
  };
  float* x       = (float*)carve((size_t)n * HD * 4);
  float* xw      = (float*)carve((size_t)n * HD * 4);
  float* dinv    = (float*)carve((size_t)n * 4);
  int*   deg     = (int*)carve((size_t)n * 4);
  int*   offs    = (int*)carve((size_t)(n + 1) * 4);
  int*   cursor  = (int*)carve((size_t)n * 4);
  int*   csr_src = (int*)carve((size_t)e * 4);
  float* csr_w   = (float*)carve((size_t)e * 4);
  float* repr    = (float*)carve((size_t)G * 256 * 4);
  int*   startg  = (int*)carve((size_t)(G + 1) * 4);
  const int nb   = (n + 1023) / 1024;       // scan blocks (98 for n=100000)
  int*   partial = (int*)carve((size_t)nb * 4);
  int*   pref    = (int*)carve((size_t)(nb + 1) * 4);

  const int gemm_grid = (n + 31) / 32;

  // graph structure (reused across layers)
  zero_int_kernel<<<(n + 255) / 256, 256, 0, stream>>>(deg, n);
  count_deg_kernel<<<(e + 255) / 256, 256, 0, stream>>>(ei + e, deg, e);
  dinv_kernel<<<(n + 255) / 256, 256, 0, stream>>>(deg, dinv, n);
  deg_reduce_kernel<<<nb, 256, 0, stream>>>(deg, partial, n);
  partial_scan_kernel<<<1, 128, 0, stream>>>(partial, pref, nb);
  offs_fill_kernel<<<nb, 256, 0, stream>>>(deg, pref, offs, cursor, n, nb);
  fill_csr_kernel<<<(e + 255) / 256, 256, 0, stream>>>(ei, ei + e, cursor, csr_src, csr_w, dinv, e);

  // encoder
  gemm_aw_kernel<FD, true, true><<<gemm_grid, 128, 0, stream>>>(nf, enc_w1, enc_b1, xw, n);
  gemm_aw_kernel<HD, true, false><<<gemm_grid, 128, 0, stream>>>(xw, enc_w2, enc_b2, x, n);

  // GCN layers
  for (int l = 0; l < L; ++l) {
    gemm_aw_kernel<HD, false, false><<<gemm_grid, 128, 0, stream>>>(
        x, gcn_w + (size_t)l * HD * HD, nullptr, xw, n);
    agg_update_kernel<<<(n + 3) / 4, 256, 0, stream>>>(
        xw, x, csr_src, csr_w, offs, dinv, gcn_b + (size_t)l * HD, n);
  }

  // pooling + heads
  bounds_kernel<<<(n + 1 + 255) / 256, 256, 0, stream>>>(batch, startg, n, G);
  pool_kernel<<<G, 128, 0, stream>>>(x, startg, repr);
  heads_kernel<<<G, 128, 0, stream>>>(repr,
      dec_w1, dec_b1, dec_w2, dec_b2, dec_w3, dec_b3,
      val_w1, val_b1, val_w2, val_b2, out, G);
}

// Round 3
// 829.595 us; speedup vs baseline: 1.4116x; 1.1527x over previous
//
#include <hip/hip_runtime.h>
#include <math.h>

constexpr int HD = 128;   // hidden dim
constexpr int FD = 64;    // input feature dim
constexpr int PCH = 8;    // pooling chunks per graph

typedef unsigned int uint;
typedef unsigned short ushort;

static __device__ inline ushort f2bf(float f) {   // round-to-nearest-even bf16
  uint u = __float_as_uint(f);
  return (ushort)((u + 0x7fffu + ((u >> 16) & 1u)) >> 16);
}
static __device__ inline float bf2f(ushort b) {
  return __uint_as_float((uint)b << 16);
}

// ---------------- utility kernels ----------------
__global__ void zero_int_kernel(int* __restrict__ p, int n) {
  int i = blockIdx.x * blockDim.x + threadIdx.x;
  if (i < n) p[i] = 0;
}

__global__ void count_deg_kernel(const int* __restrict__ dst, int* __restrict__ deg, int e) {
  int i = blockIdx.x * blockDim.x + threadIdx.x;
  if (i < e) atomicAdd(&deg[dst[i]], 1);
}

__global__ void dinv_kernel(const int* __restrict__ deg, float* __restrict__ dinv, int n) {
  int i = blockIdx.x * blockDim.x + threadIdx.x;
  if (i < n) dinv[i] = rsqrtf((float)(deg[i] + 1));   // +1: self-loop
}

// ---------------- hierarchical scan (3 kernels) ----------------
__global__ __launch_bounds__(256) void deg_reduce_kernel(const int* __restrict__ deg,
    int* __restrict__ partial, int n) {
  __shared__ int sh[256];
  int b = blockIdx.x, t = threadIdx.x;
  int base = b * 1024 + t * 4;
  int s = 0;
  #pragma unroll
  for (int k = 0; k < 4; ++k) { int i = base + k; if (i < n) s += deg[i]; }
  sh[t] = s;
  __syncthreads();
  for (int d = 128; d > 0; d >>= 1) {
    if (t < d) sh[t] += sh[t + d];
    __syncthreads();
  }
  if (t == 0) partial[b] = sh[0];
}

__global__ __launch_bounds__(128) void partial_scan_kernel(const int* __restrict__ partial,
    int* __restrict__ pref, int nb) {
  __shared__ int sh[128];
  int t = threadIdx.x;
  int v = (t < nb) ? partial[t] : 0;
  sh[t] = v;
  __syncthreads();
  for (int d = 1; d < 128; d <<= 1) {
    int u = (t >= d) ? sh[t - d] : 0;
    __syncthreads();
    sh[t] += u;
    __syncthreads();
  }
  if (t < nb) pref[t] = sh[t] - v;          // exclusive prefix
  if (t == 127) pref[nb] = sh[127];         // total
}

__global__ __launch_bounds__(256) void offs_fill_kernel(const int* __restrict__ deg,
    const int* __restrict__ pref, int* __restrict__ offs, int* __restrict__ cursor,
    int n, int nb) {
  __shared__ int sh[256];
  int b = blockIdx.x, t = threadIdx.x;
  int base = b * 1024 + t * 4;
  int d[4]; int s = 0;
  #pragma unroll
  for (int k = 0; k < 4; ++k) {
    int i = base + k;
    d[k] = (i < n) ? deg[i] : 0;
    s += d[k];
  }
  sh[t] = s;
  __syncthreads();
  for (int dd = 1; dd < 256; dd <<= 1) {
    int u = (t >= dd) ? sh[t - dd] : 0;
    __syncthreads();
    sh[t] += u;
    __syncthreads();
  }
  int run = pref[b] + sh[t] - s;
  #pragma unroll
  for (int k = 0; k < 4; ++k) {
    int i = base + k;
    if (i < n) { offs[i] = run; cursor[i] = run; }
    run += d[k];
  }
  if (b == 0 && t == 0) offs[n] = pref[nb];
}

__global__ void fill_csr_kernel(const int* __restrict__ src, const int* __restrict__ dst,
    int* __restrict__ cursor, int* __restrict__ csr_src, int e) {
  int i = blockIdx.x * blockDim.x + threadIdx.x;
  if (i >= e) return;
  int s = src[i], d = dst[i];
  int pos = atomicAdd(&cursor[d], 1);
  csr_src[pos] = s;
}

// ---------------- f32-math GEMM: C[M x 128] = A[M x K] @ W[K x 128] (+bias)(+relu) ----
// TA/TC in {float, ushort(bf16)}. Math in f32; LDS holds f32 A tile.
template<typename TA, typename TC, int K, bool BIAS, bool RELU>
__global__ __launch_bounds__(128) void gemm_aw_kernel(const TA* __restrict__ A,
    const float* __restrict__ W, const float* __restrict__ bias,
    TC* __restrict__ C, int M) {
  constexpr int K4 = K / 4;
  __shared__ float4 As4[32 * K4];
  const int tid = threadIdx.x;
  const int r0 = blockIdx.x * 32;
  #pragma unroll
  for (int i = tid; i < 32 * K4; i += 128) {
    int r = i / K4, kk = i - r * K4;
    int row = r0 + r;
    float4 v = make_float4(0.f, 0.f, 0.f, 0.f);
    if (row < M) {
      if constexpr (sizeof(TA) == 4) {
        v = ((const float4*)A)[(size_t)row * K4 + kk];
      } else {
        ushort4 u = ((const ushort4*)A)[(size_t)row * K4 + kk];
        v = make_float4(bf2f(u.x), bf2f(u.y), bf2f(u.z), bf2f(u.w));
      }
    }
    As4[i] = v;
  }
  __syncthreads();
  const int cg = tid & 31;          // columns 4*cg .. 4*cg+3
  const int rbase = (tid >> 5) * 8; // 8 rows per thread
  float acc[8][4];
  #pragma unroll
  for (int r = 0; r < 8; ++r)
    #pragma unroll
    for (int j = 0; j < 4; ++j) acc[r][j] = 0.f;
  const float4* W4 = (const float4*)W;   // [K][32] float4 view
  for (int k0 = 0; k0 < K; k0 += 4) {
    float4 w[4];
    #pragma unroll
    for (int kk = 0; kk < 4; ++kk) w[kk] = W4[(k0 + kk) * 32 + cg];
    #pragma unroll
    for (int r = 0; r < 8; ++r) {
      float4 a = As4[(rbase + r) * K4 + (k0 >> 2)];
      const float* ap = (const float*)&a;
      #pragma unroll
      for (int kk = 0; kk < 4; ++kk) {
        acc[r][0] = fmaf(ap[kk], w[kk].x, acc[r][0]);
        acc[r][1] = fmaf(ap[kk], w[kk].y, acc[r][1]);
        acc[r][2] = fmaf(ap[kk], w[kk].z, acc[r][2]);
        acc[r][3] = fmaf(ap[kk], w[kk].w, acc[r][3]);
      }
    }
  }
  float4 bb = make_float4(0.f, 0.f, 0.f, 0.f);
  if (BIAS) bb = ((const float4*)bias)[cg];
  #pragma unroll
  for (int r = 0; r < 8; ++r) {
    int row = r0 + rbase + r;
    if (row < M) {
      float o[4];
      o[0] = acc[r][0] + bb.x; o[1] = acc[r][1] + bb.y;
      o[2] = acc[r][2] + bb.z; o[3] = acc[r][3] + bb.w;
      if (RELU) {
        #pragma unroll
        for (int j = 0; j < 4; ++j) o[j] = fmaxf(o[j], 0.f);
      }
      if constexpr (sizeof(TC) == 4) {
        ((float4*)C)[(size_t)row * 32 + cg] = make_float4(o[0], o[1], o[2], o[3]);
      } else {
        ushort4 u;
        u.x = f2bf(o[0]); u.y = f2bf(o[1]); u.z = f2bf(o[2]); u.w = f2bf(o[3]);
        ((ushort4*)C)[(size_t)row * 32 + cg] = u;
      }
    }
  }
}

// ---------------- GCN aggregation + residual update (one wave per node) ----------------
// x[i] += relu( dinv[i]*( sum_{e: dst=i} xw[src]*dinv[src] + xw[i]*dinv[i] ) + bias )
// xw is bf16 [N][128].
__global__ __launch_bounds__(256) void agg_update_kernel(
    const ushort* __restrict__ xw, float* __restrict__ x,
    const int* __restrict__ csr_src, const int* __restrict__ offs,
    const float* __restrict__ dinv, const float* __restrict__ bias, int n) {
  int node = blockIdx.x * 4 + (threadIdx.x >> 6);
  if (node >= n) return;
  int lane = threadIdx.x & 63;
  const ushort2* xw2 = (const ushort2*)xw;   // row stride 64 (128 bf16)
  float accx = 0.f, accy = 0.f;
  int beg = offs[node], end = offs[node + 1];
  int j = beg;
  for (; j + 1 < end; j += 2) {
    int s0 = csr_src[j];
    int s1 = csr_src[j + 1];
    float w0 = dinv[s0];
    float w1 = dinv[s1];
    ushort2 v0 = xw2[(size_t)s0 * 64 + lane];
    ushort2 v1 = xw2[(size_t)s1 * 64 + lane];
    accx = fmaf(bf2f(v0.x), w0, accx); accy = fmaf(bf2f(v0.y), w0, accy);
    accx = fmaf(bf2f(v1.x), w1, accx); accy = fmaf(bf2f(v1.y), w1, accy);
  }
  if (j < end) {
    int s0 = csr_src[j];
    float w0 = dinv[s0];
    ushort2 v0 = xw2[(size_t)s0 * 64 + lane];
    accx = fmaf(bf2f(v0.x), w0, accx); accy = fmaf(bf2f(v0.y), w0, accy);
  }
  float di = dinv[node];
  ushort2 vi = xw2[(size_t)node * 64 + lane];
  accx = fmaf(bf2f(vi.x), di, accx);
  accy = fmaf(bf2f(vi.y), di, accy);
  float2 bb = ((const float2*)bias)[lane];
  float2* x2 = (float2*)x;
  float2 xv = x2[(size_t)node * 64 + lane];
  float2 o;
  o.x = fmaxf(fmaf(accx, di, bb.x), 0.f) + xv.x;
  o.y = fmaxf(fmaf(accy, di, bb.y), 0.f) + xv.y;
  x2[(size_t)node * 64 + lane] = o;
}

// ---------------- graph boundaries from sorted batch ----------------
__global__ void bounds_kernel(const int* __restrict__ batch, int* __restrict__ startg,
                              int n, int ng) {
  int i = blockIdx.x * blockDim.x + threadIdx.x;
  if (i > n) return;
  int bi = (i < n) ? batch[i] : ng;
  int bp = (i == 0) ? -1 : batch[i - 1];
  for (int g = bp + 1; g <= bi && g <= ng; ++g) startg[g] = i;
}

// ---------------- per-graph mean/max pooling: 2-stage ----------------
__global__ __launch_bounds__(128) void pool_partial_kernel(const float* __restrict__ x,
    const int* __restrict__ startg, float* __restrict__ psum, float* __restrict__ pmax) {
  int g = blockIdx.x / PCH, ch = blockIdx.x % PCH, c = threadIdx.x;
  int s0 = startg[g], s1 = startg[g + 1];
  int cnt = s1 - s0;
  int len = (cnt + PCH - 1) / PCH;
  int lo = s0 + ch * len;
  int hi = lo + len; if (hi > s1) hi = s1;
  float sum = 0.f, mx = -INFINITY;
  for (int r = lo; r < hi; ++r) {
    float v = x[(size_t)r * HD + c];
    sum += v;
    mx = fmaxf(mx, v);
  }
  psum[(size_t)blockIdx.x * HD + c] = sum;
  pmax[(size_t)blockIdx.x * HD + c] = mx;
}

__global__ __launch_bounds__(128) void pool_final_kernel(const float* __restrict__ psum,
    const float* __restrict__ pmax, const int* __restrict__ startg,
    float* __restrict__ repr) {
  int g = blockIdx.x, c = threadIdx.x;
  float sum = 0.f, mx = -INFINITY;
  #pragma unroll
  for (int ch = 0; ch < PCH; ++ch) {
    sum += psum[(size_t)(g * PCH + ch) * HD + c];
    mx = fmaxf(mx, pmax[(size_t)(g * PCH + ch) * HD + c]);
  }
  int cnt = startg[g + 1] - startg[g];
  float denom = (float)(cnt > 0 ? cnt : 1);
  repr[g * 256 + c] = sum / denom;
  repr[g * 256 + 128 + c] = mx;
}

// ---------------- decoder + value heads (one block per graph) ----------------
__global__ __launch_bounds__(128) void heads_kernel(
    const float* __restrict__ repr,
    const float* __restrict__ dw1, const float* __restrict__ db1,
    const float* __restrict__ dw2, const float* __restrict__ db2,
    const float* __restrict__ dw3, const float* __restrict__ db3,
    const float* __restrict__ vw1, const float* __restrict__ vb1,
    const float* __restrict__ vw2, const float* __restrict__ vb2,
    float* __restrict__ out, int ng) {
  __shared__ float rep[256];
  __shared__ float h1[128];
  __shared__ float h2[64];
  __shared__ float v1[128];
  int g = blockIdx.x, t = threadIdx.x;
  rep[t] = repr[g * 256 + t];
  rep[128 + t] = repr[g * 256 + 128 + t];
  __syncthreads();
  float a = db1[t], b = vb1[t];
  for (int k = 0; k < 256; ++k) {
    float rv = rep[k];
    a = fmaf(rv, dw1[k * 128 + t], a);
    b = fmaf(rv, vw1[k * 128 + t], b);
  }
  h1[t] = fmaxf(a, 0.f);
  v1[t] = fmaxf(b, 0.f);
  __syncthreads();
  if (t < 64) {
    float c = db2[t];
    for (int k = 0; k < 128; ++k) c = fmaf(h1[k], dw2[k * 64 + t], c);
    h2[t] = fmaxf(c, 0.f);
  }
  __syncthreads();
  if (t == 0) {
    float l0 = db3[0], l2 = db3[2];
    for (int k = 0; k < 64; ++k) {
      l0 = fmaf(h2[k], dw3[k * 3 + 0], l0);
      l2 = fmaf(h2[k], dw3[k * 3 + 2], l2);
    }
    out[g] = 1.f / (1.f + expf(-l0));          // adaptation_prob
    out[ng + g] = 1.0f;                        // softmax over 1 element == 1
    out[2 * ng + g] = 1.f / (1.f + expf(-l2)); // urgency_score
    float v = vb2[0];
    for (int k = 0; k < 128; ++k) v = fmaf(v1[k], vw2[k], v);
    out[3 * ng + g] = v;                       // value_estimate
  }
}

// ---------------- launch ----------------
extern "C" void kernel_launch(void* const* d_in, const int* in_sizes, int n_in,
                              void* d_out, int out_size, void* d_ws, size_t ws_size,
                              hipStream_t stream) {
  const float* nf     = (const float*)d_in[0];
  const int*   ei     = (const int*)d_in[1];
  const int*   batch  = (const int*)d_in[2];
  const float* enc_w1 = (const float*)d_in[3];
  const float* enc_b1 = (const float*)d_in[4];
  const float* enc_w2 = (const float*)d_in[5];
  const float* enc_b2 = (const float*)d_in[6];
  const float* gcn_w  = (const float*)d_in[7];
  const float* gcn_b  = (const float*)d_in[8];
  const float* dec_w1 = (const float*)d_in[9];
  const float* dec_b1 = (const float*)d_in[10];
  const float* dec_w2 = (const float*)d_in[11];
  const float* dec_b2 = (const float*)d_in[12];
  const float* dec_w3 = (const float*)d_in[13];
  const float* dec_b3 = (const float*)d_in[14];
  const float* val_w1 = (const float*)d_in[15];
  const float* val_b1 = (const float*)d_in[16];
  const float* val_w2 = (const float*)d_in[17];
  const float* val_b2 = (const float*)d_in[18];
  float* out = (float*)d_out;

  const int n = in_sizes[0] / FD;           // 100000
  const int e = in_sizes[1] / 2;            // 1600000
  const int L = in_sizes[7] / (HD * HD);    // 3
  const int G = out_size / 4;               // 64

  // workspace carve
  char* p = (char*)d_ws;
  auto carve = [&](size_t bytes) {
    void* r = (void*)p;
    p += (bytes + 255) & ~(size_t)255;
    return r;
  };
  float*  x       = (float*)carve((size_t)n * HD * 4);
  ushort* xwb     = (ushort*)carve((size_t)n * HD * 2);   // bf16 xw
  float*  dinv    = (float*)carve((size_t)n * 4);
  int*    deg     = (int*)carve((size_t)n * 4);
  int*    offs    = (int*)carve((size_t)(n + 1) * 4);
  int*    cursor  = (int*)carve((size_t)n * 4);
  int*    csr_src = (int*)carve((size_t)e * 4);
  float*  repr    = (float*)carve((size_t)G * 256 * 4);
  int*    startg  = (int*)carve((size_t)(G + 1) * 4);
  const int nb    = (n + 1023) / 1024;
  int*    partial = (int*)carve((size_t)nb * 4);
  int*    pref    = (int*)carve((size_t)(nb + 1) * 4);
  float*  psum    = (float*)carve((size_t)G * PCH * HD * 4);
  float*  pmax    = (float*)carve((size_t)G * PCH * HD * 4);

  const int gemm_grid = (n + 31) / 32;

  // graph structure (reused across layers)
  zero_int_kernel<<<(n + 255) / 256, 256, 0, stream>>>(deg, n);
  count_deg_kernel<<<(e + 255) / 256, 256, 0, stream>>>(ei + e, deg, e);
  dinv_kernel<<<(n + 255) / 256, 256, 0, stream>>>(deg, dinv, n);
  deg_reduce_kernel<<<nb, 256, 0, stream>>>(deg, partial, n);
  partial_scan_kernel<<<1, 128, 0, stream>>>(partial, pref, nb);
  offs_fill_kernel<<<nb, 256, 0, stream>>>(deg, pref, offs, cursor, n, nb);
  fill_csr_kernel<<<(e + 255) / 256, 256, 0, stream>>>(ei, ei + e, cursor, csr_src, e);

  // encoder: nf @ w1 -> relu (bf16 tmp), tmp @ w2 -> x (f32)
  gemm_aw_kernel<float, ushort, FD, true, true><<<gemm_grid, 128, 0, stream>>>(
      nf, enc_w1, enc_b1, xwb, n);
  gemm_aw_kernel<ushort, float, HD, true, false><<<gemm_grid, 128, 0, stream>>>(
      xwb, enc_w2, enc_b2, x, n);

  // GCN layers
  for (int l = 0; l < L; ++l) {
    gemm_aw_kernel<float, ushort, HD, false, false><<<gemm_grid, 128, 0, stream>>>(
        x, gcn_w + (size_t)l * HD * HD, nullptr, xwb, n);
    agg_update_kernel<<<(n + 3) / 4, 256, 0, stream>>>(
        xwb, x, csr_src, offs, dinv, gcn_b + (size_t)l * HD, n);
  }

  // pooling + heads
  bounds_kernel<<<(n + 1 + 255) / 256, 256, 0, stream>>>(batch, startg, n, G);
  pool_partial_kernel<<<G * PCH, 128, 0, stream>>>(x, startg, psum, pmax);
  pool_final_kernel<<<G, 128, 0, stream>>>(psum, pmax, startg, repr);
  heads_kernel<<<G, 128, 0, stream>>>(repr,
      dec_w1, dec_b1, dec_w2, dec_b2, dec_w3, dec_b3,
      val_w1, val_b1, val_w2, val_b2, out, G);
}

// Round 4
// 752.000 us; speedup vs baseline: 1.5573x; 1.1032x over previous
//
#include <hip/hip_runtime.h>
#include <math.h>

constexpr int HD = 128;   // hidden dim
constexpr int FD = 64;    // input feature dim
constexpr int PCH = 8;    // pooling chunks per graph
constexpr int BKT_SHIFT = 8;           // 256 nodes per bucket
constexpr int EPB = 8192;              // edges per block in bucket passes

typedef unsigned int uint;
typedef unsigned short ushort;

static __device__ inline ushort f2bf(float f) {   // round-to-nearest-even bf16
  uint u = __float_as_uint(f);
  return (ushort)((u + 0x7fffu + ((u >> 16) & 1u)) >> 16);
}
static __device__ inline float bf2f(ushort b) {
  return __uint_as_float((uint)b << 16);
}

// ---------------- utility kernels ----------------
__global__ void zero_int_kernel(int* __restrict__ p, int n) {
  int i = blockIdx.x * blockDim.x + threadIdx.x;
  if (i < n) p[i] = 0;
}

__global__ void count_deg_kernel(const int* __restrict__ dst, int* __restrict__ deg, int e) {
  int i = blockIdx.x * blockDim.x + threadIdx.x;
  if (i < e) atomicAdd(&deg[dst[i]], 1);
}

__global__ void dinv_kernel(const int* __restrict__ deg, float* __restrict__ dinv, int n) {
  int i = blockIdx.x * blockDim.x + threadIdx.x;
  if (i < n) dinv[i] = rsqrtf((float)(deg[i] + 1));   // +1: self-loop
}

// ---------------- hierarchical scan over deg -> offs ----------------
__global__ __launch_bounds__(256) void deg_reduce_kernel(const int* __restrict__ deg,
    int* __restrict__ partial, int n) {
  __shared__ int sh[256];
  int b = blockIdx.x, t = threadIdx.x;
  int base = b * 1024 + t * 4;
  int s = 0;
  #pragma unroll
  for (int k = 0; k < 4; ++k) { int i = base + k; if (i < n) s += deg[i]; }
  sh[t] = s;
  __syncthreads();
  for (int d = 128; d > 0; d >>= 1) {
    if (t < d) sh[t] += sh[t + d];
    __syncthreads();
  }
  if (t == 0) partial[b] = sh[0];
}

__global__ __launch_bounds__(128) void partial_scan_kernel(const int* __restrict__ partial,
    int* __restrict__ pref, int nb) {
  __shared__ int sh[128];
  int t = threadIdx.x;
  int v = (t < nb) ? partial[t] : 0;
  sh[t] = v;
  __syncthreads();
  for (int d = 1; d < 128; d <<= 1) {
    int u = (t >= d) ? sh[t - d] : 0;
    __syncthreads();
    sh[t] += u;
    __syncthreads();
  }
  if (t < nb) pref[t] = sh[t] - v;          // exclusive prefix
  if (t == 127) pref[nb] = sh[127];         // total
}

__global__ __launch_bounds__(256) void offs_fill_kernel(const int* __restrict__ deg,
    const int* __restrict__ pref, int* __restrict__ offs, int n, int nb) {
  __shared__ int sh[256];
  int b = blockIdx.x, t = threadIdx.x;
  int base = b * 1024 + t * 4;
  int d[4]; int s = 0;
  #pragma unroll
  for (int k = 0; k < 4; ++k) {
    int i = base + k;
    d[k] = (i < n) ? deg[i] : 0;
    s += d[k];
  }
  sh[t] = s;
  __syncthreads();
  for (int dd = 1; dd < 256; dd <<= 1) {
    int u = (t >= dd) ? sh[t - dd] : 0;
    __syncthreads();
    sh[t] += u;
    __syncthreads();
  }
  int run = pref[b] + sh[t] - s;
  #pragma unroll
  for (int k = 0; k < 4; ++k) {
    int i = base + k;
    if (i < n) offs[i] = run;
    run += d[k];
  }
  if (b == 0 && t == 0) offs[n] = pref[nb];
}

// ---------------- bucketed CSR build ----------------
// pass 1: per-block LDS histogram of dst>>BKT_SHIFT -> global bucket_count
__global__ __launch_bounds__(256) void bucket_count_kernel(const int* __restrict__ dst,
    int* __restrict__ bucket_count, int e, int nbk) {
  __shared__ int hist[512];
  int t = threadIdx.x;
  for (int i = t; i < nbk; i += 256) hist[i] = 0;
  __syncthreads();
  int lo = blockIdx.x * EPB;
  int hi = lo + EPB; if (hi > e) hi = e;
  for (int i = lo + t; i < hi; i += 256) atomicAdd(&hist[dst[i] >> BKT_SHIFT], 1);
  __syncthreads();
  for (int i = t; i < nbk; i += 256) {
    int c = hist[i];
    if (c) atomicAdd(&bucket_count[i], c);
  }
}

// scan bucket_count -> bucket_base (exclusive, +total), copy to bucket_cursor
__global__ __launch_bounds__(512) void bucket_scan_kernel(const int* __restrict__ bucket_count,
    int* __restrict__ bucket_base, int* __restrict__ bucket_cursor, int nbk) {
  __shared__ int sh[512];
  int t = threadIdx.x;
  int v = (t < nbk) ? bucket_count[t] : 0;
  sh[t] = v;
  __syncthreads();
  for (int d = 1; d < 512; d <<= 1) {
    int u = (t >= d) ? sh[t - d] : 0;
    __syncthreads();
    sh[t] += u;
    __syncthreads();
  }
  if (t < nbk) {
    int ex = sh[t] - v;
    bucket_base[t] = ex;
    bucket_cursor[t] = ex;
  }
  if (t == 511) bucket_base[nbk] = sh[511];
}

// pass 2: distribute (src,dst) pairs into bucket-grouped array
__global__ __launch_bounds__(256) void bucket_fill_kernel(const int* __restrict__ src,
    const int* __restrict__ dst, int* __restrict__ bucket_cursor,
    int2* __restrict__ pairs, int e, int nbk) {
  __shared__ int hist[512];
  int t = threadIdx.x;
  for (int i = t; i < nbk; i += 256) hist[i] = 0;
  __syncthreads();
  int lo = blockIdx.x * EPB;
  int hi = lo + EPB; if (hi > e) hi = e;
  for (int i = lo + t; i < hi; i += 256) atomicAdd(&hist[dst[i] >> BKT_SHIFT], 1);
  __syncthreads();
  for (int i = t; i < nbk; i += 256) {
    int c = hist[i];
    hist[i] = c ? atomicAdd(&bucket_cursor[i], c) : 0;   // hist now = write cursor
  }
  __syncthreads();
  for (int i = lo + t; i < hi; i += 256) {
    int s = src[i], d = dst[i];
    int pos = atomicAdd(&hist[d >> BKT_SHIFT], 1);
    pairs[pos] = make_int2(s, d);
  }
}

// pass 3: one block per bucket; per-node LDS cursors; local scatter into csr_src
__global__ __launch_bounds__(256) void bucket_scatter_kernel(const int2* __restrict__ pairs,
    const int* __restrict__ bucket_base, const int* __restrict__ offs,
    int* __restrict__ csr_src, int n, int nbk) {
  __shared__ int cur[1 << BKT_SHIFT];
  int b = blockIdx.x, t = threadIdx.x;
  int node0 = b << BKT_SHIFT;
  int nn = n - node0; if (nn > (1 << BKT_SHIFT)) nn = 1 << BKT_SHIFT;
  if (t < nn) cur[t] = offs[node0 + t];
  __syncthreads();
  int lo = bucket_base[b], hi = bucket_base[b + 1];
  for (int i = lo + t; i < hi; i += 256) {
    int2 p = pairs[i];
    int pos = atomicAdd(&cur[p.y - node0], 1);
    csr_src[pos] = p.x;
  }
}

// ---------------- f32-math GEMM: C[M x 128] = A[M x K] @ W[K x 128] (+bias)(+relu) ----
template<typename TA, typename TC, int K, bool BIAS, bool RELU>
__global__ __launch_bounds__(128) void gemm_aw_kernel(const TA* __restrict__ A,
    const float* __restrict__ W, const float* __restrict__ bias,
    TC* __restrict__ C, int M) {
  constexpr int K4 = K / 4;
  __shared__ float4 As4[32 * K4];
  const int tid = threadIdx.x;
  const int r0 = blockIdx.x * 32;
  #pragma unroll
  for (int i = tid; i < 32 * K4; i += 128) {
    int r = i / K4, kk = i - r * K4;
    int row = r0 + r;
    float4 v = make_float4(0.f, 0.f, 0.f, 0.f);
    if (row < M) {
      if constexpr (sizeof(TA) == 4) {
        v = ((const float4*)A)[(size_t)row * K4 + kk];
      } else {
        ushort4 u = ((const ushort4*)A)[(size_t)row * K4 + kk];
        v = make_float4(bf2f(u.x), bf2f(u.y), bf2f(u.z), bf2f(u.w));
      }
    }
    As4[i] = v;
  }
  __syncthreads();
  const int cg = tid & 31;          // columns 4*cg .. 4*cg+3
  const int rbase = (tid >> 5) * 8; // 8 rows per thread
  float acc[8][4];
  #pragma unroll
  for (int r = 0; r < 8; ++r)
    #pragma unroll
    for (int j = 0; j < 4; ++j) acc[r][j] = 0.f;
  const float4* W4 = (const float4*)W;   // [K][32] float4 view
  for (int k0 = 0; k0 < K; k0 += 4) {
    float4 w[4];
    #pragma unroll
    for (int kk = 0; kk < 4; ++kk) w[kk] = W4[(k0 + kk) * 32 + cg];
    #pragma unroll
    for (int r = 0; r < 8; ++r) {
      float4 a = As4[(rbase + r) * K4 + (k0 >> 2)];
      const float* ap = (const float*)&a;
      #pragma unroll
      for (int kk = 0; kk < 4; ++kk) {
        acc[r][0] = fmaf(ap[kk], w[kk].x, acc[r][0]);
        acc[r][1] = fmaf(ap[kk], w[kk].y, acc[r][1]);
        acc[r][2] = fmaf(ap[kk], w[kk].z, acc[r][2]);
        acc[r][3] = fmaf(ap[kk], w[kk].w, acc[r][3]);
      }
    }
  }
  float4 bb = make_float4(0.f, 0.f, 0.f, 0.f);
  if (BIAS) bb = ((const float4*)bias)[cg];
  #pragma unroll
  for (int r = 0; r < 8; ++r) {
    int row = r0 + rbase + r;
    if (row < M) {
      float o[4];
      o[0] = acc[r][0] + bb.x; o[1] = acc[r][1] + bb.y;
      o[2] = acc[r][2] + bb.z; o[3] = acc[r][3] + bb.w;
      if (RELU) {
        #pragma unroll
        for (int j = 0; j < 4; ++j) o[j] = fmaxf(o[j], 0.f);
      }
      if constexpr (sizeof(TC) == 4) {
        ((float4*)C)[(size_t)row * 32 + cg] = make_float4(o[0], o[1], o[2], o[3]);
      } else {
        ushort4 u;
        u.x = f2bf(o[0]); u.y = f2bf(o[1]); u.z = f2bf(o[2]); u.w = f2bf(o[3]);
        ((ushort4*)C)[(size_t)row * 32 + cg] = u;
      }
    }
  }
}

// ---------------- GCN aggregation + residual update (one wave per node) ----------------
__global__ __launch_bounds__(256) void agg_update_kernel(
    const ushort* __restrict__ xw, float* __restrict__ x,
    const int* __restrict__ csr_src, const int* __restrict__ offs,
    const float* __restrict__ dinv, const float* __restrict__ bias, int n) {
  int node = blockIdx.x * 4 + (threadIdx.x >> 6);
  if (node >= n) return;
  int lane = threadIdx.x & 63;
  const ushort2* xw2 = (const ushort2*)xw;   // row stride 64 (128 bf16)
  float accx = 0.f, accy = 0.f;
  int beg = offs[node], end = offs[node + 1];
  int j = beg;
  for (; j + 1 < end; j += 2) {
    int s0 = csr_src[j];
    int s1 = csr_src[j + 1];
    float w0 = dinv[s0];
    float w1 = dinv[s1];
    ushort2 v0 = xw2[(size_t)s0 * 64 + lane];
    ushort2 v1 = xw2[(size_t)s1 * 64 + lane];
    accx = fmaf(bf2f(v0.x), w0, accx); accy = fmaf(bf2f(v0.y), w0, accy);
    accx = fmaf(bf2f(v1.x), w1, accx); accy = fmaf(bf2f(v1.y), w1, accy);
  }
  if (j < end) {
    int s0 = csr_src[j];
    float w0 = dinv[s0];
    ushort2 v0 = xw2[(size_t)s0 * 64 + lane];
    accx = fmaf(bf2f(v0.x), w0, accx); accy = fmaf(bf2f(v0.y), w0, accy);
  }
  float di = dinv[node];
  ushort2 vi = xw2[(size_t)node * 64 + lane];
  accx = fmaf(bf2f(vi.x), di, accx);
  accy = fmaf(bf2f(vi.y), di, accy);
  float2 bb = ((const float2*)bias)[lane];
  float2* x2 = (float2*)x;
  float2 xv = x2[(size_t)node * 64 + lane];
  float2 o;
  o.x = fmaxf(fmaf(accx, di, bb.x), 0.f) + xv.x;
  o.y = fmaxf(fmaf(accy, di, bb.y), 0.f) + xv.y;
  x2[(size_t)node * 64 + lane] = o;
}

// ---------------- graph boundaries from sorted batch ----------------
__global__ void bounds_kernel(const int* __restrict__ batch, int* __restrict__ startg,
                              int n, int ng) {
  int i = blockIdx.x * blockDim.x + threadIdx.x;
  if (i > n) return;
  int bi = (i < n) ? batch[i] : ng;
  int bp = (i == 0) ? -1 : batch[i - 1];
  for (int g = bp + 1; g <= bi && g <= ng; ++g) startg[g] = i;
}

// ---------------- per-graph mean/max pooling: 2-stage ----------------
__global__ __launch_bounds__(128) void pool_partial_kernel(const float* __restrict__ x,
    const int* __restrict__ startg, float* __restrict__ psum, float* __restrict__ pmax) {
  int g = blockIdx.x / PCH, ch = blockIdx.x % PCH, c = threadIdx.x;
  int s0 = startg[g], s1 = startg[g + 1];
  int cnt = s1 - s0;
  int len = (cnt + PCH - 1) / PCH;
  int lo = s0 + ch * len;
  int hi = lo + len; if (hi > s1) hi = s1;
  float sum = 0.f, mx = -INFINITY;
  for (int r = lo; r < hi; ++r) {
    float v = x[(size_t)r * HD + c];
    sum += v;
    mx = fmaxf(mx, v);
  }
  psum[(size_t)blockIdx.x * HD + c] = sum;
  pmax[(size_t)blockIdx.x * HD + c] = mx;
}

__global__ __launch_bounds__(128) void pool_final_kernel(const float* __restrict__ psum,
    const float* __restrict__ pmax, const int* __restrict__ startg,
    float* __restrict__ repr) {
  int g = blockIdx.x, c = threadIdx.x;
  float sum = 0.f, mx = -INFINITY;
  #pragma unroll
  for (int ch = 0; ch < PCH; ++ch) {
    sum += psum[(size_t)(g * PCH + ch) * HD + c];
    mx = fmaxf(mx, pmax[(size_t)(g * PCH + ch) * HD + c]);
  }
  int cnt = startg[g + 1] - startg[g];
  float denom = (float)(cnt > 0 ? cnt : 1);
  repr[g * 256 + c] = sum / denom;
  repr[g * 256 + 128 + c] = mx;
}

// ---------------- decoder + value heads (one block per graph) ----------------
__global__ __launch_bounds__(128) void heads_kernel(
    const float* __restrict__ repr,
    const float* __restrict__ dw1, const float* __restrict__ db1,
    const float* __restrict__ dw2, const float* __restrict__ db2,
    const float* __restrict__ dw3, const float* __restrict__ db3,
    const float* __restrict__ vw1, const float* __restrict__ vb1,
    const float* __restrict__ vw2, const float* __restrict__ vb2,
    float* __restrict__ out, int ng) {
  __shared__ float rep[256];
  __shared__ float h1[128];
  __shared__ float h2[64];
  __shared__ float v1[128];
  int g = blockIdx.x, t = threadIdx.x;
  rep[t] = repr[g * 256 + t];
  rep[128 + t] = repr[g * 256 + 128 + t];
  __syncthreads();
  float a = db1[t], b = vb1[t];
  for (int k = 0; k < 256; ++k) {
    float rv = rep[k];
    a = fmaf(rv, dw1[k * 128 + t], a);
    b = fmaf(rv, vw1[k * 128 + t], b);
  }
  h1[t] = fmaxf(a, 0.f);
  v1[t] = fmaxf(b, 0.f);
  __syncthreads();
  if (t < 64) {
    float c = db2[t];
    for (int k = 0; k < 128; ++k) c = fmaf(h1[k], dw2[k * 64 + t], c);
    h2[t] = fmaxf(c, 0.f);
  }
  __syncthreads();
  if (t == 0) {
    float l0 = db3[0], l2 = db3[2];
    for (int k = 0; k < 64; ++k) {
      l0 = fmaf(h2[k], dw3[k * 3 + 0], l0);
      l2 = fmaf(h2[k], dw3[k * 3 + 2], l2);
    }
    out[g] = 1.f / (1.f + expf(-l0));          // adaptation_prob
    out[ng + g] = 1.0f;                        // softmax over 1 element == 1
    out[2 * ng + g] = 1.f / (1.f + expf(-l2)); // urgency_score
    float v = vb2[0];
    for (int k = 0; k < 128; ++k) v = fmaf(v1[k], vw2[k], v);
    out[3 * ng + g] = v;                       // value_estimate
  }
}

// ---------------- launch ----------------
extern "C" void kernel_launch(void* const* d_in, const int* in_sizes, int n_in,
                              void* d_out, int out_size, void* d_ws, size_t ws_size,
                              hipStream_t stream) {
  const float* nf     = (const float*)d_in[0];
  const int*   ei     = (const int*)d_in[1];
  const int*   batch  = (const int*)d_in[2];
  const float* enc_w1 = (const float*)d_in[3];
  const float* enc_b1 = (const float*)d_in[4];
  const float* enc_w2 = (const float*)d_in[5];
  const float* enc_b2 = (const float*)d_in[6];
  const float* gcn_w  = (const float*)d_in[7];
  const float* gcn_b  = (const float*)d_in[8];
  const float* dec_w1 = (const float*)d_in[9];
  const float* dec_b1 = (const float*)d_in[10];
  const float* dec_w2 = (const float*)d_in[11];
  const float* dec_b2 = (const float*)d_in[12];
  const float* dec_w3 = (const float*)d_in[13];
  const float* dec_b3 = (const float*)d_in[14];
  const float* val_w1 = (const float*)d_in[15];
  const float* val_b1 = (const float*)d_in[16];
  const float* val_w2 = (const float*)d_in[17];
  const float* val_b2 = (const float*)d_in[18];
  float* out = (float*)d_out;

  const int n = in_sizes[0] / FD;           // 100000
  const int e = in_sizes[1] / 2;            // 1600000
  const int L = in_sizes[7] / (HD * HD);    // 3
  const int G = out_size / 4;               // 64

  // workspace carve
  char* p = (char*)d_ws;
  auto carve = [&](size_t bytes) {
    void* r = (void*)p;
    p += (bytes + 255) & ~(size_t)255;
    return r;
  };
  float*  x       = (float*)carve((size_t)n * HD * 4);
  ushort* xwb     = (ushort*)carve((size_t)n * HD * 2);   // bf16 xw
  float*  dinv    = (float*)carve((size_t)n * 4);
  int*    deg     = (int*)carve((size_t)n * 4);
  int*    offs    = (int*)carve((size_t)(n + 1) * 4);
  int*    csr_src = (int*)carve((size_t)e * 4);
  float*  repr    = (float*)carve((size_t)G * 256 * 4);
  int*    startg  = (int*)carve((size_t)(G + 1) * 4);
  const int nb    = (n + 1023) / 1024;
  int*    partial = (int*)carve((size_t)nb * 4);
  int*    pref    = (int*)carve((size_t)(nb + 1) * 4);
  float*  psum    = (float*)carve((size_t)G * PCH * HD * 4);
  float*  pmax    = (float*)carve((size_t)G * PCH * HD * 4);
  const int nbk   = (n + (1 << BKT_SHIFT) - 1) >> BKT_SHIFT;   // 391 buckets
  int*    bucket_count  = (int*)carve((size_t)nbk * 4);
  int*    bucket_base   = (int*)carve((size_t)(nbk + 1) * 4);
  int*    bucket_cursor = (int*)carve((size_t)nbk * 4);
  // pairs aliases xwb: CSR build completes before enc1 writes xwb (stream-ordered)
  int2*   pairs   = (int2*)xwb;

  const int gemm_grid = (n + 31) / 32;
  const int ebk_grid = (e + EPB - 1) / EPB;

  // ---- graph structure (before encoder so pairs can alias xwb) ----
  zero_int_kernel<<<(n + 255) / 256, 256, 0, stream>>>(deg, n);
  zero_int_kernel<<<(nbk + 255) / 256, 256, 0, stream>>>(bucket_count, nbk);
  count_deg_kernel<<<(e + 255) / 256, 256, 0, stream>>>(ei + e, deg, e);
  dinv_kernel<<<(n + 255) / 256, 256, 0, stream>>>(deg, dinv, n);
  deg_reduce_kernel<<<nb, 256, 0, stream>>>(deg, partial, n);
  partial_scan_kernel<<<1, 128, 0, stream>>>(partial, pref, nb);
  offs_fill_kernel<<<nb, 256, 0, stream>>>(deg, pref, offs, n, nb);
  bucket_count_kernel<<<ebk_grid, 256, 0, stream>>>(ei + e, bucket_count, e, nbk);
  bucket_scan_kernel<<<1, 512, 0, stream>>>(bucket_count, bucket_base, bucket_cursor, nbk);
  bucket_fill_kernel<<<ebk_grid, 256, 0, stream>>>(ei, ei + e, bucket_cursor, pairs, e, nbk);
  bucket_scatter_kernel<<<nbk, 256, 0, stream>>>(pairs, bucket_base, offs, csr_src, n, nbk);

  // ---- encoder: nf @ w1 -> relu (bf16 tmp), tmp @ w2 -> x (f32) ----
  gemm_aw_kernel<float, ushort, FD, true, true><<<gemm_grid, 128, 0, stream>>>(
      nf, enc_w1, enc_b1, xwb, n);
  gemm_aw_kernel<ushort, float, HD, true, false><<<gemm_grid, 128, 0, stream>>>(
      xwb, enc_w2, enc_b2, x, n);

  // ---- GCN layers ----
  for (int l = 0; l < L; ++l) {
    gemm_aw_kernel<float, ushort, HD, false, false><<<gemm_grid, 128, 0, stream>>>(
        x, gcn_w + (size_t)l * HD * HD, nullptr, xwb, n);
    agg_update_kernel<<<(n + 3) / 4, 256, 0, stream>>>(
        xwb, x, csr_src, offs, dinv, gcn_b + (size_t)l * HD, n);
  }

  // ---- pooling + heads ----
  bounds_kernel<<<(n + 1 + 255) / 256, 256, 0, stream>>>(batch, startg, n, G);
  pool_partial_kernel<<<G * PCH, 128, 0, stream>>>(x, startg, psum, pmax);
  pool_final_kernel<<<G, 128, 0, stream>>>(psum, pmax, startg, repr);
  heads_kernel<<<G, 128, 0, stream>>>(repr,
      dec_w1, dec_b1, dec_w2, dec_b2, dec_w3, dec_b3,
      val_w1, val_b1, val_w2, val_b2, out, G);
}

// Round 5
// 665.457 us; speedup vs baseline: 1.7598x; 1.1300x over previous
//
#include <hip/hip_runtime.h>
#include <math.h>

constexpr int HD = 128;   // hidden dim
constexpr int FD = 64;    // input feature dim
constexpr int PCH = 8;    // pooling chunks per graph
constexpr int BKT_SHIFT = 8;           // 256 nodes per bucket
constexpr int EPB = 8192;              // edges per block in bucket passes

typedef unsigned int uint;
typedef unsigned short ushort;

static __device__ inline ushort f2bf(float f) {   // round-to-nearest-even bf16
  uint u = __float_as_uint(f);
  return (ushort)((u + 0x7fffu + ((u >> 16) & 1u)) >> 16);
}
static __device__ inline float bf2f(ushort b) {
  return __uint_as_float((uint)b << 16);
}

// ---------------- utility kernels ----------------
__global__ void zero_int_kernel(int* __restrict__ p, int n) {
  int i = blockIdx.x * blockDim.x + threadIdx.x;
  if (i < n) p[i] = 0;
}

__global__ void count_deg_kernel(const int* __restrict__ dst, int* __restrict__ deg, int e) {
  int i = blockIdx.x * blockDim.x + threadIdx.x;
  if (i < e) atomicAdd(&deg[dst[i]], 1);
}

__global__ void dinv_kernel(const int* __restrict__ deg, float* __restrict__ dinv, int n) {
  int i = blockIdx.x * blockDim.x + threadIdx.x;
  if (i < n) dinv[i] = rsqrtf((float)(deg[i] + 1));   // +1: self-loop
}

// ---------------- hierarchical scan over deg -> offs ----------------
__global__ __launch_bounds__(256) void deg_reduce_kernel(const int* __restrict__ deg,
    int* __restrict__ partial, int n) {
  __shared__ int sh[256];
  int b = blockIdx.x, t = threadIdx.x;
  int base = b * 1024 + t * 4;
  int s = 0;
  #pragma unroll
  for (int k = 0; k < 4; ++k) { int i = base + k; if (i < n) s += deg[i]; }
  sh[t] = s;
  __syncthreads();
  for (int d = 128; d > 0; d >>= 1) {
    if (t < d) sh[t] += sh[t + d];
    __syncthreads();
  }
  if (t == 0) partial[b] = sh[0];
}

__global__ __launch_bounds__(128) void partial_scan_kernel(const int* __restrict__ partial,
    int* __restrict__ pref, int nb) {
  __shared__ int sh[128];
  int t = threadIdx.x;
  int v = (t < nb) ? partial[t] : 0;
  sh[t] = v;
  __syncthreads();
  for (int d = 1; d < 128; d <<= 1) {
    int u = (t >= d) ? sh[t - d] : 0;
    __syncthreads();
    sh[t] += u;
    __syncthreads();
  }
  if (t < nb) pref[t] = sh[t] - v;          // exclusive prefix
  if (t == 127) pref[nb] = sh[127];         // total
}

__global__ __launch_bounds__(256) void offs_fill_kernel(const int* __restrict__ deg,
    const int* __restrict__ pref, int* __restrict__ offs, int n, int nb) {
  __shared__ int sh[256];
  int b = blockIdx.x, t = threadIdx.x;
  int base = b * 1024 + t * 4;
  int d[4]; int s = 0;
  #pragma unroll
  for (int k = 0; k < 4; ++k) {
    int i = base + k;
    d[k] = (i < n) ? deg[i] : 0;
    s += d[k];
  }
  sh[t] = s;
  __syncthreads();
  for (int dd = 1; dd < 256; dd <<= 1) {
    int u = (t >= dd) ? sh[t - dd] : 0;
    __syncthreads();
    sh[t] += u;
    __syncthreads();
  }
  int run = pref[b] + sh[t] - s;
  #pragma unroll
  for (int k = 0; k < 4; ++k) {
    int i = base + k;
    if (i < n) offs[i] = run;
    run += d[k];
  }
  if (b == 0 && t == 0) offs[n] = pref[nb];
}

// ---------------- bucketed CSR build ----------------
__global__ __launch_bounds__(256) void bucket_count_kernel(const int* __restrict__ dst,
    int* __restrict__ bucket_count, int e, int nbk) {
  __shared__ int hist[512];
  int t = threadIdx.x;
  for (int i = t; i < nbk; i += 256) hist[i] = 0;
  __syncthreads();
  int lo = blockIdx.x * EPB;
  int hi = lo + EPB; if (hi > e) hi = e;
  for (int i = lo + t; i < hi; i += 256) atomicAdd(&hist[dst[i] >> BKT_SHIFT], 1);
  __syncthreads();
  for (int i = t; i < nbk; i += 256) {
    int c = hist[i];
    if (c) atomicAdd(&bucket_count[i], c);
  }
}

__global__ __launch_bounds__(512) void bucket_scan_kernel(const int* __restrict__ bucket_count,
    int* __restrict__ bucket_base, int* __restrict__ bucket_cursor, int nbk) {
  __shared__ int sh[512];
  int t = threadIdx.x;
  int v = (t < nbk) ? bucket_count[t] : 0;
  sh[t] = v;
  __syncthreads();
  for (int d = 1; d < 512; d <<= 1) {
    int u = (t >= d) ? sh[t - d] : 0;
    __syncthreads();
    sh[t] += u;
    __syncthreads();
  }
  if (t < nbk) {
    int ex = sh[t] - v;
    bucket_base[t] = ex;
    bucket_cursor[t] = ex;
  }
  if (t == 511) bucket_base[nbk] = sh[511];
}

__global__ __launch_bounds__(256) void bucket_fill_kernel(const int* __restrict__ src,
    const int* __restrict__ dst, int* __restrict__ bucket_cursor,
    int2* __restrict__ pairs, int e, int nbk) {
  __shared__ int hist[512];
  int t = threadIdx.x;
  for (int i = t; i < nbk; i += 256) hist[i] = 0;
  __syncthreads();
  int lo = blockIdx.x * EPB;
  int hi = lo + EPB; if (hi > e) hi = e;
  for (int i = lo + t; i < hi; i += 256) atomicAdd(&hist[dst[i] >> BKT_SHIFT], 1);
  __syncthreads();
  for (int i = t; i < nbk; i += 256) {
    int c = hist[i];
    hist[i] = c ? atomicAdd(&bucket_cursor[i], c) : 0;   // hist now = write cursor
  }
  __syncthreads();
  for (int i = lo + t; i < hi; i += 256) {
    int s = src[i], d = dst[i];
    int pos = atomicAdd(&hist[d >> BKT_SHIFT], 1);
    pairs[pos] = make_int2(s, d);
  }
}

__global__ __launch_bounds__(256) void bucket_scatter_kernel(const int2* __restrict__ pairs,
    const int* __restrict__ bucket_base, const int* __restrict__ offs,
    int* __restrict__ csr_src, int n, int nbk) {
  __shared__ int cur[1 << BKT_SHIFT];
  int b = blockIdx.x, t = threadIdx.x;
  int node0 = b << BKT_SHIFT;
  int nn = n - node0; if (nn > (1 << BKT_SHIFT)) nn = 1 << BKT_SHIFT;
  if (t < nn) cur[t] = offs[node0 + t];
  __syncthreads();
  int lo = bucket_base[b], hi = bucket_base[b + 1];
  for (int i = lo + t; i < hi; i += 256) {
    int2 p = pairs[i];
    int pos = atomicAdd(&cur[p.y - node0], 1);
    csr_src[pos] = p.x;
  }
}

// ---------------- f32-math GEMM: C[M x 128] = A[M x K] @ W[K x 128] (+bias)(+relu) ----
template<typename TA, typename TC, int K, bool BIAS, bool RELU>
__global__ __launch_bounds__(128) void gemm_aw_kernel(const TA* __restrict__ A,
    const float* __restrict__ W, const float* __restrict__ bias,
    TC* __restrict__ C, int M) {
  constexpr int K4 = K / 4;
  __shared__ float4 As4[32 * K4];
  const int tid = threadIdx.x;
  const int r0 = blockIdx.x * 32;
  #pragma unroll
  for (int i = tid; i < 32 * K4; i += 128) {
    int r = i / K4, kk = i - r * K4;
    int row = r0 + r;
    float4 v = make_float4(0.f, 0.f, 0.f, 0.f);
    if (row < M) {
      if constexpr (sizeof(TA) == 4) {
        v = ((const float4*)A)[(size_t)row * K4 + kk];
      } else {
        ushort4 u = ((const ushort4*)A)[(size_t)row * K4 + kk];
        v = make_float4(bf2f(u.x), bf2f(u.y), bf2f(u.z), bf2f(u.w));
      }
    }
    As4[i] = v;
  }
  __syncthreads();
  const int cg = tid & 31;          // columns 4*cg .. 4*cg+3
  const int rbase = (tid >> 5) * 8; // 8 rows per thread
  float acc[8][4];
  #pragma unroll
  for (int r = 0; r < 8; ++r)
    #pragma unroll
    for (int j = 0; j < 4; ++j) acc[r][j] = 0.f;
  const float4* W4 = (const float4*)W;   // [K][32] float4 view
  for (int k0 = 0; k0 < K; k0 += 4) {
    float4 w[4];
    #pragma unroll
    for (int kk = 0; kk < 4; ++kk) w[kk] = W4[(k0 + kk) * 32 + cg];
    #pragma unroll
    for (int r = 0; r < 8; ++r) {
      float4 a = As4[(rbase + r) * K4 + (k0 >> 2)];
      const float* ap = (const float*)&a;
      #pragma unroll
      for (int kk = 0; kk < 4; ++kk) {
        acc[r][0] = fmaf(ap[kk], w[kk].x, acc[r][0]);
        acc[r][1] = fmaf(ap[kk], w[kk].y, acc[r][1]);
        acc[r][2] = fmaf(ap[kk], w[kk].z, acc[r][2]);
        acc[r][3] = fmaf(ap[kk], w[kk].w, acc[r][3]);
      }
    }
  }
  float4 bb = make_float4(0.f, 0.f, 0.f, 0.f);
  if (BIAS) bb = ((const float4*)bias)[cg];
  #pragma unroll
  for (int r = 0; r < 8; ++r) {
    int row = r0 + rbase + r;
    if (row < M) {
      float o[4];
      o[0] = acc[r][0] + bb.x; o[1] = acc[r][1] + bb.y;
      o[2] = acc[r][2] + bb.z; o[3] = acc[r][3] + bb.w;
      if (RELU) {
        #pragma unroll
        for (int j = 0; j < 4; ++j) o[j] = fmaxf(o[j], 0.f);
      }
      if constexpr (sizeof(TC) == 4) {
        ((float4*)C)[(size_t)row * 32 + cg] = make_float4(o[0], o[1], o[2], o[3]);
      } else {
        ushort4 u;
        u.x = f2bf(o[0]); u.y = f2bf(o[1]); u.z = f2bf(o[2]); u.w = f2bf(o[3]);
        ((ushort4*)C)[(size_t)row * 32 + cg] = u;
      }
    }
  }
}

// ---------------- GCN aggregation + residual update ----------------
// One wave per node; 4 edge-groups x 16 lanes. Each 16-lane group covers the
// full 256B bf16 row (uint4 = 8 bf16 per lane), 4 edges gathered per load
// instruction, 8 in flight with the 2-deep unroll. Cross-group reduce via
// shfl_xor(16|32); group 0 does residual+relu+store.
__global__ __launch_bounds__(256) void agg_update_kernel(
    const ushort* __restrict__ xw, float* __restrict__ x,
    const int* __restrict__ csr_src, const int* __restrict__ offs,
    const float* __restrict__ dinv, const float* __restrict__ bias, int n) {
  int node = blockIdx.x * 4 + (threadIdx.x >> 6);
  if (node >= n) return;
  int lane = threadIdx.x & 63;
  int grp = lane >> 4;       // edge group 0..3
  int cl = lane & 15;        // row chunk: bf16 elems 8*cl .. 8*cl+7
  const uint4* xw4 = (const uint4*)xw;   // row = 16 uint4
  float acc[8];
  #pragma unroll
  for (int k = 0; k < 8; ++k) acc[k] = 0.f;

  auto fma_row = [&](uint4 v, float w) {
    uint uu[4] = {v.x, v.y, v.z, v.w};
    #pragma unroll
    for (int q = 0; q < 4; ++q) {
      float lo = __uint_as_float(uu[q] << 16);
      float hi = __uint_as_float(uu[q] & 0xffff0000u);
      acc[2 * q]     = fmaf(lo, w, acc[2 * q]);
      acc[2 * q + 1] = fmaf(hi, w, acc[2 * q + 1]);
    }
  };

  int beg = offs[node], end = offs[node + 1];
  int j = beg + grp;
  for (; j + 4 < end; j += 8) {
    int s0 = csr_src[j];
    int s1 = csr_src[j + 4];
    float w0 = dinv[s0];
    float w1 = dinv[s1];
    uint4 v0 = xw4[(size_t)s0 * 16 + cl];
    uint4 v1 = xw4[(size_t)s1 * 16 + cl];
    fma_row(v0, w0);
    fma_row(v1, w1);
  }
  if (j < end) {
    int s0 = csr_src[j];
    float w0 = dinv[s0];
    uint4 v0 = xw4[(size_t)s0 * 16 + cl];
    fma_row(v0, w0);
  }
  float di = dinv[node];
  if (grp == 0) {   // self-loop term
    uint4 vi = xw4[(size_t)node * 16 + cl];
    fma_row(vi, di);
  }
  // reduce across the 4 groups
  #pragma unroll
  for (int k = 0; k < 8; ++k) {
    acc[k] += __shfl_xor(acc[k], 16);
    acc[k] += __shfl_xor(acc[k], 32);
  }
  if (grp == 0) {
    const float4* b4 = (const float4*)bias;
    float4* x4 = (float4*)x;
    size_t base = (size_t)node * 32 + cl * 2;   // float4 units
    float4 bb0 = b4[cl * 2], bb1 = b4[cl * 2 + 1];
    float4 xv0 = x4[base], xv1 = x4[base + 1];
    float4 o0, o1;
    o0.x = fmaxf(fmaf(acc[0], di, bb0.x), 0.f) + xv0.x;
    o0.y = fmaxf(fmaf(acc[1], di, bb0.y), 0.f) + xv0.y;
    o0.z = fmaxf(fmaf(acc[2], di, bb0.z), 0.f) + xv0.z;
    o0.w = fmaxf(fmaf(acc[3], di, bb0.w), 0.f) + xv0.w;
    o1.x = fmaxf(fmaf(acc[4], di, bb1.x), 0.f) + xv1.x;
    o1.y = fmaxf(fmaf(acc[5], di, bb1.y), 0.f) + xv1.y;
    o1.z = fmaxf(fmaf(acc[6], di, bb1.z), 0.f) + xv1.z;
    o1.w = fmaxf(fmaf(acc[7], di, bb1.w), 0.f) + xv1.w;
    x4[base] = o0;
    x4[base + 1] = o1;
  }
}

// ---------------- graph boundaries from sorted batch ----------------
__global__ void bounds_kernel(const int* __restrict__ batch, int* __restrict__ startg,
                              int n, int ng) {
  int i = blockIdx.x * blockDim.x + threadIdx.x;
  if (i > n) return;
  int bi = (i < n) ? batch[i] : ng;
  int bp = (i == 0) ? -1 : batch[i - 1];
  for (int g = bp + 1; g <= bi && g <= ng; ++g) startg[g] = i;
}

// ---------------- per-graph mean/max pooling: 2-stage ----------------
__global__ __launch_bounds__(128) void pool_partial_kernel(const float* __restrict__ x,
    const int* __restrict__ startg, float* __restrict__ psum, float* __restrict__ pmax) {
  int g = blockIdx.x / PCH, ch = blockIdx.x % PCH, c = threadIdx.x;
  int s0 = startg[g], s1 = startg[g + 1];
  int cnt = s1 - s0;
  int len = (cnt + PCH - 1) / PCH;
  int lo = s0 + ch * len;
  int hi = lo + len; if (hi > s1) hi = s1;
  float sum = 0.f, mx = -INFINITY;
  for (int r = lo; r < hi; ++r) {
    float v = x[(size_t)r * HD + c];
    sum += v;
    mx = fmaxf(mx, v);
  }
  psum[(size_t)blockIdx.x * HD + c] = sum;
  pmax[(size_t)blockIdx.x * HD + c] = mx;
}

__global__ __launch_bounds__(128) void pool_final_kernel(const float* __restrict__ psum,
    const float* __restrict__ pmax, const int* __restrict__ startg,
    float* __restrict__ repr) {
  int g = blockIdx.x, c = threadIdx.x;
  float sum = 0.f, mx = -INFINITY;
  #pragma unroll
  for (int ch = 0; ch < PCH; ++ch) {
    sum += psum[(size_t)(g * PCH + ch) * HD + c];
    mx = fmaxf(mx, pmax[(size_t)(g * PCH + ch) * HD + c]);
  }
  int cnt = startg[g + 1] - startg[g];
  float denom = (float)(cnt > 0 ? cnt : 1);
  repr[g * 256 + c] = sum / denom;
  repr[g * 256 + 128 + c] = mx;
}

// ---------------- decoder + value heads (one block per graph) ----------------
__global__ __launch_bounds__(128) void heads_kernel(
    const float* __restrict__ repr,
    const float* __restrict__ dw1, const float* __restrict__ db1,
    const float* __restrict__ dw2, const float* __restrict__ db2,
    const float* __restrict__ dw3, const float* __restrict__ db3,
    const float* __restrict__ vw1, const float* __restrict__ vb1,
    const float* __restrict__ vw2, const float* __restrict__ vb2,
    float* __restrict__ out, int ng) {
  __shared__ float rep[256];
  __shared__ float h1[128];
  __shared__ float h2[64];
  __shared__ float v1[128];
  int g = blockIdx.x, t = threadIdx.x;
  rep[t] = repr[g * 256 + t];
  rep[128 + t] = repr[g * 256 + 128 + t];
  __syncthreads();
  float a = db1[t], b = vb1[t];
  for (int k = 0; k < 256; ++k) {
    float rv = rep[k];
    a = fmaf(rv, dw1[k * 128 + t], a);
    b = fmaf(rv, vw1[k * 128 + t], b);
  }
  h1[t] = fmaxf(a, 0.f);
  v1[t] = fmaxf(b, 0.f);
  __syncthreads();
  if (t < 64) {
    float c = db2[t];
    for (int k = 0; k < 128; ++k) c = fmaf(h1[k], dw2[k * 64 + t], c);
    h2[t] = fmaxf(c, 0.f);
  }
  __syncthreads();
  if (t == 0) {
    float l0 = db3[0], l2 = db3[2];
    for (int k = 0; k < 64; ++k) {
      l0 = fmaf(h2[k], dw3[k * 3 + 0], l0);
      l2 = fmaf(h2[k], dw3[k * 3 + 2], l2);
    }
    out[g] = 1.f / (1.f + expf(-l0));          // adaptation_prob
    out[ng + g] = 1.0f;                        // softmax over 1 element == 1
    out[2 * ng + g] = 1.f / (1.f + expf(-l2)); // urgency_score
    float v = vb2[0];
    for (int k = 0; k < 128; ++k) v = fmaf(v1[k], vw2[k], v);
    out[3 * ng + g] = v;                       // value_estimate
  }
}

// ---------------- launch ----------------
extern "C" void kernel_launch(void* const* d_in, const int* in_sizes, int n_in,
                              void* d_out, int out_size, void* d_ws, size_t ws_size,
                              hipStream_t stream) {
  const float* nf     = (const float*)d_in[0];
  const int*   ei     = (const int*)d_in[1];
  const int*   batch  = (const int*)d_in[2];
  const float* enc_w1 = (const float*)d_in[3];
  const float* enc_b1 = (const float*)d_in[4];
  const float* enc_w2 = (const float*)d_in[5];
  const float* enc_b2 = (const float*)d_in[6];
  const float* gcn_w  = (const float*)d_in[7];
  const float* gcn_b  = (const float*)d_in[8];
  const float* dec_w1 = (const float*)d_in[9];
  const float* dec_b1 = (const float*)d_in[10];
  const float* dec_w2 = (const float*)d_in[11];
  const float* dec_b2 = (const float*)d_in[12];
  const float* dec_w3 = (const float*)d_in[13];
  const float* dec_b3 = (const float*)d_in[14];
  const float* val_w1 = (const float*)d_in[15];
  const float* val_b1 = (const float*)d_in[16];
  const float* val_w2 = (const float*)d_in[17];
  const float* val_b2 = (const float*)d_in[18];
  float* out = (float*)d_out;

  const int n = in_sizes[0] / FD;           // 100000
  const int e = in_sizes[1] / 2;            // 1600000
  const int L = in_sizes[7] / (HD * HD);    // 3
  const int G = out_size / 4;               // 64

  // workspace carve
  char* p = (char*)d_ws;
  auto carve = [&](size_t bytes) {
    void* r = (void*)p;
    p += (bytes + 255) & ~(size_t)255;
    return r;
  };
  float*  x       = (float*)carve((size_t)n * HD * 4);
  ushort* xwb     = (ushort*)carve((size_t)n * HD * 2);   // bf16 xw
  float*  dinv    = (float*)carve((size_t)n * 4);
  int*    deg     = (int*)carve((size_t)n * 4);
  int*    offs    = (int*)carve((size_t)(n + 1) * 4);
  int*    csr_src = (int*)carve((size_t)e * 4);
  float*  repr    = (float*)carve((size_t)G * 256 * 4);
  int*    startg  = (int*)carve((size_t)(G + 1) * 4);
  const int nb    = (n + 1023) / 1024;
  int*    partial = (int*)carve((size_t)nb * 4);
  int*    pref    = (int*)carve((size_t)(nb + 1) * 4);
  float*  psum    = (float*)carve((size_t)G * PCH * HD * 4);
  float*  pmax    = (float*)carve((size_t)G * PCH * HD * 4);
  const int nbk   = (n + (1 << BKT_SHIFT) - 1) >> BKT_SHIFT;   // 391 buckets
  int*    bucket_count  = (int*)carve((size_t)nbk * 4);
  int*    bucket_base   = (int*)carve((size_t)(nbk + 1) * 4);
  int*    bucket_cursor = (int*)carve((size_t)nbk * 4);
  // pairs aliases xwb: CSR build completes before enc1 writes xwb (stream-ordered)
  int2*   pairs   = (int2*)xwb;

  const int gemm_grid = (n + 31) / 32;
  const int ebk_grid = (e + EPB - 1) / EPB;

  // ---- graph structure (before encoder so pairs can alias xwb) ----
  zero_int_kernel<<<(n + 255) / 256, 256, 0, stream>>>(deg, n);
  zero_int_kernel<<<(nbk + 255) / 256, 256, 0, stream>>>(bucket_count, nbk);
  count_deg_kernel<<<(e + 255) / 256, 256, 0, stream>>>(ei + e, deg, e);
  dinv_kernel<<<(n + 255) / 256, 256, 0, stream>>>(deg, dinv, n);
  deg_reduce_kernel<<<nb, 256, 0, stream>>>(deg, partial, n);
  partial_scan_kernel<<<1, 128, 0, stream>>>(partial, pref, nb);
  offs_fill_kernel<<<nb, 256, 0, stream>>>(deg, pref, offs, n, nb);
  bucket_count_kernel<<<ebk_grid, 256, 0, stream>>>(ei + e, bucket_count, e, nbk);
  bucket_scan_kernel<<<1, 512, 0, stream>>>(bucket_count, bucket_base, bucket_cursor, nbk);
  bucket_fill_kernel<<<ebk_grid, 256, 0, stream>>>(ei, ei + e, bucket_cursor, pairs, e, nbk);
  bucket_scatter_kernel<<<nbk, 256, 0, stream>>>(pairs, bucket_base, offs, csr_src, n, nbk);

  // ---- encoder: nf @ w1 -> relu (bf16 tmp), tmp @ w2 -> x (f32) ----
  gemm_aw_kernel<float, ushort, FD, true, true><<<gemm_grid, 128, 0, stream>>>(
      nf, enc_w1, enc_b1, xwb, n);
  gemm_aw_kernel<ushort, float, HD, true, false><<<gemm_grid, 128, 0, stream>>>(
      xwb, enc_w2, enc_b2, x, n);

  // ---- GCN layers ----
  for (int l = 0; l < L; ++l) {
    gemm_aw_kernel<float, ushort, HD, false, false><<<gemm_grid, 128, 0, stream>>>(
        x, gcn_w + (size_t)l * HD * HD, nullptr, xwb, n);
    agg_update_kernel<<<(n + 3) / 4, 256, 0, stream>>>(
        xwb, x, csr_src, offs, dinv, gcn_b + (size_t)l * HD, n);
  }

  // ---- pooling + heads ----
  bounds_kernel<<<(n + 1 + 255) / 256, 256, 0, stream>>>(batch, startg, n, G);
  pool_partial_kernel<<<G * PCH, 128, 0, stream>>>(x, startg, psum, pmax);
  pool_final_kernel<<<G, 128, 0, stream>>>(psum, pmax, startg, repr);
  heads_kernel<<<G, 128, 0, stream>>>(repr,
      dec_w1, dec_b1, dec_w2, dec_b2, dec_w3, dec_b3,
      val_w1, val_b1, val_w2, val_b2, out, G);
}

// Round 6
// 568.674 us; speedup vs baseline: 2.0593x; 1.1702x over previous
//
#include <hip/hip_runtime.h>
#include <math.h>

constexpr int HD = 128;   // hidden dim
constexpr int FD = 64;    // input feature dim
constexpr int PCH = 8;    // pooling chunks per graph
constexpr int BKT_SHIFT = 8;           // 256 nodes per bucket
constexpr int EPB = 8192;              // edges per block in bucket passes

typedef unsigned int uint;
typedef unsigned short ushort;

using bf16x8 = __attribute__((ext_vector_type(8))) short;   // 4 VGPRs
using f32x4  = __attribute__((ext_vector_type(4))) float;

static __device__ inline ushort f2bf(float f) {   // round-to-nearest-even bf16
  uint u = __float_as_uint(f);
  return (ushort)((u + 0x7fffu + ((u >> 16) & 1u)) >> 16);
}
static __device__ inline float bf2f(ushort b) {
  return __uint_as_float((uint)b << 16);
}

// ---------------- utility kernels ----------------
__global__ void zero_int_kernel(int* __restrict__ p, int n) {
  int i = blockIdx.x * blockDim.x + threadIdx.x;
  if (i < n) p[i] = 0;
}

__global__ void count_deg_kernel(const int* __restrict__ dst, int* __restrict__ deg, int e) {
  int i = blockIdx.x * blockDim.x + threadIdx.x;
  if (i < e) atomicAdd(&deg[dst[i]], 1);
}

__global__ void dinv_kernel(const int* __restrict__ deg, float* __restrict__ dinv, int n) {
  int i = blockIdx.x * blockDim.x + threadIdx.x;
  if (i < n) dinv[i] = rsqrtf((float)(deg[i] + 1));   // +1: self-loop
}

// ---------------- hierarchical scan over deg -> offs ----------------
__global__ __launch_bounds__(256) void deg_reduce_kernel(const int* __restrict__ deg,
    int* __restrict__ partial, int n) {
  __shared__ int sh[256];
  int b = blockIdx.x, t = threadIdx.x;
  int base = b * 1024 + t * 4;
  int s = 0;
  #pragma unroll
  for (int k = 0; k < 4; ++k) { int i = base + k; if (i < n) s += deg[i]; }
  sh[t] = s;
  __syncthreads();
  for (int d = 128; d > 0; d >>= 1) {
    if (t < d) sh[t] += sh[t + d];
    __syncthreads();
  }
  if (t == 0) partial[b] = sh[0];
}

__global__ __launch_bounds__(128) void partial_scan_kernel(const int* __restrict__ partial,
    int* __restrict__ pref, int nb) {
  __shared__ int sh[128];
  int t = threadIdx.x;
  int v = (t < nb) ? partial[t] : 0;
  sh[t] = v;
  __syncthreads();
  for (int d = 1; d < 128; d <<= 1) {
    int u = (t >= d) ? sh[t - d] : 0;
    __syncthreads();
    sh[t] += u;
    __syncthreads();
  }
  if (t < nb) pref[t] = sh[t] - v;          // exclusive prefix
  if (t == 127) pref[nb] = sh[127];         // total
}

__global__ __launch_bounds__(256) void offs_fill_kernel(const int* __restrict__ deg,
    const int* __restrict__ pref, int* __restrict__ offs, int n, int nb) {
  __shared__ int sh[256];
  int b = blockIdx.x, t = threadIdx.x;
  int base = b * 1024 + t * 4;
  int d[4]; int s = 0;
  #pragma unroll
  for (int k = 0; k < 4; ++k) {
    int i = base + k;
    d[k] = (i < n) ? deg[i] : 0;
    s += d[k];
  }
  sh[t] = s;
  __syncthreads();
  for (int dd = 1; dd < 256; dd <<= 1) {
    int u = (t >= dd) ? sh[t - dd] : 0;
    __syncthreads();
    sh[t] += u;
    __syncthreads();
  }
  int run = pref[b] + sh[t] - s;
  #pragma unroll
  for (int k = 0; k < 4; ++k) {
    int i = base + k;
    if (i < n) offs[i] = run;
    run += d[k];
  }
  if (b == 0 && t == 0) offs[n] = pref[nb];
}

// ---------------- bucketed CSR build ----------------
__global__ __launch_bounds__(256) void bucket_count_kernel(const int* __restrict__ dst,
    int* __restrict__ bucket_count, int e, int nbk) {
  __shared__ int hist[512];
  int t = threadIdx.x;
  for (int i = t; i < nbk; i += 256) hist[i] = 0;
  __syncthreads();
  int lo = blockIdx.x * EPB;
  int hi = lo + EPB; if (hi > e) hi = e;
  for (int i = lo + t; i < hi; i += 256) atomicAdd(&hist[dst[i] >> BKT_SHIFT], 1);
  __syncthreads();
  for (int i = t; i < nbk; i += 256) {
    int c = hist[i];
    if (c) atomicAdd(&bucket_count[i], c);
  }
}

__global__ __launch_bounds__(512) void bucket_scan_kernel(const int* __restrict__ bucket_count,
    int* __restrict__ bucket_base, int* __restrict__ bucket_cursor, int nbk) {
  __shared__ int sh[512];
  int t = threadIdx.x;
  int v = (t < nbk) ? bucket_count[t] : 0;
  sh[t] = v;
  __syncthreads();
  for (int d = 1; d < 512; d <<= 1) {
    int u = (t >= d) ? sh[t - d] : 0;
    __syncthreads();
    sh[t] += u;
    __syncthreads();
  }
  if (t < nbk) {
    int ex = sh[t] - v;
    bucket_base[t] = ex;
    bucket_cursor[t] = ex;
  }
  if (t == 511) bucket_base[nbk] = sh[511];
}

__global__ __launch_bounds__(256) void bucket_fill_kernel(const int* __restrict__ src,
    const int* __restrict__ dst, int* __restrict__ bucket_cursor,
    int2* __restrict__ pairs, int e, int nbk) {
  __shared__ int hist[512];
  int t = threadIdx.x;
  for (int i = t; i < nbk; i += 256) hist[i] = 0;
  __syncthreads();
  int lo = blockIdx.x * EPB;
  int hi = lo + EPB; if (hi > e) hi = e;
  for (int i = lo + t; i < hi; i += 256) atomicAdd(&hist[dst[i] >> BKT_SHIFT], 1);
  __syncthreads();
  for (int i = t; i < nbk; i += 256) {
    int c = hist[i];
    hist[i] = c ? atomicAdd(&bucket_cursor[i], c) : 0;   // hist now = write cursor
  }
  __syncthreads();
  for (int i = lo + t; i < hi; i += 256) {
    int s = src[i], d = dst[i];
    int pos = atomicAdd(&hist[d >> BKT_SHIFT], 1);
    pairs[pos] = make_int2(s, d);
  }
}

__global__ __launch_bounds__(256) void bucket_scatter_kernel(const int2* __restrict__ pairs,
    const int* __restrict__ bucket_base, const int* __restrict__ offs,
    int* __restrict__ csr_src, int n, int nbk) {
  __shared__ int cur[1 << BKT_SHIFT];
  int b = blockIdx.x, t = threadIdx.x;
  int node0 = b << BKT_SHIFT;
  int nn = n - node0; if (nn > (1 << BKT_SHIFT)) nn = 1 << BKT_SHIFT;
  if (t < nn) cur[t] = offs[node0 + t];
  __syncthreads();
  int lo = bucket_base[b], hi = bucket_base[b + 1];
  for (int i = lo + t; i < hi; i += 256) {
    int2 p = pairs[i];
    int pos = atomicAdd(&cur[p.y - node0], 1);
    csr_src[pos] = p.x;
  }
}

// ---------------- weight transpose+convert: wt[c][k] = bf16(W[k][c]) ----------------
__global__ void convert_wt_kernel(const float* __restrict__ W, ushort* __restrict__ wt,
                                  int KK) {
  int i = blockIdx.x * 256 + threadIdx.x;   // over 128*KK
  if (i < 128 * KK) {
    int c = i / KK, k = i - c * KK;
    wt[i] = f2bf(W[k * 128 + c]);
  }
}

// ---------------- MFMA GEMM: C[M x 128] = A[M x K] @ W[K x 128] (+bias)(+relu) ----
// 4 waves, 64-row tile. A staged (f32->bf16) and Wt (bf16, pre-transposed [c][k])
// staged in LDS with elem ^= (row&7)<<3 swizzle (kills the stride-256B 16-way
// bank conflict on ds_read_b128). mfma_f32_16x16x32_bf16, f32 accum.
template<typename TA, typename TC, int K, bool BIAS, bool RELU>
__global__ __launch_bounds__(256) void mfma_gemm_kernel(const TA* __restrict__ A,
    const ushort* __restrict__ Wt, const float* __restrict__ bias,
    TC* __restrict__ C, int M) {
  __shared__ ushort As[64 * K];
  __shared__ ushort Ws[128 * K];
  const int tid = threadIdx.x;
  const int r0 = blockIdx.x * 64;

  // stage A tile (convert to bf16 if f32), swizzled
  if constexpr (sizeof(TA) == 4) {
    constexpr int C4 = K / 4;
    const float4* A4 = (const float4*)A;
    #pragma unroll
    for (int i = tid; i < 64 * C4; i += 256) {
      int r = i / C4, c4 = i - r * C4;
      int row = r0 + r;
      float4 v = make_float4(0.f, 0.f, 0.f, 0.f);
      if (row < M) v = A4[(size_t)row * C4 + c4];
      ushort4 u;
      u.x = f2bf(v.x); u.y = f2bf(v.y); u.z = f2bf(v.z); u.w = f2bf(v.w);
      int elem = (r * K + c4 * 4) ^ ((r & 7) << 3);
      *(ushort4*)&As[elem] = u;
    }
  } else {
    constexpr int C8 = K / 8;
    const uint4* A4 = (const uint4*)A;
    #pragma unroll
    for (int i = tid; i < 64 * C8; i += 256) {
      int r = i / C8, c8 = i - r * C8;
      int row = r0 + r;
      uint4 v = make_uint4(0u, 0u, 0u, 0u);
      if (row < M) v = A4[(size_t)row * C8 + c8];
      int elem = (r * K + c8 * 8) ^ ((r & 7) << 3);
      *(uint4*)&As[elem] = v;
    }
  }
  // stage Wt (bf16 [128][K]), swizzled
  {
    constexpr int C8 = K / 8;
    const uint4* W4 = (const uint4*)Wt;
    #pragma unroll
    for (int i = tid; i < 128 * C8; i += 256) {
      int c = i / C8, k8 = i - c * C8;
      uint4 v = W4[i];
      int elem = (c * K + k8 * 8) ^ ((c & 7) << 3);
      *(uint4*)&Ws[elem] = v;
    }
  }
  __syncthreads();

  const int l = tid & 63;
  const int wid = tid >> 6;
  const int lr = l & 15;       // fragment row/col within 16
  const int lk = l >> 4;       // k sub-block 0..3
  const int wr = wid * 16;     // wave's row base in tile
  f32x4 acc[8];
  #pragma unroll
  for (int cb = 0; cb < 8; ++cb) acc[cb] = (f32x4){0.f, 0.f, 0.f, 0.f};

  #pragma unroll
  for (int kc = 0; kc < K / 32; ++kc) {
    int ar = wr + lr;
    bf16x8 af = *(const bf16x8*)&As[(ar * K + kc * 32 + lk * 8) ^ ((ar & 7) << 3)];
    #pragma unroll
    for (int cb = 0; cb < 8; ++cb) {
      int col = cb * 16 + lr;
      bf16x8 bfr = *(const bf16x8*)&Ws[(col * K + kc * 32 + lk * 8) ^ ((col & 7) << 3)];
      acc[cb] = __builtin_amdgcn_mfma_f32_16x16x32_bf16(af, bfr, acc[cb], 0, 0, 0);
    }
  }

  #pragma unroll
  for (int cb = 0; cb < 8; ++cb) {
    int col = cb * 16 + lr;
    float bb = BIAS ? bias[col] : 0.f;
    #pragma unroll
    for (int j = 0; j < 4; ++j) {
      int row = r0 + wr + lk * 4 + j;
      if (row < M) {
        float o = acc[cb][j] + bb;
        if (RELU) o = fmaxf(o, 0.f);
        if constexpr (sizeof(TC) == 4) {
          C[(size_t)row * 128 + col] = o;
        } else {
          C[(size_t)row * 128 + col] = f2bf(o);
        }
      }
    }
  }
}

// ---------------- GCN aggregation + residual update ----------------
// One wave per node; 4 edge-groups x 16 lanes; 8 row-gathers in flight.
__global__ __launch_bounds__(256) void agg_update_kernel(
    const ushort* __restrict__ xw, float* __restrict__ x,
    const int* __restrict__ csr_src, const int* __restrict__ offs,
    const float* __restrict__ dinv, const float* __restrict__ bias, int n) {
  int node = blockIdx.x * 4 + (threadIdx.x >> 6);
  if (node >= n) return;
  int lane = threadIdx.x & 63;
  int grp = lane >> 4;       // edge group 0..3
  int cl = lane & 15;        // row chunk: bf16 elems 8*cl .. 8*cl+7
  const uint4* xw4 = (const uint4*)xw;   // row = 16 uint4
  float acc[8];
  #pragma unroll
  for (int k = 0; k < 8; ++k) acc[k] = 0.f;

  auto fma_row = [&](uint4 v, float w) {
    uint uu[4] = {v.x, v.y, v.z, v.w};
    #pragma unroll
    for (int q = 0; q < 4; ++q) {
      float lo = __uint_as_float(uu[q] << 16);
      float hi = __uint_as_float(uu[q] & 0xffff0000u);
      acc[2 * q]     = fmaf(lo, w, acc[2 * q]);
      acc[2 * q + 1] = fmaf(hi, w, acc[2 * q + 1]);
    }
  };

  int beg = offs[node], end = offs[node + 1];
  int j = beg + grp;
  for (; j + 4 < end; j += 8) {
    int s0 = csr_src[j];
    int s1 = csr_src[j + 4];
    float w0 = dinv[s0];
    float w1 = dinv[s1];
    uint4 v0 = xw4[(size_t)s0 * 16 + cl];
    uint4 v1 = xw4[(size_t)s1 * 16 + cl];
    fma_row(v0, w0);
    fma_row(v1, w1);
  }
  if (j < end) {
    int s0 = csr_src[j];
    float w0 = dinv[s0];
    uint4 v0 = xw4[(size_t)s0 * 16 + cl];
    fma_row(v0, w0);
  }
  float di = dinv[node];
  if (grp == 0) {   // self-loop term
    uint4 vi = xw4[(size_t)node * 16 + cl];
    fma_row(vi, di);
  }
  #pragma unroll
  for (int k = 0; k < 8; ++k) {
    acc[k] += __shfl_xor(acc[k], 16);
    acc[k] += __shfl_xor(acc[k], 32);
  }
  if (grp == 0) {
    const float4* b4 = (const float4*)bias;
    float4* x4 = (float4*)x;
    size_t base = (size_t)node * 32 + cl * 2;   // float4 units
    float4 bb0 = b4[cl * 2], bb1 = b4[cl * 2 + 1];
    float4 xv0 = x4[base], xv1 = x4[base + 1];
    float4 o0, o1;
    o0.x = fmaxf(fmaf(acc[0], di, bb0.x), 0.f) + xv0.x;
    o0.y = fmaxf(fmaf(acc[1], di, bb0.y), 0.f) + xv0.y;
    o0.z = fmaxf(fmaf(acc[2], di, bb0.z), 0.f) + xv0.z;
    o0.w = fmaxf(fmaf(acc[3], di, bb0.w), 0.f) + xv0.w;
    o1.x = fmaxf(fmaf(acc[4], di, bb1.x), 0.f) + xv1.x;
    o1.y = fmaxf(fmaf(acc[5], di, bb1.y), 0.f) + xv1.y;
    o1.z = fmaxf(fmaf(acc[6], di, bb1.z), 0.f) + xv1.z;
    o1.w = fmaxf(fmaf(acc[7], di, bb1.w), 0.f) + xv1.w;
    x4[base] = o0;
    x4[base + 1] = o1;
  }
}

// ---------------- graph boundaries from sorted batch ----------------
__global__ void bounds_kernel(const int* __restrict__ batch, int* __restrict__ startg,
                              int n, int ng) {
  int i = blockIdx.x * blockDim.x + threadIdx.x;
  if (i > n) return;
  int bi = (i < n) ? batch[i] : ng;
  int bp = (i == 0) ? -1 : batch[i - 1];
  for (int g = bp + 1; g <= bi && g <= ng; ++g) startg[g] = i;
}

// ---------------- per-graph mean/max pooling: 2-stage ----------------
__global__ __launch_bounds__(128) void pool_partial_kernel(const float* __restrict__ x,
    const int* __restrict__ startg, float* __restrict__ psum, float* __restrict__ pmax) {
  int g = blockIdx.x / PCH, ch = blockIdx.x % PCH, c = threadIdx.x;
  int s0 = startg[g], s1 = startg[g + 1];
  int cnt = s1 - s0;
  int len = (cnt + PCH - 1) / PCH;
  int lo = s0 + ch * len;
  int hi = lo + len; if (hi > s1) hi = s1;
  float sum = 0.f, mx = -INFINITY;
  for (int r = lo; r < hi; ++r) {
    float v = x[(size_t)r * HD + c];
    sum += v;
    mx = fmaxf(mx, v);
  }
  psum[(size_t)blockIdx.x * HD + c] = sum;
  pmax[(size_t)blockIdx.x * HD + c] = mx;
}

__global__ __launch_bounds__(128) void pool_final_kernel(const float* __restrict__ psum,
    const float* __restrict__ pmax, const int* __restrict__ startg,
    float* __restrict__ repr) {
  int g = blockIdx.x, c = threadIdx.x;
  float sum = 0.f, mx = -INFINITY;
  #pragma unroll
  for (int ch = 0; ch < PCH; ++ch) {
    sum += psum[(size_t)(g * PCH + ch) * HD + c];
    mx = fmaxf(mx, pmax[(size_t)(g * PCH + ch) * HD + c]);
  }
  int cnt = startg[g + 1] - startg[g];
  float denom = (float)(cnt > 0 ? cnt : 1);
  repr[g * 256 + c] = sum / denom;
  repr[g * 256 + 128 + c] = mx;
}

// ---------------- decoder + value heads (one block per graph) ----------------
__global__ __launch_bounds__(128) void heads_kernel(
    const float* __restrict__ repr,
    const float* __restrict__ dw1, const float* __restrict__ db1,
    const float* __restrict__ dw2, const float* __restrict__ db2,
    const float* __restrict__ dw3, const float* __restrict__ db3,
    const float* __restrict__ vw1, const float* __restrict__ vb1,
    const float* __restrict__ vw2, const float* __restrict__ vb2,
    float* __restrict__ out, int ng) {
  __shared__ float rep[256];
  __shared__ float h1[128];
  __shared__ float h2[64];
  __shared__ float v1[128];
  int g = blockIdx.x, t = threadIdx.x;
  rep[t] = repr[g * 256 + t];
  rep[128 + t] = repr[g * 256 + 128 + t];
  __syncthreads();
  float a = db1[t], b = vb1[t];
  for (int k = 0; k < 256; ++k) {
    float rv = rep[k];
    a = fmaf(rv, dw1[k * 128 + t], a);
    b = fmaf(rv, vw1[k * 128 + t], b);
  }
  h1[t] = fmaxf(a, 0.f);
  v1[t] = fmaxf(b, 0.f);
  __syncthreads();
  if (t < 64) {
    float c = db2[t];
    for (int k = 0; k < 128; ++k) c = fmaf(h1[k], dw2[k * 64 + t], c);
    h2[t] = fmaxf(c, 0.f);
  }
  __syncthreads();
  if (t == 0) {
    float l0 = db3[0], l2 = db3[2];
    for (int k = 0; k < 64; ++k) {
      l0 = fmaf(h2[k], dw3[k * 3 + 0], l0);
      l2 = fmaf(h2[k], dw3[k * 3 + 2], l2);
    }
    out[g] = 1.f / (1.f + expf(-l0));          // adaptation_prob
    out[ng + g] = 1.0f;                        // softmax over 1 element == 1
    out[2 * ng + g] = 1.f / (1.f + expf(-l2)); // urgency_score
    float v = vb2[0];
    for (int k = 0; k < 128; ++k) v = fmaf(v1[k], vw2[k], v);
    out[3 * ng + g] = v;                       // value_estimate
  }
}

// ---------------- launch ----------------
extern "C" void kernel_launch(void* const* d_in, const int* in_sizes, int n_in,
                              void* d_out, int out_size, void* d_ws, size_t ws_size,
                              hipStream_t stream) {
  const float* nf     = (const float*)d_in[0];
  const int*   ei     = (const int*)d_in[1];
  const int*   batch  = (const int*)d_in[2];
  const float* enc_w1 = (const float*)d_in[3];
  const float* enc_b1 = (const float*)d_in[4];
  const float* enc_w2 = (const float*)d_in[5];
  const float* enc_b2 = (const float*)d_in[6];
  const float* gcn_w  = (const float*)d_in[7];
  const float* gcn_b  = (const float*)d_in[8];
  const float* dec_w1 = (const float*)d_in[9];
  const float* dec_b1 = (const float*)d_in[10];
  const float* dec_w2 = (const float*)d_in[11];
  const float* dec_b2 = (const float*)d_in[12];
  const float* dec_w3 = (const float*)d_in[13];
  const float* dec_b3 = (const float*)d_in[14];
  const float* val_w1 = (const float*)d_in[15];
  const float* val_b1 = (const float*)d_in[16];
  const float* val_w2 = (const float*)d_in[17];
  const float* val_b2 = (const float*)d_in[18];
  float* out = (float*)d_out;

  const int n = in_sizes[0] / FD;           // 100000
  const int e = in_sizes[1] / 2;            // 1600000
  const int L = in_sizes[7] / (HD * HD);    // 3
  const int G = out_size / 4;               // 64

  // workspace carve
  char* p = (char*)d_ws;
  auto carve = [&](size_t bytes) {
    void* r = (void*)p;
    p += (bytes + 255) & ~(size_t)255;
    return r;
  };
  float*  x       = (float*)carve((size_t)n * HD * 4);
  ushort* xwb     = (ushort*)carve((size_t)n * HD * 2);   // bf16 xw
  float*  dinv    = (float*)carve((size_t)n * 4);
  int*    deg     = (int*)carve((size_t)n * 4);
  int*    offs    = (int*)carve((size_t)(n + 1) * 4);
  int*    csr_src = (int*)carve((size_t)e * 4);
  float*  repr    = (float*)carve((size_t)G * 256 * 4);
  int*    startg  = (int*)carve((size_t)(G + 1) * 4);
  const int nb    = (n + 1023) / 1024;
  int*    partial = (int*)carve((size_t)nb * 4);
  int*    pref    = (int*)carve((size_t)(nb + 1) * 4);
  float*  psum    = (float*)carve((size_t)G * PCH * HD * 4);
  float*  pmax    = (float*)carve((size_t)G * PCH * HD * 4);
  const int nbk   = (n + (1 << BKT_SHIFT) - 1) >> BKT_SHIFT;   // 391 buckets
  int*    bucket_count  = (int*)carve((size_t)nbk * 4);
  int*    bucket_base   = (int*)carve((size_t)(nbk + 1) * 4);
  int*    bucket_cursor = (int*)carve((size_t)nbk * 4);
  ushort* wt_e1   = (ushort*)carve((size_t)128 * FD * 2);      // enc_w1^T bf16
  ushort* wt_e2   = (ushort*)carve((size_t)128 * HD * 2);      // enc_w2^T bf16
  ushort* wt_g    = (ushort*)carve((size_t)3 * 128 * HD * 2);  // gcn_w^T bf16
  // pairs aliases xwb: CSR build completes before enc1 writes xwb (stream-ordered)
  int2*   pairs   = (int2*)xwb;

  const int gemm_grid = (n + 63) / 64;
  const int ebk_grid = (e + EPB - 1) / EPB;

  // ---- graph structure (before encoder so pairs can alias xwb) ----
  zero_int_kernel<<<(n + 255) / 256, 256, 0, stream>>>(deg, n);
  zero_int_kernel<<<(nbk + 255) / 256, 256, 0, stream>>>(bucket_count, nbk);
  count_deg_kernel<<<(e + 255) / 256, 256, 0, stream>>>(ei + e, deg, e);
  dinv_kernel<<<(n + 255) / 256, 256, 0, stream>>>(deg, dinv, n);
  deg_reduce_kernel<<<nb, 256, 0, stream>>>(deg, partial, n);
  partial_scan_kernel<<<1, 128, 0, stream>>>(partial, pref, nb);
  offs_fill_kernel<<<nb, 256, 0, stream>>>(deg, pref, offs, n, nb);
  bucket_count_kernel<<<ebk_grid, 256, 0, stream>>>(ei + e, bucket_count, e, nbk);
  bucket_scan_kernel<<<1, 512, 0, stream>>>(bucket_count, bucket_base, bucket_cursor, nbk);
  bucket_fill_kernel<<<ebk_grid, 256, 0, stream>>>(ei, ei + e, bucket_cursor, pairs, e, nbk);
  bucket_scatter_kernel<<<nbk, 256, 0, stream>>>(pairs, bucket_base, offs, csr_src, n, nbk);

  // ---- weight transposes (tiny) ----
  convert_wt_kernel<<<(128 * FD + 255) / 256, 256, 0, stream>>>(enc_w1, wt_e1, FD);
  convert_wt_kernel<<<(128 * HD + 255) / 256, 256, 0, stream>>>(enc_w2, wt_e2, HD);
  for (int l = 0; l < L; ++l)
    convert_wt_kernel<<<(128 * HD + 255) / 256, 256, 0, stream>>>(
        gcn_w + (size_t)l * HD * HD, wt_g + (size_t)l * 128 * HD, HD);

  // ---- encoder: nf @ w1 -> relu (bf16 tmp), tmp @ w2 -> x (f32) ----
  mfma_gemm_kernel<float, ushort, FD, true, true><<<gemm_grid, 256, 0, stream>>>(
      nf, wt_e1, enc_b1, xwb, n);
  mfma_gemm_kernel<ushort, float, HD, true, false><<<gemm_grid, 256, 0, stream>>>(
      xwb, wt_e2, enc_b2, x, n);

  // ---- GCN layers ----
  for (int l = 0; l < L; ++l) {
    mfma_gemm_kernel<float, ushort, HD, false, false><<<gemm_grid, 256, 0, stream>>>(
        x, wt_g + (size_t)l * 128 * HD, nullptr, xwb, n);
    agg_update_kernel<<<(n + 3) / 4, 256, 0, stream>>>(
        xwb, x, csr_src, offs, dinv, gcn_b + (size_t)l * HD, n);
  }

  // ---- pooling + heads ----
  bounds_kernel<<<(n + 1 + 255) / 256, 256, 0, stream>>>(batch, startg, n, G);
  pool_partial_kernel<<<G * PCH, 128, 0, stream>>>(x, startg, psum, pmax);
  pool_final_kernel<<<G, 128, 0, stream>>>(psum, pmax, startg, repr);
  heads_kernel<<<G, 128, 0, stream>>>(repr,
      dec_w1, dec_b1, dec_w2, dec_b2, dec_w3, dec_b3,
      val_w1, val_b1, val_w2, val_b2, out, G);
}

// Round 7
// 457.975 us; speedup vs baseline: 2.5571x; 1.2417x over previous
//
#include <hip/hip_runtime.h>
#include <math.h>

constexpr int HD = 128;   // hidden dim
constexpr int FD = 64;    // input feature dim
constexpr int PCH = 8;    // pooling chunks per graph
constexpr int BKT_SHIFT = 8;           // 256 nodes per bucket
constexpr int EPB = 8192;              // edges per block in bucket passes

typedef unsigned int uint;
typedef unsigned short ushort;

using bf16x8 = __attribute__((ext_vector_type(8))) short;   // 4 VGPRs
using f32x4  = __attribute__((ext_vector_type(4))) float;

static __device__ inline ushort f2bf(float f) {   // round-to-nearest-even bf16
  uint u = __float_as_uint(f);
  return (ushort)((u + 0x7fffu + ((u >> 16) & 1u)) >> 16);
}
static __device__ inline float bf2f(ushort b) {
  return __uint_as_float((uint)b << 16);
}
static __device__ inline uint pack2bf(float a, float b) {
  return (uint)f2bf(a) | ((uint)f2bf(b) << 16);
}

// ---------------- utility ----------------
__global__ void zero_int_kernel(int* __restrict__ p, int n) {
  int i = blockIdx.x * blockDim.x + threadIdx.x;
  if (i < n) p[i] = 0;
}

// ---------------- bucketed CSR build (also produces offs, dinv) ----------------
__global__ __launch_bounds__(256) void bucket_count_kernel(const int* __restrict__ dst,
    int* __restrict__ bucket_count, int e, int nbk) {
  __shared__ int hist[512];
  int t = threadIdx.x;
  for (int i = t; i < nbk; i += 256) hist[i] = 0;
  __syncthreads();
  int lo = blockIdx.x * EPB;
  int hi = lo + EPB; if (hi > e) hi = e;
  for (int i = lo + t; i < hi; i += 256) atomicAdd(&hist[dst[i] >> BKT_SHIFT], 1);
  __syncthreads();
  for (int i = t; i < nbk; i += 256) {
    int c = hist[i];
    if (c) atomicAdd(&bucket_count[i], c);
  }
}

__global__ __launch_bounds__(512) void bucket_scan_kernel(const int* __restrict__ bucket_count,
    int* __restrict__ bucket_base, int* __restrict__ bucket_cursor, int nbk) {
  __shared__ int sh[512];
  int t = threadIdx.x;
  int v = (t < nbk) ? bucket_count[t] : 0;
  sh[t] = v;
  __syncthreads();
  for (int d = 1; d < 512; d <<= 1) {
    int u = (t >= d) ? sh[t - d] : 0;
    __syncthreads();
    sh[t] += u;
    __syncthreads();
  }
  if (t < nbk) {
    int ex = sh[t] - v;
    bucket_base[t] = ex;
    bucket_cursor[t] = ex;
  }
  if (t == 511) bucket_base[nbk] = sh[511];
}

__global__ __launch_bounds__(256) void bucket_fill_kernel(const int* __restrict__ src,
    const int* __restrict__ dst, int* __restrict__ bucket_cursor,
    int2* __restrict__ pairs, int e, int nbk) {
  __shared__ int hist[512];
  int t = threadIdx.x;
  for (int i = t; i < nbk; i += 256) hist[i] = 0;
  __syncthreads();
  int lo = blockIdx.x * EPB;
  int hi = lo + EPB; if (hi > e) hi = e;
  for (int i = lo + t; i < hi; i += 256) atomicAdd(&hist[dst[i] >> BKT_SHIFT], 1);
  __syncthreads();
  for (int i = t; i < nbk; i += 256) {
    int c = hist[i];
    hist[i] = c ? atomicAdd(&bucket_cursor[i], c) : 0;   // hist now = write cursor
  }
  __syncthreads();
  for (int i = lo + t; i < hi; i += 256) {
    int s = src[i], d = dst[i];
    int pos = atomicAdd(&hist[d >> BKT_SHIFT], 1);
    pairs[pos] = make_int2(s, d);
  }
}

// one block per bucket: count per-node in LDS, scan -> offs & dinv, then scatter
__global__ __launch_bounds__(256) void bucket_scatter_kernel(const int2* __restrict__ pairs,
    const int* __restrict__ bucket_base, int* __restrict__ offs,
    float* __restrict__ dinv, int* __restrict__ csr_src, int n, int nbk) {
  __shared__ int cnt[256];
  __shared__ int pre[256];
  int b = blockIdx.x, t = threadIdx.x;
  int node0 = b << BKT_SHIFT;
  bool valid_node = (node0 + t) < n;
  cnt[t] = 0;
  __syncthreads();
  int lo = bucket_base[b], hi = bucket_base[b + 1];
  for (int i = lo + t; i < hi; i += 256)
    atomicAdd(&cnt[pairs[i].y - node0], 1);
  __syncthreads();
  int v = cnt[t];
  pre[t] = v;
  __syncthreads();
  for (int d = 1; d < 256; d <<= 1) {
    int u = (t >= d) ? pre[t - d] : 0;
    __syncthreads();
    pre[t] += u;
    __syncthreads();
  }
  int off = lo + pre[t] - v;   // exclusive prefix within bucket + bucket base
  if (valid_node) {
    offs[node0 + t] = off;
    dinv[node0 + t] = rsqrtf((float)(v + 1));   // +1: self-loop
  }
  __syncthreads();
  cnt[t] = off;   // reuse as cursor
  __syncthreads();
  for (int i = lo + t; i < hi; i += 256) {
    int2 pp = pairs[i];
    int pos = atomicAdd(&cnt[pp.y - node0], 1);
    csr_src[pos] = pp.x;
  }
  if (b == 0 && t == 0) offs[n] = bucket_base[nbk];
}

// ---------------- weight transpose+convert: wt[c][k] = bf16(W[k][c]) ----------------
__global__ void convert_wt_kernel(const float* __restrict__ W, ushort* __restrict__ wt,
                                  int KK) {
  int i = blockIdx.x * 256 + threadIdx.x;   // over 128*KK
  if (i < 128 * KK) {
    int c = i / KK, k = i - c * KK;
    wt[i] = f2bf(W[k * 128 + c]);
  }
}

// ---------------- MFMA GEMM: C[M x 128] = A[M x K] @ W[K x 128] (+bias)(+relu) ----
// 4 waves, 64-row tile. A (f32->bf16 or bf16) and Wt (bf16 [c][k]) staged in LDS
// with elem ^= (row&7)<<3 swizzle. mfma_f32_16x16x32_bf16, f32 accum.
template<typename TA, int K, bool BIAS, bool RELU>
__global__ __launch_bounds__(256) void mfma_gemm_kernel(const TA* __restrict__ A,
    const ushort* __restrict__ Wt, const float* __restrict__ bias,
    ushort* __restrict__ C, int M) {
  __shared__ ushort As[64 * K];
  __shared__ ushort Ws[128 * K];
  const int tid = threadIdx.x;
  const int r0 = blockIdx.x * 64;

  if constexpr (sizeof(TA) == 4) {
    constexpr int C4 = K / 4;
    const float4* A4 = (const float4*)A;
    #pragma unroll
    for (int i = tid; i < 64 * C4; i += 256) {
      int r = i / C4, c4 = i - r * C4;
      int row = r0 + r;
      float4 v = make_float4(0.f, 0.f, 0.f, 0.f);
      if (row < M) v = A4[(size_t)row * C4 + c4];
      ushort4 u;
      u.x = f2bf(v.x); u.y = f2bf(v.y); u.z = f2bf(v.z); u.w = f2bf(v.w);
      int elem = (r * K + c4 * 4) ^ ((r & 7) << 3);
      *(ushort4*)&As[elem] = u;
    }
  } else {
    constexpr int C8 = K / 8;
    const uint4* A4 = (const uint4*)A;
    #pragma unroll
    for (int i = tid; i < 64 * C8; i += 256) {
      int r = i / C8, c8 = i - r * C8;
      int row = r0 + r;
      uint4 v = make_uint4(0u, 0u, 0u, 0u);
      if (row < M) v = A4[(size_t)row * C8 + c8];
      int elem = (r * K + c8 * 8) ^ ((r & 7) << 3);
      *(uint4*)&As[elem] = v;
    }
  }
  {
    constexpr int C8 = K / 8;
    const uint4* W4 = (const uint4*)Wt;
    #pragma unroll
    for (int i = tid; i < 128 * C8; i += 256) {
      int c = i / C8, k8 = i - c * C8;
      uint4 v = W4[i];
      int elem = (c * K + k8 * 8) ^ ((c & 7) << 3);
      *(uint4*)&Ws[elem] = v;
    }
  }
  __syncthreads();

  const int l = tid & 63;
  const int wid = tid >> 6;
  const int lr = l & 15;       // fragment row/col within 16
  const int lk = l >> 4;       // k sub-block 0..3
  const int wr = wid * 16;     // wave's row base in tile
  f32x4 acc[8];
  #pragma unroll
  for (int cb = 0; cb < 8; ++cb) acc[cb] = (f32x4){0.f, 0.f, 0.f, 0.f};

  #pragma unroll
  for (int kc = 0; kc < K / 32; ++kc) {
    int ar = wr + lr;
    bf16x8 af = *(const bf16x8*)&As[(ar * K + kc * 32 + lk * 8) ^ ((ar & 7) << 3)];
    #pragma unroll
    for (int cb = 0; cb < 8; ++cb) {
      int col = cb * 16 + lr;
      bf16x8 bfr = *(const bf16x8*)&Ws[(col * K + kc * 32 + lk * 8) ^ ((col & 7) << 3)];
      acc[cb] = __builtin_amdgcn_mfma_f32_16x16x32_bf16(af, bfr, acc[cb], 0, 0, 0);
    }
  }

  #pragma unroll
  for (int cb = 0; cb < 8; ++cb) {
    int col = cb * 16 + lr;
    float bb = BIAS ? bias[col] : 0.f;
    #pragma unroll
    for (int j = 0; j < 4; ++j) {
      int row = r0 + wr + lk * 4 + j;
      if (row < M) {
        float o = acc[cb][j] + bb;
        if (RELU) o = fmaxf(o, 0.f);
        C[(size_t)row * 128 + col] = f2bf(o);
      }
    }
  }
}

// ---------------- GCN aggregation + residual update ----------------
// x (bf16) += relu( dinv*(sum xw[src]*dinv[src] + xw[self]*dinv) + bias ).
// One wave per node; 4 edge-groups x 16 lanes; 4-deep unroll = 16 gathers in flight.
__global__ __launch_bounds__(256) void agg_update_kernel(
    const ushort* __restrict__ xw, ushort* __restrict__ x,
    const int* __restrict__ csr_src, const int* __restrict__ offs,
    const float* __restrict__ dinv, const float* __restrict__ bias, int n) {
  int node = blockIdx.x * 4 + (threadIdx.x >> 6);
  if (node >= n) return;
  int lane = threadIdx.x & 63;
  int grp = lane >> 4;       // edge group 0..3
  int cl = lane & 15;        // row chunk: bf16 elems 8*cl .. 8*cl+7
  const uint4* xw4 = (const uint4*)xw;   // row = 16 uint4
  float acc[8];
  #pragma unroll
  for (int k = 0; k < 8; ++k) acc[k] = 0.f;

  auto fma_row = [&](uint4 v, float w) {
    uint uu[4] = {v.x, v.y, v.z, v.w};
    #pragma unroll
    for (int q = 0; q < 4; ++q) {
      float lo = __uint_as_float(uu[q] << 16);
      float hi = __uint_as_float(uu[q] & 0xffff0000u);
      acc[2 * q]     = fmaf(lo, w, acc[2 * q]);
      acc[2 * q + 1] = fmaf(hi, w, acc[2 * q + 1]);
    }
  };

  int beg = offs[node], end = offs[node + 1];
  int j = beg + grp;
  for (; j + 12 < end; j += 16) {
    int s0 = csr_src[j];
    int s1 = csr_src[j + 4];
    int s2 = csr_src[j + 8];
    int s3 = csr_src[j + 12];
    float w0 = dinv[s0], w1 = dinv[s1], w2 = dinv[s2], w3 = dinv[s3];
    uint4 v0 = xw4[(size_t)s0 * 16 + cl];
    uint4 v1 = xw4[(size_t)s1 * 16 + cl];
    uint4 v2 = xw4[(size_t)s2 * 16 + cl];
    uint4 v3 = xw4[(size_t)s3 * 16 + cl];
    fma_row(v0, w0); fma_row(v1, w1); fma_row(v2, w2); fma_row(v3, w3);
  }
  for (; j + 4 < end; j += 8) {
    int s0 = csr_src[j];
    int s1 = csr_src[j + 4];
    float w0 = dinv[s0], w1 = dinv[s1];
    uint4 v0 = xw4[(size_t)s0 * 16 + cl];
    uint4 v1 = xw4[(size_t)s1 * 16 + cl];
    fma_row(v0, w0); fma_row(v1, w1);
  }
  if (j < end) {
    int s0 = csr_src[j];
    float w0 = dinv[s0];
    uint4 v0 = xw4[(size_t)s0 * 16 + cl];
    fma_row(v0, w0);
  }
  float di = dinv[node];
  if (grp == 0) {   // self-loop term
    uint4 vi = xw4[(size_t)node * 16 + cl];
    fma_row(vi, di);
  }
  #pragma unroll
  for (int k = 0; k < 8; ++k) {
    acc[k] += __shfl_xor(acc[k], 16);
    acc[k] += __shfl_xor(acc[k], 32);
  }
  if (grp == 0) {
    const float4* b4 = (const float4*)bias;
    float4 bb0 = b4[cl * 2], bb1 = b4[cl * 2 + 1];
    float bbv[8] = {bb0.x, bb0.y, bb0.z, bb0.w, bb1.x, bb1.y, bb1.z, bb1.w};
    uint4* xv4 = (uint4*)x;
    size_t xi = (size_t)node * 16 + cl;
    uint4 xv = xv4[xi];
    uint xu[4] = {xv.x, xv.y, xv.z, xv.w};
    float o[8];
    #pragma unroll
    for (int q = 0; q < 4; ++q) {
      float lo = __uint_as_float(xu[q] << 16);
      float hi = __uint_as_float(xu[q] & 0xffff0000u);
      o[2 * q]     = fmaxf(fmaf(acc[2 * q],     di, bbv[2 * q]),     0.f) + lo;
      o[2 * q + 1] = fmaxf(fmaf(acc[2 * q + 1], di, bbv[2 * q + 1]), 0.f) + hi;
    }
    uint4 ou;
    ou.x = pack2bf(o[0], o[1]);
    ou.y = pack2bf(o[2], o[3]);
    ou.z = pack2bf(o[4], o[5]);
    ou.w = pack2bf(o[6], o[7]);
    xv4[xi] = ou;
  }
}

// ---------------- graph boundaries from sorted batch ----------------
__global__ void bounds_kernel(const int* __restrict__ batch, int* __restrict__ startg,
                              int n, int ng) {
  int i = blockIdx.x * blockDim.x + threadIdx.x;
  if (i > n) return;
  int bi = (i < n) ? batch[i] : ng;
  int bp = (i == 0) ? -1 : batch[i - 1];
  for (int g = bp + 1; g <= bi && g <= ng; ++g) startg[g] = i;
}

// ---------------- per-graph mean/max pooling: 2-stage (bf16 x) ----------------
__global__ __launch_bounds__(128) void pool_partial_kernel(const ushort* __restrict__ x,
    const int* __restrict__ startg, float* __restrict__ psum, float* __restrict__ pmax) {
  int g = blockIdx.x / PCH, ch = blockIdx.x % PCH, c = threadIdx.x;
  int s0 = startg[g], s1 = startg[g + 1];
  int cnt = s1 - s0;
  int len = (cnt + PCH - 1) / PCH;
  int lo = s0 + ch * len;
  int hi = lo + len; if (hi > s1) hi = s1;
  float sum = 0.f, mx = -INFINITY;
  for (int r = lo; r < hi; ++r) {
    float v = bf2f(x[(size_t)r * HD + c]);
    sum += v;
    mx = fmaxf(mx, v);
  }
  psum[(size_t)blockIdx.x * HD + c] = sum;
  pmax[(size_t)blockIdx.x * HD + c] = mx;
}

__global__ __launch_bounds__(128) void pool_final_kernel(const float* __restrict__ psum,
    const float* __restrict__ pmax, const int* __restrict__ startg,
    float* __restrict__ repr) {
  int g = blockIdx.x, c = threadIdx.x;
  float sum = 0.f, mx = -INFINITY;
  #pragma unroll
  for (int ch = 0; ch < PCH; ++ch) {
    sum += psum[(size_t)(g * PCH + ch) * HD + c];
    mx = fmaxf(mx, pmax[(size_t)(g * PCH + ch) * HD + c]);
  }
  int cnt = startg[g + 1] - startg[g];
  float denom = (float)(cnt > 0 ? cnt : 1);
  repr[g * 256 + c] = sum / denom;
  repr[g * 256 + 128 + c] = mx;
}

// ---------------- decoder + value heads (one block per graph) ----------------
__global__ __launch_bounds__(128) void heads_kernel(
    const float* __restrict__ repr,
    const float* __restrict__ dw1, const float* __restrict__ db1,
    const float* __restrict__ dw2, const float* __restrict__ db2,
    const float* __restrict__ dw3, const float* __restrict__ db3,
    const float* __restrict__ vw1, const float* __restrict__ vb1,
    const float* __restrict__ vw2, const float* __restrict__ vb2,
    float* __restrict__ out, int ng) {
  __shared__ float rep[256];
  __shared__ float h1[128];
  __shared__ float h2[64];
  __shared__ float v1[128];
  int g = blockIdx.x, t = threadIdx.x;
  rep[t] = repr[g * 256 + t];
  rep[128 + t] = repr[g * 256 + 128 + t];
  __syncthreads();
  float a = db1[t], b = vb1[t];
  for (int k = 0; k < 256; ++k) {
    float rv = rep[k];
    a = fmaf(rv, dw1[k * 128 + t], a);
    b = fmaf(rv, vw1[k * 128 + t], b);
  }
  h1[t] = fmaxf(a, 0.f);
  v1[t] = fmaxf(b, 0.f);
  __syncthreads();
  if (t < 64) {
    float c = db2[t];
    for (int k = 0; k < 128; ++k) c = fmaf(h1[k], dw2[k * 64 + t], c);
    h2[t] = fmaxf(c, 0.f);
  }
  __syncthreads();
  if (t == 0) {
    float l0 = db3[0], l2 = db3[2];
    for (int k = 0; k < 64; ++k) {
      l0 = fmaf(h2[k], dw3[k * 3 + 0], l0);
      l2 = fmaf(h2[k], dw3[k * 3 + 2], l2);
    }
    out[g] = 1.f / (1.f + expf(-l0));          // adaptation_prob
    out[ng + g] = 1.0f;                        // softmax over 1 element == 1
    out[2 * ng + g] = 1.f / (1.f + expf(-l2)); // urgency_score
    float v = vb2[0];
    for (int k = 0; k < 128; ++k) v = fmaf(v1[k], vw2[k], v);
    out[3 * ng + g] = v;                       // value_estimate
  }
}

// ---------------- launch ----------------
extern "C" void kernel_launch(void* const* d_in, const int* in_sizes, int n_in,
                              void* d_out, int out_size, void* d_ws, size_t ws_size,
                              hipStream_t stream) {
  const float* nf     = (const float*)d_in[0];
  const int*   ei     = (const int*)d_in[1];
  const int*   batch  = (const int*)d_in[2];
  const float* enc_w1 = (const float*)d_in[3];
  const float* enc_b1 = (const float*)d_in[4];
  const float* enc_w2 = (const float*)d_in[5];
  const float* enc_b2 = (const float*)d_in[6];
  const float* gcn_w  = (const float*)d_in[7];
  const float* gcn_b  = (const float*)d_in[8];
  const float* dec_w1 = (const float*)d_in[9];
  const float* dec_b1 = (const float*)d_in[10];
  const float* dec_w2 = (const float*)d_in[11];
  const float* dec_b2 = (const float*)d_in[12];
  const float* dec_w3 = (const float*)d_in[13];
  const float* dec_b3 = (const float*)d_in[14];
  const float* val_w1 = (const float*)d_in[15];
  const float* val_b1 = (const float*)d_in[16];
  const float* val_w2 = (const float*)d_in[17];
  const float* val_b2 = (const float*)d_in[18];
  float* out = (float*)d_out;

  const int n = in_sizes[0] / FD;           // 100000
  const int e = in_sizes[1] / 2;            // 1600000
  const int L = in_sizes[7] / (HD * HD);    // 3
  const int G = out_size / 4;               // 64

  // workspace carve
  char* p = (char*)d_ws;
  auto carve = [&](size_t bytes) {
    void* r = (void*)p;
    p += (bytes + 255) & ~(size_t)255;
    return r;
  };
  ushort* x       = (ushort*)carve((size_t)n * HD * 2);    // bf16 x
  ushort* xwb     = (ushort*)carve((size_t)n * HD * 2);    // bf16 xw
  float*  dinv    = (float*)carve((size_t)n * 4);
  int*    offs    = (int*)carve((size_t)(n + 1) * 4);
  int*    csr_src = (int*)carve((size_t)e * 4);
  float*  repr    = (float*)carve((size_t)G * 256 * 4);
  int*    startg  = (int*)carve((size_t)(G + 1) * 4);
  float*  psum    = (float*)carve((size_t)G * PCH * HD * 4);
  float*  pmax    = (float*)carve((size_t)G * PCH * HD * 4);
  const int nbk   = (n + (1 << BKT_SHIFT) - 1) >> BKT_SHIFT;   // 391 buckets
  int*    bucket_count  = (int*)carve((size_t)nbk * 4);
  int*    bucket_base   = (int*)carve((size_t)(nbk + 1) * 4);
  int*    bucket_cursor = (int*)carve((size_t)nbk * 4);
  ushort* wt_e1   = (ushort*)carve((size_t)128 * FD * 2);      // enc_w1^T bf16
  ushort* wt_e2   = (ushort*)carve((size_t)128 * HD * 2);      // enc_w2^T bf16
  ushort* wt_g    = (ushort*)carve((size_t)3 * 128 * HD * 2);  // gcn_w^T bf16
  // pairs aliases xwb: CSR build completes before enc1 writes xwb (stream-ordered)
  int2*   pairs   = (int2*)xwb;

  const int gemm_grid = (n + 63) / 64;
  const int ebk_grid = (e + EPB - 1) / EPB;

  // ---- graph structure (before encoder so pairs can alias xwb) ----
  zero_int_kernel<<<(nbk + 255) / 256, 256, 0, stream>>>(bucket_count, nbk);
  bucket_count_kernel<<<ebk_grid, 256, 0, stream>>>(ei + e, bucket_count, e, nbk);
  bucket_scan_kernel<<<1, 512, 0, stream>>>(bucket_count, bucket_base, bucket_cursor, nbk);
  bucket_fill_kernel<<<ebk_grid, 256, 0, stream>>>(ei, ei + e, bucket_cursor, pairs, e, nbk);
  bucket_scatter_kernel<<<nbk, 256, 0, stream>>>(pairs, bucket_base, offs, dinv, csr_src, n, nbk);

  // ---- weight transposes (tiny) ----
  convert_wt_kernel<<<(128 * FD + 255) / 256, 256, 0, stream>>>(enc_w1, wt_e1, FD);
  convert_wt_kernel<<<(128 * HD + 255) / 256, 256, 0, stream>>>(enc_w2, wt_e2, HD);
  for (int l = 0; l < L; ++l)
    convert_wt_kernel<<<(128 * HD + 255) / 256, 256, 0, stream>>>(
        gcn_w + (size_t)l * HD * HD, wt_g + (size_t)l * 128 * HD, HD);

  // ---- encoder: nf @ w1 -> relu (bf16), @ w2 -> x (bf16) ----
  mfma_gemm_kernel<float, FD, true, true><<<gemm_grid, 256, 0, stream>>>(
      nf, wt_e1, enc_b1, xwb, n);
  mfma_gemm_kernel<ushort, HD, true, false><<<gemm_grid, 256, 0, stream>>>(
      xwb, wt_e2, enc_b2, x, n);

  // ---- GCN layers ----
  for (int l = 0; l < L; ++l) {
    mfma_gemm_kernel<ushort, HD, false, false><<<gemm_grid, 256, 0, stream>>>(
        x, wt_g + (size_t)l * 128 * HD, nullptr, xwb, n);
    agg_update_kernel<<<(n + 3) / 4, 256, 0, stream>>>(
        xwb, x, csr_src, offs, dinv, gcn_b + (size_t)l * HD, n);
  }

  // ---- pooling + heads ----
  bounds_kernel<<<(n + 1 + 255) / 256, 256, 0, stream>>>(batch, startg, n, G);
  pool_partial_kernel<<<G * PCH, 128, 0, stream>>>(x, startg, psum, pmax);
  pool_final_kernel<<<G, 128, 0, stream>>>(psum, pmax, startg, repr);
  heads_kernel<<<G, 128, 0, stream>>>(repr,
      dec_w1, dec_b1, dec_w2, dec_b2, dec_w3, dec_b3,
      val_w1, val_b1, val_w2, val_b2, out, G);
}

// Round 8
// 416.618 us; speedup vs baseline: 2.8110x; 1.0993x over previous
//
#include <hip/hip_runtime.h>
#include <math.h>

constexpr int HD = 128;   // hidden dim
constexpr int FD = 64;    // input feature dim
constexpr int PCH = 8;    // pooling chunks per graph
constexpr int BKT_SHIFT = 8;           // 256 nodes per bucket
constexpr int EPB = 8192;              // edges per block in bucket passes
constexpr float FP8_SCALE = 16.f;      // pre-scale before e4m3 quantization
constexpr float FP8_INV_SCALE = 1.f / 16.f;

typedef unsigned int uint;
typedef unsigned short ushort;
typedef unsigned char uchar;

using bf16x8 = __attribute__((ext_vector_type(8))) short;   // 4 VGPRs
using f32x4  = __attribute__((ext_vector_type(4))) float;

#if defined(__has_builtin)
#if __has_builtin(__builtin_amdgcn_cvt_pk_f32_fp8) && __has_builtin(__builtin_amdgcn_cvt_pk_fp8_f32)
#define HW_FP8 1
#endif
#endif

static __device__ inline ushort f2bf(float f) {   // round-to-nearest-even bf16
  uint u = __float_as_uint(f);
  return (ushort)((u + 0x7fffu + ((u >> 16) & 1u)) >> 16);
}
static __device__ inline float bf2f(ushort b) {
  return __uint_as_float((uint)b << 16);
}
static __device__ inline uint pack2bf(float a, float b) {
  return (uint)f2bf(a) | ((uint)f2bf(b) << 16);
}

// ---- fp8 e4m3 (OCP) helpers: HW path + bit-exact-enough fallback ----
static __device__ inline uchar enc_fp8_byte(float f) {
#ifdef HW_FP8
  return (uchar)(__builtin_amdgcn_cvt_pk_fp8_f32(f, f, 0, false) & 0xff);
#else
  float a = fabsf(f);
  uint s = (f < 0.f) ? 0x80u : 0u;
  if (!(a > 0.f)) return (uchar)s;
  a = fminf(a, 448.f);
  uint b = __float_as_uint(a);
  int e = (int)(b >> 23) - 127;
  if (e < -6) {                       // denormal domain: multiples of 2^-9
    int q = (int)rintf(a * 512.f);
    if (q <= 0) return (uchar)s;
    if (q >= 8) return (uchar)(s | 0x08u);
    return (uchar)(s | (uint)q);
  }
  uint r = b + 0x7ffffu + ((b >> 20) & 1u);   // RTN-even at mantissa bit 20
  uint m = (r >> 20) & 7u;
  int ee = (int)(r >> 23) - 127 + 7;
  if (ee <= 0) return (uchar)(s | 0x08u);
  if (ee > 15) return (uchar)(s | 0x7eu);
  return (uchar)(s | ((uint)ee << 3) | m);
#endif
}

static __device__ inline float dec_fp8_byte(uint em_s) {   // fallback scalar decode
  uint s = (em_s & 0x80u) << 24;
  uint em = em_s & 0x7fu;
  float v;
  if (em < 8) v = (float)em * (1.f / 512.f);
  else v = __uint_as_float((em + (120u << 3)) << 20);
  return __uint_as_float(__float_as_uint(v) | s);
}

static __device__ inline void dec_fp8x4(uint u, float* dst) {
#ifdef HW_FP8
  auto a = __builtin_amdgcn_cvt_pk_f32_fp8((int)u, false);
  auto b = __builtin_amdgcn_cvt_pk_f32_fp8((int)u, true);
  dst[0] = a[0]; dst[1] = a[1]; dst[2] = b[0]; dst[3] = b[1];
#else
  dst[0] = dec_fp8_byte(u & 0xffu);
  dst[1] = dec_fp8_byte((u >> 8) & 0xffu);
  dst[2] = dec_fp8_byte((u >> 16) & 0xffu);
  dst[3] = dec_fp8_byte(u >> 24);
#endif
}

// ---------------- utility ----------------
__global__ void zero_int_kernel(int* __restrict__ p, int n) {
  int i = blockIdx.x * blockDim.x + threadIdx.x;
  if (i < n) p[i] = 0;
}

// ---------------- bucketed CSR build (also produces offs, dinv) ----------------
__global__ __launch_bounds__(256) void bucket_count_kernel(const int* __restrict__ dst,
    int* __restrict__ bucket_count, int e, int nbk) {
  __shared__ int hist[512];
  int t = threadIdx.x;
  for (int i = t; i < nbk; i += 256) hist[i] = 0;
  __syncthreads();
  int lo = blockIdx.x * EPB;
  int hi = lo + EPB; if (hi > e) hi = e;
  for (int i = lo + t; i < hi; i += 256) atomicAdd(&hist[dst[i] >> BKT_SHIFT], 1);
  __syncthreads();
  for (int i = t; i < nbk; i += 256) {
    int c = hist[i];
    if (c) atomicAdd(&bucket_count[i], c);
  }
}

__global__ __launch_bounds__(512) void bucket_scan_kernel(const int* __restrict__ bucket_count,
    int* __restrict__ bucket_base, int* __restrict__ bucket_cursor, int nbk) {
  __shared__ int sh[512];
  int t = threadIdx.x;
  int v = (t < nbk) ? bucket_count[t] : 0;
  sh[t] = v;
  __syncthreads();
  for (int d = 1; d < 512; d <<= 1) {
    int u = (t >= d) ? sh[t - d] : 0;
    __syncthreads();
    sh[t] += u;
    __syncthreads();
  }
  if (t < nbk) {
    int ex = sh[t] - v;
    bucket_base[t] = ex;
    bucket_cursor[t] = ex;
  }
  if (t == 511) bucket_base[nbk] = sh[511];
}

// pairs packed: (src << 8) | (dst & 255); src < 2^17, bucket-local dst < 256
__global__ __launch_bounds__(256) void bucket_fill_kernel(const int* __restrict__ src,
    const int* __restrict__ dst, int* __restrict__ bucket_cursor,
    uint* __restrict__ pairs, int e, int nbk) {
  __shared__ int hist[512];
  int t = threadIdx.x;
  for (int i = t; i < nbk; i += 256) hist[i] = 0;
  __syncthreads();
  int lo = blockIdx.x * EPB;
  int hi = lo + EPB; if (hi > e) hi = e;
  for (int i = lo + t; i < hi; i += 256) atomicAdd(&hist[dst[i] >> BKT_SHIFT], 1);
  __syncthreads();
  for (int i = t; i < nbk; i += 256) {
    int c = hist[i];
    hist[i] = c ? atomicAdd(&bucket_cursor[i], c) : 0;   // hist now = write cursor
  }
  __syncthreads();
  for (int i = lo + t; i < hi; i += 256) {
    int s = src[i], d = dst[i];
    int pos = atomicAdd(&hist[d >> BKT_SHIFT], 1);
    pairs[pos] = ((uint)s << 8) | (uint)(d & 255);
  }
}

// one block per bucket: count per-node in LDS, scan -> offs & dinv, then scatter
__global__ __launch_bounds__(256) void bucket_scatter_kernel(const uint* __restrict__ pairs,
    const int* __restrict__ bucket_base, int* __restrict__ offs,
    float* __restrict__ dinv, int* __restrict__ csr_src, int n, int nbk) {
  __shared__ int cnt[256];
  __shared__ int pre[256];
  int b = blockIdx.x, t = threadIdx.x;
  int node0 = b << BKT_SHIFT;
  bool valid_node = (node0 + t) < n;
  cnt[t] = 0;
  __syncthreads();
  int lo = bucket_base[b], hi = bucket_base[b + 1];
  for (int i = lo + t; i < hi; i += 256)
    atomicAdd(&cnt[pairs[i] & 255u], 1);
  __syncthreads();
  int v = cnt[t];
  pre[t] = v;
  __syncthreads();
  for (int d = 1; d < 256; d <<= 1) {
    int u = (t >= d) ? pre[t - d] : 0;
    __syncthreads();
    pre[t] += u;
    __syncthreads();
  }
  int off = lo + pre[t] - v;   // exclusive prefix within bucket + bucket base
  if (valid_node) {
    offs[node0 + t] = off;
    dinv[node0 + t] = rsqrtf((float)(v + 1));   // +1: self-loop
  }
  __syncthreads();
  cnt[t] = off;   // reuse as cursor
  __syncthreads();
  for (int i = lo + t; i < hi; i += 256) {
    uint pp = pairs[i];
    int pos = atomicAdd(&cnt[pp & 255u], 1);
    csr_src[pos] = (int)(pp >> 8);
  }
  if (b == 0 && t == 0) offs[n] = bucket_base[nbk];
}

// ---------------- weight transpose+convert: wt[c][k] = bf16(W[k][c]) ----------------
__global__ void convert_wt_kernel(const float* __restrict__ W, ushort* __restrict__ wt,
                                  int KK) {
  int i = blockIdx.x * 256 + threadIdx.x;   // over 128*KK
  if (i < 128 * KK) {
    int c = i / KK, k = i - c * KK;
    wt[i] = f2bf(W[k * 128 + c]);
  }
}

// ---------------- MFMA GEMM: C[M x 128] = A[M x K] @ W[K x 128] ----------------
// FP8OUT: write fp8(e4m3) of (o * dinv[row] * 16) -- GCN message rows.
// else:   write bf16 (+bias)(+relu).
template<typename TA, int K, bool BIAS, bool RELU, bool FP8OUT>
__global__ __launch_bounds__(256) void mfma_gemm_kernel(const TA* __restrict__ A,
    const ushort* __restrict__ Wt, const float* __restrict__ bias,
    void* __restrict__ Cout, const float* __restrict__ dinv, int M) {
  __shared__ ushort As[64 * K];
  __shared__ ushort Ws[128 * K];
  const int tid = threadIdx.x;
  const int r0 = blockIdx.x * 64;

  if constexpr (sizeof(TA) == 4) {
    constexpr int C4 = K / 4;
    const float4* A4 = (const float4*)A;
    #pragma unroll
    for (int i = tid; i < 64 * C4; i += 256) {
      int r = i / C4, c4 = i - r * C4;
      int row = r0 + r;
      float4 v = make_float4(0.f, 0.f, 0.f, 0.f);
      if (row < M) v = A4[(size_t)row * C4 + c4];
      ushort4 u;
      u.x = f2bf(v.x); u.y = f2bf(v.y); u.z = f2bf(v.z); u.w = f2bf(v.w);
      int elem = (r * K + c4 * 4) ^ ((r & 7) << 3);
      *(ushort4*)&As[elem] = u;
    }
  } else {
    constexpr int C8 = K / 8;
    const uint4* A4 = (const uint4*)A;
    #pragma unroll
    for (int i = tid; i < 64 * C8; i += 256) {
      int r = i / C8, c8 = i - r * C8;
      int row = r0 + r;
      uint4 v = make_uint4(0u, 0u, 0u, 0u);
      if (row < M) v = A4[(size_t)row * C8 + c8];
      int elem = (r * K + c8 * 8) ^ ((r & 7) << 3);
      *(uint4*)&As[elem] = v;
    }
  }
  {
    constexpr int C8 = K / 8;
    const uint4* W4 = (const uint4*)Wt;
    #pragma unroll
    for (int i = tid; i < 128 * C8; i += 256) {
      int c = i / C8, k8 = i - c * C8;
      uint4 v = W4[i];
      int elem = (c * K + k8 * 8) ^ ((c & 7) << 3);
      *(uint4*)&Ws[elem] = v;
    }
  }
  __syncthreads();

  const int l = tid & 63;
  const int wid = tid >> 6;
  const int lr = l & 15;       // fragment row/col within 16
  const int lk = l >> 4;       // k sub-block 0..3
  const int wr = wid * 16;     // wave's row base in tile
  f32x4 acc[8];
  #pragma unroll
  for (int cb = 0; cb < 8; ++cb) acc[cb] = (f32x4){0.f, 0.f, 0.f, 0.f};

  #pragma unroll
  for (int kc = 0; kc < K / 32; ++kc) {
    int ar = wr + lr;
    bf16x8 af = *(const bf16x8*)&As[(ar * K + kc * 32 + lk * 8) ^ ((ar & 7) << 3)];
    #pragma unroll
    for (int cb = 0; cb < 8; ++cb) {
      int col = cb * 16 + lr;
      bf16x8 bfr = *(const bf16x8*)&Ws[(col * K + kc * 32 + lk * 8) ^ ((col & 7) << 3)];
      acc[cb] = __builtin_amdgcn_mfma_f32_16x16x32_bf16(af, bfr, acc[cb], 0, 0, 0);
    }
  }

  if constexpr (FP8OUT) {
    uchar* C8p = (uchar*)Cout;
    float dv[4];
    #pragma unroll
    for (int j = 0; j < 4; ++j) {
      int row = r0 + wr + lk * 4 + j;
      dv[j] = (row < M) ? dinv[row] * FP8_SCALE : 0.f;
    }
    #pragma unroll
    for (int cb = 0; cb < 8; ++cb) {
      int col = cb * 16 + lr;
      #pragma unroll
      for (int j = 0; j < 4; ++j) {
        int row = r0 + wr + lk * 4 + j;
        if (row < M) {
          C8p[(size_t)row * 128 + col] = enc_fp8_byte(acc[cb][j] * dv[j]);
        }
      }
    }
  } else {
    ushort* Cb = (ushort*)Cout;
    #pragma unroll
    for (int cb = 0; cb < 8; ++cb) {
      int col = cb * 16 + lr;
      float bb = BIAS ? bias[col] : 0.f;
      #pragma unroll
      for (int j = 0; j < 4; ++j) {
        int row = r0 + wr + lk * 4 + j;
        if (row < M) {
          float o = acc[cb][j] + bb;
          if (RELU) o = fmaxf(o, 0.f);
          Cb[(size_t)row * 128 + col] = f2bf(o);
        }
      }
    }
  }
}

// ---------------- GCN aggregation + residual update ----------------
// xws rows are fp8: xws[i] = xw[i]*dinv[i]*16. Update:
//   x[i] (bf16) += relu( (dinv[i]/16) * (sum_{src} xws[src] + xws[i]) + bias )
// One wave per node; 4 edge-groups x 16 lanes (8B fp8 per lane); 4-deep unroll.
__global__ __launch_bounds__(256) void agg_update_kernel(
    const uchar* __restrict__ xws, ushort* __restrict__ x,
    const int* __restrict__ csr_src, const int* __restrict__ offs,
    const float* __restrict__ dinv, const float* __restrict__ bias, int n) {
  int node = blockIdx.x * 4 + (threadIdx.x >> 6);
  if (node >= n) return;
  int lane = threadIdx.x & 63;
  int grp = lane >> 4;       // edge group 0..3
  int cl = lane & 15;        // row chunk: dims 8*cl .. 8*cl+7
  const uint2* xw2 = (const uint2*)xws;   // row = 16 uint2 (128 fp8)
  float acc[8];
  #pragma unroll
  for (int k = 0; k < 8; ++k) acc[k] = 0.f;

  auto add_row = [&](uint2 v) {
    float f[4];
    dec_fp8x4(v.x, f);
    acc[0] += f[0]; acc[1] += f[1]; acc[2] += f[2]; acc[3] += f[3];
    dec_fp8x4(v.y, f);
    acc[4] += f[0]; acc[5] += f[1]; acc[6] += f[2]; acc[7] += f[3];
  };

  int beg = offs[node], end = offs[node + 1];
  int j = beg + grp;
  for (; j + 12 < end; j += 16) {
    int s0 = csr_src[j];
    int s1 = csr_src[j + 4];
    int s2 = csr_src[j + 8];
    int s3 = csr_src[j + 12];
    uint2 v0 = xw2[(size_t)s0 * 16 + cl];
    uint2 v1 = xw2[(size_t)s1 * 16 + cl];
    uint2 v2 = xw2[(size_t)s2 * 16 + cl];
    uint2 v3 = xw2[(size_t)s3 * 16 + cl];
    add_row(v0); add_row(v1); add_row(v2); add_row(v3);
  }
  for (; j + 4 < end; j += 8) {
    int s0 = csr_src[j];
    int s1 = csr_src[j + 4];
    uint2 v0 = xw2[(size_t)s0 * 16 + cl];
    uint2 v1 = xw2[(size_t)s1 * 16 + cl];
    add_row(v0); add_row(v1);
  }
  if (j < end) {
    uint2 v0 = xw2[(size_t)csr_src[j] * 16 + cl];
    add_row(v0);
  }
  if (grp == 0) {   // self-loop term
    uint2 vi = xw2[(size_t)node * 16 + cl];
    add_row(vi);
  }
  #pragma unroll
  for (int k = 0; k < 8; ++k) {
    acc[k] += __shfl_xor(acc[k], 16);
    acc[k] += __shfl_xor(acc[k], 32);
  }
  if (grp == 0) {
    float di = dinv[node] * FP8_INV_SCALE;
    const float4* b4 = (const float4*)bias;
    float4 bb0 = b4[cl * 2], bb1 = b4[cl * 2 + 1];
    float bbv[8] = {bb0.x, bb0.y, bb0.z, bb0.w, bb1.x, bb1.y, bb1.z, bb1.w};
    uint4* xv4 = (uint4*)x;
    size_t xi = (size_t)node * 16 + cl;
    uint4 xv = xv4[xi];
    uint xu[4] = {xv.x, xv.y, xv.z, xv.w};
    float o[8];
    #pragma unroll
    for (int q = 0; q < 4; ++q) {
      float lo = __uint_as_float(xu[q] << 16);
      float hi = __uint_as_float(xu[q] & 0xffff0000u);
      o[2 * q]     = fmaxf(fmaf(acc[2 * q],     di, bbv[2 * q]),     0.f) + lo;
      o[2 * q + 1] = fmaxf(fmaf(acc[2 * q + 1], di, bbv[2 * q + 1]), 0.f) + hi;
    }
    uint4 ou;
    ou.x = pack2bf(o[0], o[1]);
    ou.y = pack2bf(o[2], o[3]);
    ou.z = pack2bf(o[4], o[5]);
    ou.w = pack2bf(o[6], o[7]);
    xv4[xi] = ou;
  }
}

// ---------------- graph boundaries from sorted batch ----------------
__global__ void bounds_kernel(const int* __restrict__ batch, int* __restrict__ startg,
                              int n, int ng) {
  int i = blockIdx.x * blockDim.x + threadIdx.x;
  if (i > n) return;
  int bi = (i < n) ? batch[i] : ng;
  int bp = (i == 0) ? -1 : batch[i - 1];
  for (int g = bp + 1; g <= bi && g <= ng; ++g) startg[g] = i;
}

// ---------------- per-graph mean/max pooling: 2-stage (bf16 x) ----------------
__global__ __launch_bounds__(128) void pool_partial_kernel(const ushort* __restrict__ x,
    const int* __restrict__ startg, float* __restrict__ psum, float* __restrict__ pmax) {
  int g = blockIdx.x / PCH, ch = blockIdx.x % PCH, c = threadIdx.x;
  int s0 = startg[g], s1 = startg[g + 1];
  int cnt = s1 - s0;
  int len = (cnt + PCH - 1) / PCH;
  int lo = s0 + ch * len;
  int hi = lo + len; if (hi > s1) hi = s1;
  float sum = 0.f, mx = -INFINITY;
  for (int r = lo; r < hi; ++r) {
    float v = bf2f(x[(size_t)r * HD + c]);
    sum += v;
    mx = fmaxf(mx, v);
  }
  psum[(size_t)blockIdx.x * HD + c] = sum;
  pmax[(size_t)blockIdx.x * HD + c] = mx;
}

__global__ __launch_bounds__(128) void pool_final_kernel(const float* __restrict__ psum,
    const float* __restrict__ pmax, const int* __restrict__ startg,
    float* __restrict__ repr) {
  int g = blockIdx.x, c = threadIdx.x;
  float sum = 0.f, mx = -INFINITY;
  #pragma unroll
  for (int ch = 0; ch < PCH; ++ch) {
    sum += psum[(size_t)(g * PCH + ch) * HD + c];
    mx = fmaxf(mx, pmax[(size_t)(g * PCH + ch) * HD + c]);
  }
  int cnt = startg[g + 1] - startg[g];
  float denom = (float)(cnt > 0 ? cnt : 1);
  repr[g * 256 + c] = sum / denom;
  repr[g * 256 + 128 + c] = mx;
}

// ---------------- decoder + value heads (one block per graph) ----------------
__global__ __launch_bounds__(128) void heads_kernel(
    const float* __restrict__ repr,
    const float* __restrict__ dw1, const float* __restrict__ db1,
    const float* __restrict__ dw2, const float* __restrict__ db2,
    const float* __restrict__ dw3, const float* __restrict__ db3,
    const float* __restrict__ vw1, const float* __restrict__ vb1,
    const float* __restrict__ vw2, const float* __restrict__ vb2,
    float* __restrict__ out, int ng) {
  __shared__ float rep[256];
  __shared__ float h1[128];
  __shared__ float h2[64];
  __shared__ float v1[128];
  int g = blockIdx.x, t = threadIdx.x;
  rep[t] = repr[g * 256 + t];
  rep[128 + t] = repr[g * 256 + 128 + t];
  __syncthreads();
  float a = db1[t], b = vb1[t];
  for (int k = 0; k < 256; ++k) {
    float rv = rep[k];
    a = fmaf(rv, dw1[k * 128 + t], a);
    b = fmaf(rv, vw1[k * 128 + t], b);
  }
  h1[t] = fmaxf(a, 0.f);
  v1[t] = fmaxf(b, 0.f);
  __syncthreads();
  if (t < 64) {
    float c = db2[t];
    for (int k = 0; k < 128; ++k) c = fmaf(h1[k], dw2[k * 64 + t], c);
    h2[t] = fmaxf(c, 0.f);
  }
  __syncthreads();
  if (t == 0) {
    float l0 = db3[0], l2 = db3[2];
    for (int k = 0; k < 64; ++k) {
      l0 = fmaf(h2[k], dw3[k * 3 + 0], l0);
      l2 = fmaf(h2[k], dw3[k * 3 + 2], l2);
    }
    out[g] = 1.f / (1.f + expf(-l0));          // adaptation_prob
    out[ng + g] = 1.0f;                        // softmax over 1 element == 1
    out[2 * ng + g] = 1.f / (1.f + expf(-l2)); // urgency_score
    float v = vb2[0];
    for (int k = 0; k < 128; ++k) v = fmaf(v1[k], vw2[k], v);
    out[3 * ng + g] = v;                       // value_estimate
  }
}

// ---------------- launch ----------------
extern "C" void kernel_launch(void* const* d_in, const int* in_sizes, int n_in,
                              void* d_out, int out_size, void* d_ws, size_t ws_size,
                              hipStream_t stream) {
  const float* nf     = (const float*)d_in[0];
  const int*   ei     = (const int*)d_in[1];
  const int*   batch  = (const int*)d_in[2];
  const float* enc_w1 = (const float*)d_in[3];
  const float* enc_b1 = (const float*)d_in[4];
  const float* enc_w2 = (const float*)d_in[5];
  const float* enc_b2 = (const float*)d_in[6];
  const float* gcn_w  = (const float*)d_in[7];
  const float* gcn_b  = (const float*)d_in[8];
  const float* dec_w1 = (const float*)d_in[9];
  const float* dec_b1 = (const float*)d_in[10];
  const float* dec_w2 = (const float*)d_in[11];
  const float* dec_b2 = (const float*)d_in[12];
  const float* dec_w3 = (const float*)d_in[13];
  const float* dec_b3 = (const float*)d_in[14];
  const float* val_w1 = (const float*)d_in[15];
  const float* val_b1 = (const float*)d_in[16];
  const float* val_w2 = (const float*)d_in[17];
  const float* val_b2 = (const float*)d_in[18];
  float* out = (float*)d_out;

  const int n = in_sizes[0] / FD;           // 100000
  const int e = in_sizes[1] / 2;            // 1600000
  const int L = in_sizes[7] / (HD * HD);    // 3
  const int G = out_size / 4;               // 64

  // workspace carve
  char* p = (char*)d_ws;
  auto carve = [&](size_t bytes) {
    void* r = (void*)p;
    p += (bytes + 255) & ~(size_t)255;
    return r;
  };
  ushort* x       = (ushort*)carve((size_t)n * HD * 2);    // bf16 x
  ushort* xwb     = (ushort*)carve((size_t)n * HD * 2);    // bf16 encoder tmp
  uchar*  xw8     = (uchar*)carve((size_t)n * HD);         // fp8 message rows
  float*  dinv    = (float*)carve((size_t)n * 4);
  int*    offs    = (int*)carve((size_t)(n + 1) * 4);
  int*    csr_src = (int*)carve((size_t)e * 4);
  float*  repr    = (float*)carve((size_t)G * 256 * 4);
  int*    startg  = (int*)carve((size_t)(G + 1) * 4);
  float*  psum    = (float*)carve((size_t)G * PCH * HD * 4);
  float*  pmax    = (float*)carve((size_t)G * PCH * HD * 4);
  const int nbk   = (n + (1 << BKT_SHIFT) - 1) >> BKT_SHIFT;   // 391 buckets
  int*    bucket_count  = (int*)carve((size_t)nbk * 4);
  int*    bucket_base   = (int*)carve((size_t)(nbk + 1) * 4);
  int*    bucket_cursor = (int*)carve((size_t)nbk * 4);
  ushort* wt_e1   = (ushort*)carve((size_t)128 * FD * 2);      // enc_w1^T bf16
  ushort* wt_e2   = (ushort*)carve((size_t)128 * HD * 2);      // enc_w2^T bf16
  ushort* wt_g    = (ushort*)carve((size_t)3 * 128 * HD * 2);  // gcn_w^T bf16
  // pairs aliases xwb: CSR build completes before enc1 writes xwb (stream-ordered)
  uint*   pairs   = (uint*)xwb;

  const int gemm_grid = (n + 63) / 64;
  const int ebk_grid = (e + EPB - 1) / EPB;

  // ---- graph structure (before encoder so pairs can alias xwb) ----
  zero_int_kernel<<<(nbk + 255) / 256, 256, 0, stream>>>(bucket_count, nbk);
  bucket_count_kernel<<<ebk_grid, 256, 0, stream>>>(ei + e, bucket_count, e, nbk);
  bucket_scan_kernel<<<1, 512, 0, stream>>>(bucket_count, bucket_base, bucket_cursor, nbk);
  bucket_fill_kernel<<<ebk_grid, 256, 0, stream>>>(ei, ei + e, bucket_cursor, pairs, e, nbk);
  bucket_scatter_kernel<<<nbk, 256, 0, stream>>>(pairs, bucket_base, offs, dinv, csr_src, n, nbk);

  // ---- weight transposes (tiny) ----
  convert_wt_kernel<<<(128 * FD + 255) / 256, 256, 0, stream>>>(enc_w1, wt_e1, FD);
  convert_wt_kernel<<<(128 * HD + 255) / 256, 256, 0, stream>>>(enc_w2, wt_e2, HD);
  for (int l = 0; l < L; ++l)
    convert_wt_kernel<<<(128 * HD + 255) / 256, 256, 0, stream>>>(
        gcn_w + (size_t)l * HD * HD, wt_g + (size_t)l * 128 * HD, HD);

  // ---- encoder: nf @ w1 -> relu (bf16), @ w2 -> x (bf16) ----
  mfma_gemm_kernel<float, FD, true, true, false><<<gemm_grid, 256, 0, stream>>>(
      nf, wt_e1, enc_b1, xwb, nullptr, n);
  mfma_gemm_kernel<ushort, HD, true, false, false><<<gemm_grid, 256, 0, stream>>>(
      xwb, wt_e2, enc_b2, x, nullptr, n);

  // ---- GCN layers: GEMM writes fp8 rows pre-scaled by dinv*16 ----
  for (int l = 0; l < L; ++l) {
    mfma_gemm_kernel<ushort, HD, false, false, true><<<gemm_grid, 256, 0, stream>>>(
        x, wt_g + (size_t)l * 128 * HD, nullptr, xw8, dinv, n);
    agg_update_kernel<<<(n + 3) / 4, 256, 0, stream>>>(
        xw8, x, csr_src, offs, dinv, gcn_b + (size_t)l * HD, n);
  }

  // ---- pooling + heads ----
  bounds_kernel<<<(n + 1 + 255) / 256, 256, 0, stream>>>(batch, startg, n, G);
  pool_partial_kernel<<<G * PCH, 128, 0, stream>>>(x, startg, psum, pmax);
  pool_final_kernel<<<G, 128, 0, stream>>>(psum, pmax, startg, repr);
  heads_kernel<<<G, 128, 0, stream>>>(repr,
      dec_w1, dec_b1, dec_w2, dec_b2, dec_w3, dec_b3,
      val_w1, val_b1, val_w2, val_b2, out, G);
}

// Round 9
// 372.789 us; speedup vs baseline: 3.1414x; 1.1176x over previous
//
#include <hip/hip_runtime.h>
#include <math.h>

constexpr int HD = 128;   // hidden dim
constexpr int FD = 64;    // input feature dim
constexpr int PCH = 32;   // pooling chunks per graph
constexpr int BKT_SHIFT = 8;           // 256 nodes per bucket
constexpr int EPB = 8192;              // edges per block in bucket passes
constexpr float FP8_SCALE = 16.f;      // pre-scale before e4m3 quantization
constexpr float FP8_INV_SCALE = 1.f / 16.f;

typedef unsigned int uint;
typedef unsigned short ushort;
typedef unsigned char uchar;

using bf16x8 = __attribute__((ext_vector_type(8))) short;   // 4 VGPRs
using f32x4  = __attribute__((ext_vector_type(4))) float;

#if defined(__has_builtin)
#if __has_builtin(__builtin_amdgcn_cvt_pk_f32_fp8) && __has_builtin(__builtin_amdgcn_cvt_pk_fp8_f32)
#define HW_FP8 1
#endif
#endif

static __device__ inline ushort f2bf(float f) {   // round-to-nearest-even bf16
  uint u = __float_as_uint(f);
  return (ushort)((u + 0x7fffu + ((u >> 16) & 1u)) >> 16);
}
static __device__ inline float bf2f(ushort b) {
  return __uint_as_float((uint)b << 16);
}
static __device__ inline uint pack2bf(float a, float b) {
  return (uint)f2bf(a) | ((uint)f2bf(b) << 16);
}

// ---- fp8 e4m3 (OCP) helpers: HW path + fallback ----
static __device__ inline uchar enc_fp8_byte(float f) {
#ifdef HW_FP8
  return (uchar)(__builtin_amdgcn_cvt_pk_fp8_f32(f, f, 0, false) & 0xff);
#else
  float a = fabsf(f);
  uint s = (f < 0.f) ? 0x80u : 0u;
  if (!(a > 0.f)) return (uchar)s;
  a = fminf(a, 448.f);
  uint b = __float_as_uint(a);
  int e = (int)(b >> 23) - 127;
  if (e < -6) {                       // denormal domain: multiples of 2^-9
    int q = (int)rintf(a * 512.f);
    if (q <= 0) return (uchar)s;
    if (q >= 8) return (uchar)(s | 0x08u);
    return (uchar)(s | (uint)q);
  }
  uint r = b + 0x7ffffu + ((b >> 20) & 1u);   // RTN-even at mantissa bit 20
  uint m = (r >> 20) & 7u;
  int ee = (int)(r >> 23) - 127 + 7;
  if (ee <= 0) return (uchar)(s | 0x08u);
  if (ee > 15) return (uchar)(s | 0x7eu);
  return (uchar)(s | ((uint)ee << 3) | m);
#endif
}

static __device__ inline float dec_fp8_byte(uint em_s) {   // fallback scalar decode
  uint s = (em_s & 0x80u) << 24;
  uint em = em_s & 0x7fu;
  float v;
  if (em < 8) v = (float)em * (1.f / 512.f);
  else v = __uint_as_float((em + (120u << 3)) << 20);
  return __uint_as_float(__float_as_uint(v) | s);
}

static __device__ inline void dec_fp8x4(uint u, float* dst) {
#ifdef HW_FP8
  auto a = __builtin_amdgcn_cvt_pk_f32_fp8((int)u, false);
  auto b = __builtin_amdgcn_cvt_pk_f32_fp8((int)u, true);
  dst[0] = a[0]; dst[1] = a[1]; dst[2] = b[0]; dst[3] = b[1];
#else
  dst[0] = dec_fp8_byte(u & 0xffu);
  dst[1] = dec_fp8_byte((u >> 8) & 0xffu);
  dst[2] = dec_fp8_byte((u >> 16) & 0xffu);
  dst[3] = dec_fp8_byte(u >> 24);
#endif
}

// ---------------- utility ----------------
__global__ void zero_int_kernel(int* __restrict__ p, int n) {
  int i = blockIdx.x * blockDim.x + threadIdx.x;
  if (i < n) p[i] = 0;
}

// ---------------- bucketed CSR build (also produces offs, dinv) ----------------
__global__ __launch_bounds__(256) void bucket_count_kernel(const int* __restrict__ dst,
    int* __restrict__ bucket_count, int e, int nbk) {
  __shared__ int hist[512];
  int t = threadIdx.x;
  for (int i = t; i < nbk; i += 256) hist[i] = 0;
  __syncthreads();
  int lo = blockIdx.x * EPB;
  int hi = lo + EPB; if (hi > e) hi = e;
  for (int i = lo + t; i < hi; i += 256) atomicAdd(&hist[dst[i] >> BKT_SHIFT], 1);
  __syncthreads();
  for (int i = t; i < nbk; i += 256) {
    int c = hist[i];
    if (c) atomicAdd(&bucket_count[i], c);
  }
}

__global__ __launch_bounds__(512) void bucket_scan_kernel(const int* __restrict__ bucket_count,
    int* __restrict__ bucket_base, int* __restrict__ bucket_cursor, int nbk) {
  __shared__ int sh[512];
  int t = threadIdx.x;
  int v = (t < nbk) ? bucket_count[t] : 0;
  sh[t] = v;
  __syncthreads();
  for (int d = 1; d < 512; d <<= 1) {
    int u = (t >= d) ? sh[t - d] : 0;
    __syncthreads();
    sh[t] += u;
    __syncthreads();
  }
  if (t < nbk) {
    int ex = sh[t] - v;
    bucket_base[t] = ex;
    bucket_cursor[t] = ex;
  }
  if (t == 511) bucket_base[nbk] = sh[511];
}

// pairs packed: (src << 8) | (dst & 255); src < 2^17, bucket-local dst < 256
__global__ __launch_bounds__(256) void bucket_fill_kernel(const int* __restrict__ src,
    const int* __restrict__ dst, int* __restrict__ bucket_cursor,
    uint* __restrict__ pairs, int e, int nbk) {
  __shared__ int hist[512];
  int t = threadIdx.x;
  for (int i = t; i < nbk; i += 256) hist[i] = 0;
  __syncthreads();
  int lo = blockIdx.x * EPB;
  int hi = lo + EPB; if (hi > e) hi = e;
  for (int i = lo + t; i < hi; i += 256) atomicAdd(&hist[dst[i] >> BKT_SHIFT], 1);
  __syncthreads();
  for (int i = t; i < nbk; i += 256) {
    int c = hist[i];
    hist[i] = c ? atomicAdd(&bucket_cursor[i], c) : 0;   // hist now = write cursor
  }
  __syncthreads();
  for (int i = lo + t; i < hi; i += 256) {
    int s = src[i], d = dst[i];
    int pos = atomicAdd(&hist[d >> BKT_SHIFT], 1);
    pairs[pos] = ((uint)s << 8) | (uint)(d & 255);
  }
}

// one block per bucket: count per-node in LDS, scan -> offs & dinv, then scatter
__global__ __launch_bounds__(256) void bucket_scatter_kernel(const uint* __restrict__ pairs,
    const int* __restrict__ bucket_base, int* __restrict__ offs,
    float* __restrict__ dinv, int* __restrict__ csr_src, int n, int nbk) {
  __shared__ int cnt[256];
  __shared__ int pre[256];
  int b = blockIdx.x, t = threadIdx.x;
  int node0 = b << BKT_SHIFT;
  bool valid_node = (node0 + t) < n;
  cnt[t] = 0;
  __syncthreads();
  int lo = bucket_base[b], hi = bucket_base[b + 1];
  for (int i = lo + t; i < hi; i += 256)
    atomicAdd(&cnt[pairs[i] & 255u], 1);
  __syncthreads();
  int v = cnt[t];
  pre[t] = v;
  __syncthreads();
  for (int d = 1; d < 256; d <<= 1) {
    int u = (t >= d) ? pre[t - d] : 0;
    __syncthreads();
    pre[t] += u;
    __syncthreads();
  }
  int off = lo + pre[t] - v;   // exclusive prefix within bucket + bucket base
  if (valid_node) {
    offs[node0 + t] = off;
    dinv[node0 + t] = rsqrtf((float)(v + 1));   // +1: self-loop
  }
  __syncthreads();
  cnt[t] = off;   // reuse as cursor
  __syncthreads();
  for (int i = lo + t; i < hi; i += 256) {
    uint pp = pairs[i];
    int pos = atomicAdd(&cnt[pp & 255u], 1);
    csr_src[pos] = (int)(pp >> 8);
  }
  if (b == 0 && t == 0) offs[n] = bucket_base[nbk];
}

// ---------------- weight transpose+convert: wt[c][k] = bf16(W[k][c]) ----------------
__global__ void convert_wt_kernel(const float* __restrict__ W, ushort* __restrict__ wt,
                                  int KK) {
  int i = blockIdx.x * 256 + threadIdx.x;   // over 128*KK
  if (i < 128 * KK) {
    int c = i / KK, k = i - c * KK;
    wt[i] = f2bf(W[k * 128 + c]);
  }
}

// ---------------- MFMA GEMM: C[M x 128] = A[M x K] @ W[K x 128] ----------------
// FP8OUT: write fp8(e4m3) of (o * dinv[row] * 16) -- GCN message rows.
// else:   write bf16 (+bias)(+relu).
template<typename TA, int K, bool BIAS, bool RELU, bool FP8OUT>
__global__ __launch_bounds__(256) void mfma_gemm_kernel(const TA* __restrict__ A,
    const ushort* __restrict__ Wt, const float* __restrict__ bias,
    void* __restrict__ Cout, const float* __restrict__ dinv, int M) {
  __shared__ ushort As[64 * K];
  __shared__ ushort Ws[128 * K];
  const int tid = threadIdx.x;
  const int r0 = blockIdx.x * 64;

  if constexpr (sizeof(TA) == 4) {
    constexpr int C4 = K / 4;
    const float4* A4 = (const float4*)A;
    #pragma unroll
    for (int i = tid; i < 64 * C4; i += 256) {
      int r = i / C4, c4 = i - r * C4;
      int row = r0 + r;
      float4 v = make_float4(0.f, 0.f, 0.f, 0.f);
      if (row < M) v = A4[(size_t)row * C4 + c4];
      ushort4 u;
      u.x = f2bf(v.x); u.y = f2bf(v.y); u.z = f2bf(v.z); u.w = f2bf(v.w);
      int elem = (r * K + c4 * 4) ^ ((r & 7) << 3);
      *(ushort4*)&As[elem] = u;
    }
  } else {
    constexpr int C8 = K / 8;
    const uint4* A4 = (const uint4*)A;
    #pragma unroll
    for (int i = tid; i < 64 * C8; i += 256) {
      int r = i / C8, c8 = i - r * C8;
      int row = r0 + r;
      uint4 v = make_uint4(0u, 0u, 0u, 0u);
      if (row < M) v = A4[(size_t)row * C8 + c8];
      int elem = (r * K + c8 * 8) ^ ((r & 7) << 3);
      *(uint4*)&As[elem] = v;
    }
  }
  {
    constexpr int C8 = K / 8;
    const uint4* W4 = (const uint4*)Wt;
    #pragma unroll
    for (int i = tid; i < 128 * C8; i += 256) {
      int c = i / C8, k8 = i - c * C8;
      uint4 v = W4[i];
      int elem = (c * K + k8 * 8) ^ ((c & 7) << 3);
      *(uint4*)&Ws[elem] = v;
    }
  }
  __syncthreads();

  const int l = tid & 63;
  const int wid = tid >> 6;
  const int lr = l & 15;       // fragment row/col within 16
  const int lk = l >> 4;       // k sub-block 0..3
  const int wr = wid * 16;     // wave's row base in tile
  f32x4 acc[8];
  #pragma unroll
  for (int cb = 0; cb < 8; ++cb) acc[cb] = (f32x4){0.f, 0.f, 0.f, 0.f};

  #pragma unroll
  for (int kc = 0; kc < K / 32; ++kc) {
    int ar = wr + lr;
    bf16x8 af = *(const bf16x8*)&As[(ar * K + kc * 32 + lk * 8) ^ ((ar & 7) << 3)];
    #pragma unroll
    for (int cb = 0; cb < 8; ++cb) {
      int col = cb * 16 + lr;
      bf16x8 bfr = *(const bf16x8*)&Ws[(col * K + kc * 32 + lk * 8) ^ ((col & 7) << 3)];
      acc[cb] = __builtin_amdgcn_mfma_f32_16x16x32_bf16(af, bfr, acc[cb], 0, 0, 0);
    }
  }

  if constexpr (FP8OUT) {
    uchar* C8p = (uchar*)Cout;
    float dv[4];
    #pragma unroll
    for (int j = 0; j < 4; ++j) {
      int row = r0 + wr + lk * 4 + j;
      dv[j] = (row < M) ? dinv[row] * FP8_SCALE : 0.f;
    }
    #pragma unroll
    for (int cb = 0; cb < 8; ++cb) {
      int col = cb * 16 + lr;
      #pragma unroll
      for (int j = 0; j < 4; ++j) {
        int row = r0 + wr + lk * 4 + j;
        if (row < M) {
          C8p[(size_t)row * 128 + col] = enc_fp8_byte(acc[cb][j] * dv[j]);
        }
      }
    }
  } else {
    ushort* Cb = (ushort*)Cout;
    #pragma unroll
    for (int cb = 0; cb < 8; ++cb) {
      int col = cb * 16 + lr;
      float bb = BIAS ? bias[col] : 0.f;
      #pragma unroll
      for (int j = 0; j < 4; ++j) {
        int row = r0 + wr + lk * 4 + j;
        if (row < M) {
          float o = acc[cb][j] + bb;
          if (RELU) o = fmaxf(o, 0.f);
          Cb[(size_t)row * 128 + col] = f2bf(o);
        }
      }
    }
  }
}

// ---------------- GCN aggregation + residual update ----------------
// xws rows are fp8: xws[i] = xw[i]*dinv[i]*16. Update:
//   x[i] (bf16) += relu( (dinv[i]/16) * (sum_{src} xws[src] + xws[i]) + bias )
__global__ __launch_bounds__(256) void agg_update_kernel(
    const uchar* __restrict__ xws, ushort* __restrict__ x,
    const int* __restrict__ csr_src, const int* __restrict__ offs,
    const float* __restrict__ dinv, const float* __restrict__ bias, int n) {
  int node = blockIdx.x * 4 + (threadIdx.x >> 6);
  if (node >= n) return;
  int lane = threadIdx.x & 63;
  int grp = lane >> 4;       // edge group 0..3
  int cl = lane & 15;        // row chunk: dims 8*cl .. 8*cl+7
  const uint2* xw2 = (const uint2*)xws;   // row = 16 uint2 (128 fp8)
  float acc[8];
  #pragma unroll
  for (int k = 0; k < 8; ++k) acc[k] = 0.f;

  auto add_row = [&](uint2 v) {
    float f[4];
    dec_fp8x4(v.x, f);
    acc[0] += f[0]; acc[1] += f[1]; acc[2] += f[2]; acc[3] += f[3];
    dec_fp8x4(v.y, f);
    acc[4] += f[0]; acc[5] += f[1]; acc[6] += f[2]; acc[7] += f[3];
  };

  int beg = offs[node], end = offs[node + 1];
  int j = beg + grp;
  for (; j + 12 < end; j += 16) {
    int s0 = csr_src[j];
    int s1 = csr_src[j + 4];
    int s2 = csr_src[j + 8];
    int s3 = csr_src[j + 12];
    uint2 v0 = xw2[(size_t)s0 * 16 + cl];
    uint2 v1 = xw2[(size_t)s1 * 16 + cl];
    uint2 v2 = xw2[(size_t)s2 * 16 + cl];
    uint2 v3 = xw2[(size_t)s3 * 16 + cl];
    add_row(v0); add_row(v1); add_row(v2); add_row(v3);
  }
  for (; j + 4 < end; j += 8) {
    int s0 = csr_src[j];
    int s1 = csr_src[j + 4];
    uint2 v0 = xw2[(size_t)s0 * 16 + cl];
    uint2 v1 = xw2[(size_t)s1 * 16 + cl];
    add_row(v0); add_row(v1);
  }
  if (j < end) {
    uint2 v0 = xw2[(size_t)csr_src[j] * 16 + cl];
    add_row(v0);
  }
  if (grp == 0) {   // self-loop term
    uint2 vi = xw2[(size_t)node * 16 + cl];
    add_row(vi);
  }
  #pragma unroll
  for (int k = 0; k < 8; ++k) {
    acc[k] += __shfl_xor(acc[k], 16);
    acc[k] += __shfl_xor(acc[k], 32);
  }
  if (grp == 0) {
    float di = dinv[node] * FP8_INV_SCALE;
    const float4* b4 = (const float4*)bias;
    float4 bb0 = b4[cl * 2], bb1 = b4[cl * 2 + 1];
    float bbv[8] = {bb0.x, bb0.y, bb0.z, bb0.w, bb1.x, bb1.y, bb1.z, bb1.w};
    uint4* xv4 = (uint4*)x;
    size_t xi = (size_t)node * 16 + cl;
    uint4 xv = xv4[xi];
    uint xu[4] = {xv.x, xv.y, xv.z, xv.w};
    float o[8];
    #pragma unroll
    for (int q = 0; q < 4; ++q) {
      float lo = __uint_as_float(xu[q] << 16);
      float hi = __uint_as_float(xu[q] & 0xffff0000u);
      o[2 * q]     = fmaxf(fmaf(acc[2 * q],     di, bbv[2 * q]),     0.f) + lo;
      o[2 * q + 1] = fmaxf(fmaf(acc[2 * q + 1], di, bbv[2 * q + 1]), 0.f) + hi;
    }
    uint4 ou;
    ou.x = pack2bf(o[0], o[1]);
    ou.y = pack2bf(o[2], o[3]);
    ou.z = pack2bf(o[4], o[5]);
    ou.w = pack2bf(o[6], o[7]);
    xv4[xi] = ou;
  }
}

// ---------------- graph boundaries from sorted batch ----------------
__global__ void bounds_kernel(const int* __restrict__ batch, int* __restrict__ startg,
                              int n, int ng) {
  int i = blockIdx.x * blockDim.x + threadIdx.x;
  if (i > n) return;
  int bi = (i < n) ? batch[i] : ng;
  int bp = (i == 0) ? -1 : batch[i - 1];
  for (int g = bp + 1; g <= bi && g <= ng; ++g) startg[g] = i;
}

// ---------------- per-graph mean/max pooling: 2-stage, vectorized ----------------
// 256 threads: 16 row-groups x 16 col-groups (uint4 = 8 bf16 per thread).
__global__ __launch_bounds__(256) void pool_partial_kernel(const ushort* __restrict__ x,
    const int* __restrict__ startg, float* __restrict__ psum, float* __restrict__ pmax) {
  __shared__ float ssum[16][128];
  __shared__ float smax[16][128];
  int g = blockIdx.x / PCH, ch = blockIdx.x % PCH;
  int t = threadIdx.x;
  int rg = t >> 4, cg = t & 15;
  int s0 = startg[g], s1 = startg[g + 1];
  int cnt = s1 - s0;
  int len = (cnt + PCH - 1) / PCH;
  int lo = s0 + ch * len;
  int hi = lo + len; if (hi > s1) hi = s1;
  float sum[8], mx[8];
  #pragma unroll
  for (int k = 0; k < 8; ++k) { sum[k] = 0.f; mx[k] = -INFINITY; }
  const uint4* x4 = (const uint4*)x;
  for (int r = lo + rg; r < hi; r += 16) {
    uint4 v = x4[(size_t)r * 16 + cg];
    uint uu[4] = {v.x, v.y, v.z, v.w};
    #pragma unroll
    for (int q = 0; q < 4; ++q) {
      float a = __uint_as_float(uu[q] << 16);
      float b = __uint_as_float(uu[q] & 0xffff0000u);
      sum[2 * q] += a;     mx[2 * q]     = fmaxf(mx[2 * q], a);
      sum[2 * q + 1] += b; mx[2 * q + 1] = fmaxf(mx[2 * q + 1], b);
    }
  }
  #pragma unroll
  for (int k = 0; k < 8; ++k) {
    ssum[rg][cg * 8 + k] = sum[k];
    smax[rg][cg * 8 + k] = mx[k];
  }
  __syncthreads();
  #pragma unroll
  for (int d = 8; d > 0; d >>= 1) {
    if (rg < d) {
      #pragma unroll
      for (int k = 0; k < 8; ++k) {
        int c = cg * 8 + k;
        ssum[rg][c] += ssum[rg + d][c];
        smax[rg][c] = fmaxf(smax[rg][c], smax[rg + d][c]);
      }
    }
    __syncthreads();
  }
  if (rg == 0) {
    #pragma unroll
    for (int k = 0; k < 8; ++k) {
      int c = cg * 8 + k;
      psum[(size_t)blockIdx.x * HD + c] = ssum[0][c];
      pmax[(size_t)blockIdx.x * HD + c] = smax[0][c];
    }
  }
}

__global__ __launch_bounds__(128) void pool_final_kernel(const float* __restrict__ psum,
    const float* __restrict__ pmax, const int* __restrict__ startg,
    float* __restrict__ repr) {
  int g = blockIdx.x, c = threadIdx.x;
  float sum = 0.f, mx = -INFINITY;
  #pragma unroll
  for (int ch = 0; ch < PCH; ++ch) {
    sum += psum[(size_t)(g * PCH + ch) * HD + c];
    mx = fmaxf(mx, pmax[(size_t)(g * PCH + ch) * HD + c]);
  }
  int cnt = startg[g + 1] - startg[g];
  float denom = (float)(cnt > 0 ? cnt : 1);
  repr[g * 256 + c] = sum / denom;
  repr[g * 256 + 128 + c] = mx;
}

// ---------------- decoder + value heads (one block per graph) ----------------
__global__ __launch_bounds__(128) void heads_kernel(
    const float* __restrict__ repr,
    const float* __restrict__ dw1, const float* __restrict__ db1,
    const float* __restrict__ dw2, const float* __restrict__ db2,
    const float* __restrict__ dw3, const float* __restrict__ db3,
    const float* __restrict__ vw1, const float* __restrict__ vb1,
    const float* __restrict__ vw2, const float* __restrict__ vb2,
    float* __restrict__ out, int ng) {
  __shared__ float rep[256];
  __shared__ float h1[128];
  __shared__ float h2[64];
  __shared__ float v1[128];
  int g = blockIdx.x, t = threadIdx.x;
  rep[t] = repr[g * 256 + t];
  rep[128 + t] = repr[g * 256 + 128 + t];
  __syncthreads();
  float a = db1[t], b = vb1[t];
  for (int k = 0; k < 256; ++k) {
    float rv = rep[k];
    a = fmaf(rv, dw1[k * 128 + t], a);
    b = fmaf(rv, vw1[k * 128 + t], b);
  }
  h1[t] = fmaxf(a, 0.f);
  v1[t] = fmaxf(b, 0.f);
  __syncthreads();
  if (t < 64) {
    float c = db2[t];
    for (int k = 0; k < 128; ++k) c = fmaf(h1[k], dw2[k * 64 + t], c);
    h2[t] = fmaxf(c, 0.f);
  }
  __syncthreads();
  if (t == 0) {
    float l0 = db3[0], l2 = db3[2];
    for (int k = 0; k < 64; ++k) {
      l0 = fmaf(h2[k], dw3[k * 3 + 0], l0);
      l2 = fmaf(h2[k], dw3[k * 3 + 2], l2);
    }
    out[g] = 1.f / (1.f + expf(-l0));          // adaptation_prob
    out[ng + g] = 1.0f;                        // softmax over 1 element == 1
    out[2 * ng + g] = 1.f / (1.f + expf(-l2)); // urgency_score
    float v = vb2[0];
    for (int k = 0; k < 128; ++k) v = fmaf(v1[k], vw2[k], v);
    out[3 * ng + g] = v;                       // value_estimate
  }
}

// ---------------- launch ----------------
extern "C" void kernel_launch(void* const* d_in, const int* in_sizes, int n_in,
                              void* d_out, int out_size, void* d_ws, size_t ws_size,
                              hipStream_t stream) {
  const float* nf     = (const float*)d_in[0];
  const int*   ei     = (const int*)d_in[1];
  const int*   batch  = (const int*)d_in[2];
  const float* enc_w1 = (const float*)d_in[3];
  const float* enc_b1 = (const float*)d_in[4];
  const float* enc_w2 = (const float*)d_in[5];
  const float* enc_b2 = (const float*)d_in[6];
  const float* gcn_w  = (const float*)d_in[7];
  const float* gcn_b  = (const float*)d_in[8];
  const float* dec_w1 = (const float*)d_in[9];
  const float* dec_b1 = (const float*)d_in[10];
  const float* dec_w2 = (const float*)d_in[11];
  const float* dec_b2 = (const float*)d_in[12];
  const float* dec_w3 = (const float*)d_in[13];
  const float* dec_b3 = (const float*)d_in[14];
  const float* val_w1 = (const float*)d_in[15];
  const float* val_b1 = (const float*)d_in[16];
  const float* val_w2 = (const float*)d_in[17];
  const float* val_b2 = (const float*)d_in[18];
  float* out = (float*)d_out;

  const int n = in_sizes[0] / FD;           // 100000
  const int e = in_sizes[1] / 2;            // 1600000
  const int L = in_sizes[7] / (HD * HD);    // 3
  const int G = out_size / 4;               // 64

  // workspace carve
  char* p = (char*)d_ws;
  auto carve = [&](size_t bytes) {
    void* r = (void*)p;
    p += (bytes + 255) & ~(size_t)255;
    return r;
  };
  ushort* x       = (ushort*)carve((size_t)n * HD * 2);    // bf16 x
  ushort* xwb     = (ushort*)carve((size_t)n * HD * 2);    // bf16 encoder tmp
  uchar*  xw8     = (uchar*)carve((size_t)n * HD);         // fp8 message rows
  float*  dinv    = (float*)carve((size_t)n * 4);
  int*    offs    = (int*)carve((size_t)(n + 1) * 4);
  int*    csr_src = (int*)carve((size_t)e * 4);
  float*  repr    = (float*)carve((size_t)G * 256 * 4);
  int*    startg  = (int*)carve((size_t)(G + 1) * 4);
  float*  psum    = (float*)carve((size_t)G * PCH * HD * 4);
  float*  pmax    = (float*)carve((size_t)G * PCH * HD * 4);
  const int nbk   = (n + (1 << BKT_SHIFT) - 1) >> BKT_SHIFT;   // 391 buckets
  int*    bucket_count  = (int*)carve((size_t)nbk * 4);
  int*    bucket_base   = (int*)carve((size_t)(nbk + 1) * 4);
  int*    bucket_cursor = (int*)carve((size_t)nbk * 4);
  ushort* wt_e1   = (ushort*)carve((size_t)128 * FD * 2);      // enc_w1^T bf16
  ushort* wt_e2   = (ushort*)carve((size_t)128 * HD * 2);      // enc_w2^T bf16
  ushort* wt_g    = (ushort*)carve((size_t)3 * 128 * HD * 2);  // gcn_w^T bf16
  // pairs aliases xwb: CSR build completes before enc1 writes xwb (stream-ordered)
  uint*   pairs   = (uint*)xwb;

  const int gemm_grid = (n + 63) / 64;
  const int ebk_grid = (e + EPB - 1) / EPB;

  // ---- graph structure (before encoder so pairs can alias xwb) ----
  zero_int_kernel<<<(nbk + 255) / 256, 256, 0, stream>>>(bucket_count, nbk);
  bucket_count_kernel<<<ebk_grid, 256, 0, stream>>>(ei + e, bucket_count, e, nbk);
  bucket_scan_kernel<<<1, 512, 0, stream>>>(bucket_count, bucket_base, bucket_cursor, nbk);
  bucket_fill_kernel<<<ebk_grid, 256, 0, stream>>>(ei, ei + e, bucket_cursor, pairs, e, nbk);
  bucket_scatter_kernel<<<nbk, 256, 0, stream>>>(pairs, bucket_base, offs, dinv, csr_src, n, nbk);

  // ---- weight transposes (tiny) ----
  convert_wt_kernel<<<(128 * FD + 255) / 256, 256, 0, stream>>>(enc_w1, wt_e1, FD);
  convert_wt_kernel<<<(128 * HD + 255) / 256, 256, 0, stream>>>(enc_w2, wt_e2, HD);
  for (int l = 0; l < L; ++l)
    convert_wt_kernel<<<(128 * HD + 255) / 256, 256, 0, stream>>>(
        gcn_w + (size_t)l * HD * HD, wt_g + (size_t)l * 128 * HD, HD);

  // ---- encoder: nf @ w1 -> relu (bf16), @ w2 -> x (bf16) ----
  mfma_gemm_kernel<float, FD, true, true, false><<<gemm_grid, 256, 0, stream>>>(
      nf, wt_e1, enc_b1, xwb, nullptr, n);
  mfma_gemm_kernel<ushort, HD, true, false, false><<<gemm_grid, 256, 0, stream>>>(
      xwb, wt_e2, enc_b2, x, nullptr, n);

  // ---- GCN layers: GEMM writes fp8 rows pre-scaled by dinv*16 ----
  for (int l = 0; l < L; ++l) {
    mfma_gemm_kernel<ushort, HD, false, false, true><<<gemm_grid, 256, 0, stream>>>(
        x, wt_g + (size_t)l * 128 * HD, nullptr, xw8, dinv, n);
    agg_update_kernel<<<(n + 3) / 4, 256, 0, stream>>>(
        xw8, x, csr_src, offs, dinv, gcn_b + (size_t)l * HD, n);
  }

  // ---- pooling + heads ----
  bounds_kernel<<<(n + 1 + 255) / 256, 256, 0, stream>>>(batch, startg, n, G);
  pool_partial_kernel<<<G * PCH, 256, 0, stream>>>(x, startg, psum, pmax);
  pool_final_kernel<<<G, 128, 0, stream>>>(psum, pmax, startg, repr);
  heads_kernel<<<G, 128, 0, stream>>>(repr,
      dec_w1, dec_b1, dec_w2, dec_b2, dec_w3, dec_b3,
      val_w1, val_b1, val_w2, val_b2, out, G);
}